// Round 2
// baseline (1603.435 us; speedup 1.0000x reference)
//
#include <hip/hip_runtime.h>
#include <hip/hip_bf16.h>
#include <cstdint>
#include <cstddef>

// Problem constants (from reference)
#define B_    32
#define N_    1024
#define DEG_  8
#define FIN_  512
#define H_    1024
#define OUT_  10
#define E_    (B_ * N_ * DEG_)   // 262144
#define NN1_  (B_ * N_)          // 32768
#define K1_   (N_ / 2)           // 512
#define NN2_  (B_ * K1_)         // 16384
#define K2_   (N_ / 4)           // 256
#define EPS_  1e-5f

// ---------------- workspace layout (bytes) ----------------
// R1 (64 MiB): Xagg [NN1 x FIN] in stage 1; hpool [NN2 x H] in stage 2 (same size)
// R2 (128 MiB): convout1/h1 [NN1 x H]; after pooling reused as
//               hagg2 [NN2 x H] (first half) + convout2/h2 [NN2 x H] (second half)
constexpr size_t SZ_R1    = (size_t)NN1_ * FIN_ * 4;           // 64 MiB (== NN2*H*4)
constexpr size_t SZ_R2    = (size_t)NN1_ * H_ * 4;             // 128 MiB
constexpr size_t OFF_R1   = 0;
constexpr size_t OFF_R2   = OFF_R1 + SZ_R1;
constexpr size_t OFF_CNT1 = OFF_R2 + SZ_R2;                    // NN1 ints (zeroed)
constexpr size_t OFF_FILL1= OFF_CNT1 + (size_t)NN1_ * 4;       // NN1 ints (zeroed)
constexpr size_t OFF_CNT2 = OFF_FILL1 + (size_t)NN1_ * 4;      // NN2 ints (zeroed)
constexpr size_t OFF_FILL2= OFF_CNT2 + (size_t)NN2_ * 4;       // NN2 ints (zeroed)
constexpr size_t OFF_BN1  = OFF_FILL2 + (size_t)NN2_ * 4;      // 2H floats (zeroed)
constexpr size_t OFF_BN2  = OFF_BN1 + (size_t)2 * H_ * 4;      // 2H floats (zeroed)
constexpr size_t ZERO_BASE = OFF_CNT1;
constexpr size_t ZERO_BYTES = OFF_BN2 + (size_t)2 * H_ * 4 - ZERO_BASE;
constexpr size_t OFF_PTR1 = OFF_BN2 + (size_t)2 * H_ * 4;      // NN1+64 ints
constexpr size_t OFF_PTR2 = OFF_PTR1 + (size_t)(NN1_ + 64) * 4;// NN2+64 ints
constexpr size_t OFF_CSR1 = OFF_PTR2 + (size_t)(NN2_ + 64) * 4;// E ints
constexpr size_t OFF_CSR2 = OFF_CSR1 + (size_t)E_ * 4;         // E ints
constexpr size_t OFF_SC1  = OFF_CSR2 + (size_t)E_ * 4;         // NN1 floats
constexpr size_t OFF_SC2  = OFF_SC1 + (size_t)NN1_ * 4;        // NN2 floats
constexpr size_t OFF_PERM1= OFF_SC2 + (size_t)NN2_ * 4;        // NN2 ints
constexpr size_t OFF_VAL1 = OFF_PERM1 + (size_t)NN2_ * 4;      // NN2 floats
constexpr size_t OFF_PERM2= OFF_VAL1 + (size_t)NN2_ * 4;       // B*K2 ints
constexpr size_t OFF_VAL2 = OFF_PERM2 + (size_t)(B_ * K2_) * 4;// B*K2 floats
constexpr size_t OFF_NEWID= OFF_VAL2 + (size_t)(B_ * K2_) * 4; // NN1 ints (memset 0xFF)
constexpr size_t OFF_PNORM= OFF_NEWID + (size_t)NN1_ * 4;      // 2 floats (padded)
constexpr size_t OFF_X1   = OFF_PNORM + 256;                   // B*H floats
constexpr size_t OFF_X2   = OFF_X1 + (size_t)B_ * H_ * 4;      // B*H floats
// total ≈ 196 MiB

// ---------------- kernels ----------------

// Sparse symmetric-norm aggregation (pre-GEMM):
// out[v,:] = sum_{s in csr[ptr[v]..ptr[v+1])} X[s,:] * dinv[s]*dinv[v] + X[v,:]/deg[v]
// deg[v] = 1 + cnt[v]. blockDim.x == F/4.
__global__ void k_agg(const float* __restrict__ X,
                      const int* __restrict__ csr,
                      const int* __restrict__ ptr,
                      const int* __restrict__ cnt,
                      float* __restrict__ out, int F) {
  int v = blockIdx.x;
  int c = threadIdx.x * 4;
  float degv = 1.0f + (float)cnt[v];
  float dinvv = rsqrtf(degv);
  float inv = 1.0f / degv;
  float4 xv = *(const float4*)&X[(size_t)v * F + c];
  float4 acc = {xv.x * inv, xv.y * inv, xv.z * inv, xv.w * inv};
  int e0 = ptr[v], e1 = ptr[v + 1];
  for (int e = e0; e < e1; ++e) {
    int s = csr[e];
    float w = dinvv * rsqrtf(1.0f + (float)cnt[s]);
    float4 xs = *(const float4*)&X[(size_t)s * F + c];
    acc.x += xs.x * w; acc.y += xs.y * w; acc.z += xs.z * w; acc.w += xs.w * w;
  }
  *(float4*)&out[(size_t)v * F + c] = acc;
}

// fp32 GEMM + bias: C[M,N] = A[M,K] @ B[K,N] + bias[N]. 64x64 tile, BK=16.
__global__ __launch_bounds__(256) void k_gemm(const float* __restrict__ A,
                                              const float* __restrict__ Bm,
                                              const float* __restrict__ bias,
                                              float* __restrict__ C,
                                              int M, int N, int K) {
  __shared__ float As[16][68];   // As[k][m]
  __shared__ float Bs[16][68];   // Bs[k][n]
  const int tx = threadIdx.x, ty = threadIdx.y;
  const int tid = ty * 16 + tx;
  const int arow = tid >> 2, ak = (tid & 3) * 4;
  const int brow = tid >> 4, bc = (tid & 15) * 4;
  const int gm = blockIdx.y * 64, gn = blockIdx.x * 64;
  float acc[4][4] = {};
  for (int k0 = 0; k0 < K; k0 += 16) {
    float4 a4 = *(const float4*)&A[(size_t)(gm + arow) * K + k0 + ak];
    float4 b4 = *(const float4*)&Bm[(size_t)(k0 + brow) * N + gn + bc];
    __syncthreads();
    As[ak + 0][arow] = a4.x; As[ak + 1][arow] = a4.y;
    As[ak + 2][arow] = a4.z; As[ak + 3][arow] = a4.w;
    *(float4*)&Bs[brow][bc] = b4;
    __syncthreads();
#pragma unroll
    for (int kk = 0; kk < 16; ++kk) {
      float4 av = *(const float4*)&As[kk][ty * 4];
      float4 bv = *(const float4*)&Bs[kk][tx * 4];
      float am[4] = {av.x, av.y, av.z, av.w};
      float bb[4] = {bv.x, bv.y, bv.z, bv.w};
#pragma unroll
      for (int i = 0; i < 4; ++i)
#pragma unroll
        for (int j = 0; j < 4; ++j) acc[i][j] += am[i] * bb[j];
    }
  }
  float4 bv4 = *(const float4*)&bias[gn + tx * 4];
#pragma unroll
  for (int i = 0; i < 4; ++i) {
    float4 o = {acc[i][0] + bv4.x, acc[i][1] + bv4.y,
                acc[i][2] + bv4.z, acc[i][3] + bv4.w};
    *(float4*)&C[(size_t)(gm + ty * 4 + i) * N + gn + tx * 4] = o;
  }
}

__global__ void k_pnorm(const float* __restrict__ p1, const float* __restrict__ p2,
                        float* __restrict__ pn) {
  __shared__ float red[256];
  const float* p = (blockIdx.x == 0) ? p1 : p2;
  int t = threadIdx.x;
  float s = 0.f;
  for (int i = t; i < H_; i += 256) s += p[i] * p[i];
  red[t] = s; __syncthreads();
  for (int st = 128; st > 0; st >>= 1) { if (t < st) red[t] += red[t + st]; __syncthreads(); }
  if (t == 0) pn[blockIdx.x] = sqrtf(red[0]);
}

__global__ void k_count(const int* __restrict__ dst, int* __restrict__ cnt) {
  int e = blockIdx.x * 256 + threadIdx.x;
  atomicAdd(&cnt[dst[e]], 1);
}

__global__ void k_count2(const int* __restrict__ src, const int* __restrict__ dst,
                         const int* __restrict__ nid, int* __restrict__ cnt) {
  int e = blockIdx.x * 256 + threadIdx.x;
  int s = nid[src[e]], d = nid[dst[e]];
  if (s >= 0 && d >= 0) atomicAdd(&cnt[d], 1);
}

// single-block exclusive scan of cnt[n] -> ptr[n+1]; n divisible by 1024
__global__ __launch_bounds__(1024) void k_scan(const int* __restrict__ cnt,
                                               int* __restrict__ ptr, int n) {
  __shared__ int sums[1024];
  int t = threadIdx.x;
  int chunk = n / 1024;
  int base = t * chunk;
  int s = 0;
  for (int i = 0; i < chunk; ++i) s += cnt[base + i];
  sums[t] = s; __syncthreads();
  for (int off = 1; off < 1024; off <<= 1) {
    int v = (t >= off) ? sums[t - off] : 0;
    __syncthreads();
    sums[t] += v;
    __syncthreads();
  }
  int run = (t == 0) ? 0 : sums[t - 1];
  for (int i = 0; i < chunk; ++i) { ptr[base + i] = run; run += cnt[base + i]; }
  if (t == 1023) ptr[n] = run;
}

__global__ void k_fill(const int* __restrict__ src, const int* __restrict__ dst,
                       const int* __restrict__ ptr, int* __restrict__ fill,
                       int* __restrict__ csr) {
  int e = blockIdx.x * 256 + threadIdx.x;
  int d = dst[e];
  int pos = ptr[d] + atomicAdd(&fill[d], 1);
  csr[pos] = src[e];
}

__global__ void k_fill2(const int* __restrict__ src, const int* __restrict__ dst,
                        const int* __restrict__ nid, const int* __restrict__ ptr,
                        int* __restrict__ fill, int* __restrict__ csr) {
  int e = blockIdx.x * 256 + threadIdx.x;
  int s = nid[src[e]], d = nid[dst[e]];
  if (s >= 0 && d >= 0) {
    int pos = ptr[d] + atomicAdd(&fill[d], 1);
    csr[pos] = s;
  }
}

// column sums / sumsq (256 rows per block) -> bn[0..H) sum, bn[H..2H) sumsq
__global__ __launch_bounds__(256) void k_colstats(const float* __restrict__ X,
                                                  float* __restrict__ bn) {
  int col = blockIdx.x * 256 + threadIdx.x;
  size_t r0 = (size_t)blockIdx.y * 256;
  float s = 0.f, s2 = 0.f;
  for (int r = 0; r < 256; ++r) {
    float v = X[(r0 + r) * H_ + col];
    s += v; s2 += v * v;
  }
  atomicAdd(&bn[col], s);
  atomicAdd(&bn[H_ + col], s2);
}

__global__ void k_bn_finalize(float* __restrict__ bn, const float* __restrict__ g,
                              const float* __restrict__ be, float inv_n) {
  int c = blockIdx.x * 256 + threadIdx.x;
  float mean = bn[c] * inv_n;
  float var = bn[H_ + c] * inv_n - mean * mean;
  float a = g[c] * rsqrtf(var + EPS_);
  bn[c] = a;
  bn[H_ + c] = be[c] - mean * a;
}

// in-place BN+ReLU, plus score[v] = tanh(dot(h, p)/||p||)
__global__ __launch_bounds__(256) void k_bn_score(float* __restrict__ X,
                                                  const float* __restrict__ bn,
                                                  const float* __restrict__ p,
                                                  const float* __restrict__ pnorm,
                                                  float* __restrict__ score) {
  __shared__ float red[256];
  int v = blockIdx.x;
  int t = threadIdx.x;
  int c = t * 4;
  float4 x = *(float4*)&X[(size_t)v * H_ + c];
  float4 a = *(const float4*)&bn[c];
  float4 cc = *(const float4*)&bn[H_ + c];
  float4 h;
  h.x = fmaxf(x.x * a.x + cc.x, 0.f);
  h.y = fmaxf(x.y * a.y + cc.y, 0.f);
  h.z = fmaxf(x.z * a.z + cc.z, 0.f);
  h.w = fmaxf(x.w * a.w + cc.w, 0.f);
  *(float4*)&X[(size_t)v * H_ + c] = h;
  float4 p4 = *(const float4*)&p[c];
  red[t] = h.x * p4.x + h.y * p4.y + h.z * p4.z + h.w * p4.w;
  __syncthreads();
  for (int s = 128; s > 0; s >>= 1) { if (t < s) red[t] += red[t + s]; __syncthreads(); }
  if (t == 0) score[v] = tanhf(red[0] / pnorm[0]);
}

// per-graph exact descending bitonic sort (tie: smaller index first), keep top-k
__global__ __launch_bounds__(512) void k_topk(const float* __restrict__ score,
                                              int nper, int k,
                                              int* __restrict__ perm,
                                              float* __restrict__ val,
                                              int* __restrict__ newid) {
  __shared__ float sk[1024];
  __shared__ int si[1024];
  int g = blockIdx.x, t = threadIdx.x;
  for (int i = t; i < nper; i += blockDim.x) { sk[i] = score[g * nper + i]; si[i] = i; }
  __syncthreads();
  for (int k2 = 2; k2 <= nper; k2 <<= 1) {
    for (int j = k2 >> 1; j > 0; j >>= 1) {
      for (int i = t; i < nper; i += blockDim.x) {
        int ixj = i ^ j;
        if (ixj > i) {
          float a = sk[i], b = sk[ixj];
          int ia = si[i], ib = si[ixj];
          bool aFirst = (a > b) || (a == b && ia < ib);  // descending rank
          bool dirDesc = ((i & k2) == 0);
          bool doSwap = dirDesc ? (!aFirst) : aFirst;
          if (doSwap) { sk[i] = b; sk[ixj] = a; si[i] = ib; si[ixj] = ia; }
        }
      }
      __syncthreads();
    }
  }
  for (int i = t; i < k; i += blockDim.x) {
    perm[g * k + i] = g * nper + si[i];
    val[g * k + i] = sk[i];
    if (newid) newid[g * nper + si[i]] = g * k + i;
  }
}

// h_new[i] = h[perm[i]] * val[i]
__global__ __launch_bounds__(256) void k_pool(const float* __restrict__ Hm,
                                              const int* __restrict__ perm,
                                              const float* __restrict__ val,
                                              float* __restrict__ out) {
  int i = blockIdx.x;
  int c = threadIdx.x * 4;
  int old = perm[i];
  float vv = val[i];
  float4 x = *(const float4*)&Hm[(size_t)old * H_ + c];
  x.x *= vv; x.y *= vv; x.z *= vv; x.w *= vv;
  *(float4*)&out[(size_t)i * H_ + c] = x;
}

__global__ __launch_bounds__(256) void k_mean(const float* __restrict__ X,
                                              float* __restrict__ out, int k) {
  int g = blockIdx.x;
  int col = blockIdx.y * 256 + threadIdx.x;
  float s = 0.f;
  for (int j = 0; j < k; ++j) s += X[(size_t)(g * k + j) * H_ + col];
  out[g * H_ + col] = s / (float)k;
}

__global__ __launch_bounds__(256) void k_mean_scaled(const float* __restrict__ X,
                                                     const int* __restrict__ perm,
                                                     const float* __restrict__ val,
                                                     float* __restrict__ out, int k) {
  int g = blockIdx.x;
  int col = blockIdx.y * 256 + threadIdx.x;
  float s = 0.f;
  for (int j = 0; j < k; ++j) {
    int r = perm[g * k + j];
    s += val[g * k + j] * X[(size_t)r * H_ + col];
  }
  out[g * H_ + col] = s / (float)k;
}

// fused head: t = x1+x2 ; z = relu(t@Wf + bf) ; out = z@Wf1 + bf1
__global__ __launch_bounds__(512) void k_head(const float* __restrict__ x1,
                                              const float* __restrict__ x2,
                                              const float* __restrict__ Wf,
                                              const float* __restrict__ bf,
                                              const float* __restrict__ Wf1,
                                              const float* __restrict__ bf1,
                                              float* __restrict__ out) {
  __shared__ float tv[H_];
  __shared__ float zs[512];
  __shared__ float red[512];
  int g = blockIdx.x, t = threadIdx.x;
  for (int i = t; i < H_; i += 512) tv[i] = x1[g * H_ + i] + x2[g * H_ + i];
  __syncthreads();
  float acc = bf[t];
  for (int k = 0; k < H_; ++k) acc += tv[k] * Wf[(size_t)k * 512 + t];
  zs[t] = fmaxf(acc, 0.f);
  __syncthreads();
  for (int o = 0; o < OUT_; ++o) {
    red[t] = zs[t] * Wf1[t * OUT_ + o];
    __syncthreads();
    for (int s = 256; s > 0; s >>= 1) { if (t < s) red[t] += red[t + s]; __syncthreads(); }
    if (t == 0) out[g * OUT_ + o] = red[0] + bf1[o];
    __syncthreads();
  }
}

// ---------------- launch ----------------
extern "C" void kernel_launch(void* const* d_in, const int* in_sizes, int n_in,
                              void* d_out, int out_size, void* d_ws, size_t ws_size,
                              hipStream_t stream) {
  (void)in_sizes; (void)n_in; (void)out_size; (void)ws_size;
  const float* x   = (const float*)d_in[0];
  const int*   ei  = (const int*)d_in[1];
  const float* W1  = (const float*)d_in[3];
  const float* b1  = (const float*)d_in[4];
  const float* g1  = (const float*)d_in[5];
  const float* be1 = (const float*)d_in[6];
  const float* p1  = (const float*)d_in[7];
  const float* W2  = (const float*)d_in[8];
  const float* b2  = (const float*)d_in[9];
  const float* g2  = (const float*)d_in[10];
  const float* be2 = (const float*)d_in[11];
  const float* p2  = (const float*)d_in[12];
  const float* Wf  = (const float*)d_in[13];
  const float* bf  = (const float*)d_in[14];
  const float* Wf1 = (const float*)d_in[15];
  const float* bf1 = (const float*)d_in[16];
  const int* srcv = ei;
  const int* dstv = ei + E_;

  char* ws = (char*)d_ws;
  float* r1    = (float*)(ws + OFF_R1);                 // Xagg -> hpool
  float* r2    = (float*)(ws + OFF_R2);                 // convout1/h1
  float* hagg2 = r2;                                    // stage2: first half of R2
  float* h2    = r2 + (size_t)NN2_ * H_;                // stage2: second half of R2
  int* cnt1    = (int*)(ws + OFF_CNT1);
  int* fill1   = (int*)(ws + OFF_FILL1);
  int* cnt2    = (int*)(ws + OFF_CNT2);
  int* fill2   = (int*)(ws + OFF_FILL2);
  float* bn1   = (float*)(ws + OFF_BN1);
  float* bn2   = (float*)(ws + OFF_BN2);
  int* ptr1    = (int*)(ws + OFF_PTR1);
  int* ptr2    = (int*)(ws + OFF_PTR2);
  int* csr1    = (int*)(ws + OFF_CSR1);
  int* csr2    = (int*)(ws + OFF_CSR2);
  float* sc1   = (float*)(ws + OFF_SC1);
  float* sc2   = (float*)(ws + OFF_SC2);
  int* perm1   = (int*)(ws + OFF_PERM1);
  float* val1  = (float*)(ws + OFF_VAL1);
  int* perm2   = (int*)(ws + OFF_PERM2);
  float* val2  = (float*)(ws + OFF_VAL2);
  int* newid1  = (int*)(ws + OFF_NEWID);
  float* pnorm = (float*)(ws + OFF_PNORM);
  float* x1    = (float*)(ws + OFF_X1);
  float* x2    = (float*)(ws + OFF_X2);

  hipMemsetAsync(ws + ZERO_BASE, 0, ZERO_BYTES, stream);
  hipMemsetAsync(ws + OFF_NEWID, 0xFF, (size_t)NN1_ * 4, stream);  // new_id = -1

  k_pnorm<<<2, 256, 0, stream>>>(p1, p2, pnorm);

  // ---- stage 1 ----
  k_count<<<E_ / 256, 256, 0, stream>>>(dstv, cnt1);
  k_scan<<<1, 1024, 0, stream>>>(cnt1, ptr1, NN1_);
  k_fill<<<E_ / 256, 256, 0, stream>>>(srcv, dstv, ptr1, fill1, csr1);
  k_agg<<<NN1_, FIN_ / 4, 0, stream>>>(x, csr1, ptr1, cnt1, r1, FIN_);      // Xagg
  k_gemm<<<dim3(H_ / 64, NN1_ / 64), dim3(16, 16), 0, stream>>>(r1, W1, b1, r2, NN1_, H_, FIN_);
  k_colstats<<<dim3(H_ / 256, NN1_ / 256), 256, 0, stream>>>(r2, bn1);
  k_bn_finalize<<<H_ / 256, 256, 0, stream>>>(bn1, g1, be1, 1.0f / (float)NN1_);
  k_bn_score<<<NN1_, 256, 0, stream>>>(r2, bn1, p1, pnorm + 0, sc1);
  k_topk<<<B_, 512, 0, stream>>>(sc1, N_, K1_, perm1, val1, newid1);
  k_pool<<<NN2_, 256, 0, stream>>>(r2, perm1, val1, r1);                    // hpool -> R1
  k_mean<<<dim3(B_, H_ / 256), 256, 0, stream>>>(r1, x1, K1_);

  // ---- stage 2 ----
  k_count2<<<E_ / 256, 256, 0, stream>>>(srcv, dstv, newid1, cnt2);
  k_scan<<<1, 1024, 0, stream>>>(cnt2, ptr2, NN2_);
  k_fill2<<<E_ / 256, 256, 0, stream>>>(srcv, dstv, newid1, ptr2, fill2, csr2);
  k_agg<<<NN2_, H_ / 4, 0, stream>>>(r1, csr2, ptr2, cnt2, hagg2, H_);      // hagg2 -> R2a (h1 dead)
  k_gemm<<<dim3(H_ / 64, NN2_ / 64), dim3(16, 16), 0, stream>>>(hagg2, W2, b2, h2, NN2_, H_, H_);
  k_colstats<<<dim3(H_ / 256, NN2_ / 256), 256, 0, stream>>>(h2, bn2);
  k_bn_finalize<<<H_ / 256, 256, 0, stream>>>(bn2, g2, be2, 1.0f / (float)NN2_);
  k_bn_score<<<NN2_, 256, 0, stream>>>(h2, bn2, p2, pnorm + 1, sc2);
  k_topk<<<B_, 512, 0, stream>>>(sc2, K1_, K2_, perm2, val2, nullptr);
  k_mean_scaled<<<dim3(B_, H_ / 256), 256, 0, stream>>>(h2, perm2, val2, x2, K2_);

  // ---- head ----
  k_head<<<B_, 512, 0, stream>>>(x1, x2, Wf, bf, Wf1, bf1, (float*)d_out);
}

// Round 3
// 853.616 us; speedup vs baseline: 1.8784x; 1.8784x over previous
//
#include <hip/hip_runtime.h>
#include <hip/hip_bf16.h>
#include <cstdint>
#include <cstddef>

// Problem constants (from reference)
#define B_    32
#define N_    1024
#define DEG_  8
#define FIN_  512
#define H_    1024
#define OUT_  10
#define E_    (B_ * N_ * DEG_)   // 262144
#define NN1_  (B_ * N_)          // 32768
#define K1_   (N_ / 2)           // 512
#define NN2_  (B_ * K1_)         // 16384
#define K2_   (N_ / 4)           // 256
#define EPS_  1e-5f

// ---------------- workspace layout (bytes) ----------------
// R1 (64 MiB): Xagg bf16 [NN1 x FIN] in stage 1; hpool fp32 [NN2 x H] in stage 2
// R2 (128 MiB): convout1/h1 fp32 [NN1 x H]; stage2 reuse:
//               hagg2 bf16 [NN2 x H] (first half) + convout2/h2 fp32 [NN2 x H] (second half)
constexpr size_t SZ_R1    = (size_t)NN1_ * FIN_ * 4;           // 64 MiB (== NN2*H*4)
constexpr size_t SZ_R2    = (size_t)NN1_ * H_ * 4;             // 128 MiB
constexpr size_t OFF_R1   = 0;
constexpr size_t OFF_R2   = OFF_R1 + SZ_R1;
constexpr size_t OFF_CNT1 = OFF_R2 + SZ_R2;                    // NN1 ints (zeroed)
constexpr size_t OFF_FILL1= OFF_CNT1 + (size_t)NN1_ * 4;       // NN1 ints (zeroed)
constexpr size_t OFF_CNT2 = OFF_FILL1 + (size_t)NN1_ * 4;      // NN2 ints (zeroed)
constexpr size_t OFF_FILL2= OFF_CNT2 + (size_t)NN2_ * 4;       // NN2 ints (zeroed)
constexpr size_t OFF_BN1  = OFF_FILL2 + (size_t)NN2_ * 4;      // 2H floats (zeroed)
constexpr size_t OFF_BN2  = OFF_BN1 + (size_t)2 * H_ * 4;      // 2H floats (zeroed)
constexpr size_t ZERO_BASE = OFF_CNT1;
constexpr size_t ZERO_BYTES = OFF_BN2 + (size_t)2 * H_ * 4 - ZERO_BASE;
constexpr size_t OFF_PTR1 = OFF_BN2 + (size_t)2 * H_ * 4;      // NN1+64 ints
constexpr size_t OFF_PTR2 = OFF_PTR1 + (size_t)(NN1_ + 64) * 4;// NN2+64 ints
constexpr size_t OFF_CSR1 = OFF_PTR2 + (size_t)(NN2_ + 64) * 4;// E ints
constexpr size_t OFF_CSR2 = OFF_CSR1 + (size_t)E_ * 4;         // E ints
constexpr size_t OFF_SC1  = OFF_CSR2 + (size_t)E_ * 4;         // NN1 floats
constexpr size_t OFF_SC2  = OFF_SC1 + (size_t)NN1_ * 4;        // NN2 floats
constexpr size_t OFF_PERM1= OFF_SC2 + (size_t)NN2_ * 4;        // NN2 ints
constexpr size_t OFF_VAL1 = OFF_PERM1 + (size_t)NN2_ * 4;      // NN2 floats
constexpr size_t OFF_PERM2= OFF_VAL1 + (size_t)NN2_ * 4;       // B*K2 ints
constexpr size_t OFF_VAL2 = OFF_PERM2 + (size_t)(B_ * K2_) * 4;// B*K2 floats
constexpr size_t OFF_NEWID= OFF_VAL2 + (size_t)(B_ * K2_) * 4; // NN1 ints (memset 0xFF)
constexpr size_t OFF_PNORM= OFF_NEWID + (size_t)NN1_ * 4;      // 2 floats (padded)
constexpr size_t OFF_X1   = OFF_PNORM + 256;                   // B*H floats
constexpr size_t OFF_X2   = OFF_X1 + (size_t)B_ * H_ * 4;      // B*H floats
constexpr size_t OFF_WT1  = OFF_X2 + (size_t)B_ * H_ * 4;      // H*FIN ushort (W1^T bf16)
constexpr size_t OFF_WT2  = OFF_WT1 + (size_t)H_ * FIN_ * 2;   // H*H ushort  (W2^T bf16)
// total ≈ 199 MiB

// ---------------- helpers ----------------
typedef short short8 __attribute__((ext_vector_type(8)));
typedef float f32x4 __attribute__((ext_vector_type(4)));

__device__ inline unsigned short f2bf(float f) {
  uint32_t u = __float_as_uint(f);
  u += 0x7fffu + ((u >> 16) & 1u);   // RNE
  return (unsigned short)(u >> 16);
}

__device__ inline void load_lds16(const void* g, void* l) {
  __builtin_amdgcn_global_load_lds(
      (const __attribute__((address_space(1))) uint32_t*)g,
      (__attribute__((address_space(3))) uint32_t*)l, 16, 0, 0);
}

// ---------------- kernels ----------------

// Sparse symmetric-norm aggregation (pre-GEMM), fp32 in -> bf16 out:
// out[v,:] = sum_{s in csr} X[s,:]*dinv[s]*dinv[v] + X[v,:]/deg[v]
__global__ void k_agg(const float* __restrict__ X,
                      const int* __restrict__ csr,
                      const int* __restrict__ ptr,
                      const int* __restrict__ cnt,
                      unsigned short* __restrict__ out, int F) {
  int v = blockIdx.x;
  int c = threadIdx.x * 4;
  float degv = 1.0f + (float)cnt[v];
  float dinvv = rsqrtf(degv);
  float inv = 1.0f / degv;
  float4 xv = *(const float4*)&X[(size_t)v * F + c];
  float4 acc = {xv.x * inv, xv.y * inv, xv.z * inv, xv.w * inv};
  int e0 = ptr[v], e1 = ptr[v + 1];
  for (int e = e0; e < e1; ++e) {
    int s = csr[e];
    float w = dinvv * rsqrtf(1.0f + (float)cnt[s]);
    float4 xs = *(const float4*)&X[(size_t)s * F + c];
    acc.x += xs.x * w; acc.y += xs.y * w; acc.z += xs.z * w; acc.w += xs.w * w;
  }
  ushort4 o = {f2bf(acc.x), f2bf(acc.y), f2bf(acc.z), f2bf(acc.w)};
  *(ushort4*)&out[(size_t)v * F + c] = o;
}

// W [K][N] fp32 -> Wt [N][K] bf16
__global__ __launch_bounds__(256) void k_wt(const float* __restrict__ W,
                                            unsigned short* __restrict__ Wt,
                                            int K, int N) {
  __shared__ float t[32][33];
  int k0 = blockIdx.y * 32, n0 = blockIdx.x * 32;
  int tx = threadIdx.x, ty = threadIdx.y;
  for (int i = ty; i < 32; i += 8)
    t[i][tx] = W[(size_t)(k0 + i) * N + n0 + tx];
  __syncthreads();
  for (int i = ty; i < 32; i += 8)
    Wt[(size_t)(n0 + i) * K + k0 + tx] = f2bf(t[tx][i]);
}

// bf16 MFMA GEMM (m97 structure): C[M,N] = A[M,K](bf16) @ Bt[N,K](bf16)^T + bias
// 128x128 tile, BK=32, 256 threads = 4 waves (2x2), 4x4 16x16x32 frags/wave.
__global__ __launch_bounds__(256) void k_gemm_bf(const unsigned short* __restrict__ A,
                                                 const unsigned short* __restrict__ Bt,
                                                 const float* __restrict__ bias,
                                                 float* __restrict__ C,
                                                 int M, int N, int K) {
  __shared__ unsigned short sA[128 * 32];
  __shared__ unsigned short sB[128 * 32];
  const int tid = threadIdx.x;
  const int lane = tid & 63;
  const int w = tid >> 6;               // wave 0..3
  const int wy = w >> 1, wx = w & 1;    // 2x2 wave grid
  const int gm = blockIdx.y * 128, gn = blockIdx.x * 128;
  const int m_l = lane & 15, kq = lane >> 4;
  const int srow = lane >> 2;           // staging: row within 16-row chunk
  const int sseg = (lane & 3) * 8;      // staging: k-element offset (16B)

  f32x4 acc[4][4] = {};

  for (int k0 = 0; k0 < K; k0 += 32) {
    __syncthreads();   // prev iteration's LDS reads done
#pragma unroll
    for (int i = 0; i < 2; ++i) {
      int row = w * 32 + i * 16 + srow;
      load_lds16(&A[(size_t)(gm + row) * K + k0 + sseg],
                 (void*)&sA[(size_t)(w * 32 + i * 16) * 32 + (size_t)lane * 8]);
    }
#pragma unroll
    for (int i = 0; i < 2; ++i) {
      int row = w * 32 + i * 16 + srow;
      load_lds16(&Bt[(size_t)(gn + row) * K + k0 + sseg],
                 (void*)&sB[(size_t)(w * 32 + i * 16) * 32 + (size_t)lane * 8]);
    }
    __syncthreads();   // compiler drains vmcnt before barrier

    short8 af[4], bfr[4];
#pragma unroll
    for (int mi = 0; mi < 4; ++mi)
      af[mi] = *(const short8*)&sA[(size_t)(wy * 64 + mi * 16 + m_l) * 32 + kq * 8];
#pragma unroll
    for (int ni = 0; ni < 4; ++ni)
      bfr[ni] = *(const short8*)&sB[(size_t)(wx * 64 + ni * 16 + m_l) * 32 + kq * 8];
#pragma unroll
    for (int mi = 0; mi < 4; ++mi)
#pragma unroll
      for (int ni = 0; ni < 4; ++ni)
        acc[mi][ni] = __builtin_amdgcn_mfma_f32_16x16x32_bf16(af[mi], bfr[ni], acc[mi][ni], 0, 0, 0);
  }

  const int r0 = kq * 4;   // C/D: col = lane&15, row = (lane>>4)*4 + reg
#pragma unroll
  for (int ni = 0; ni < 4; ++ni) {
    int col = gn + wx * 64 + ni * 16 + m_l;
    float bv = bias[col];
#pragma unroll
    for (int mi = 0; mi < 4; ++mi) {
      int rowb = gm + wy * 64 + mi * 16 + r0;
#pragma unroll
      for (int r = 0; r < 4; ++r)
        C[(size_t)(rowb + r) * N + col] = acc[mi][ni][r] + bv;
    }
  }
}

__global__ void k_pnorm(const float* __restrict__ p1, const float* __restrict__ p2,
                        float* __restrict__ pn) {
  __shared__ float red[256];
  const float* p = (blockIdx.x == 0) ? p1 : p2;
  int t = threadIdx.x;
  float s = 0.f;
  for (int i = t; i < H_; i += 256) s += p[i] * p[i];
  red[t] = s; __syncthreads();
  for (int st = 128; st > 0; st >>= 1) { if (t < st) red[t] += red[t + st]; __syncthreads(); }
  if (t == 0) pn[blockIdx.x] = sqrtf(red[0]);
}

__global__ void k_count(const int* __restrict__ dst, int* __restrict__ cnt) {
  int e = blockIdx.x * 256 + threadIdx.x;
  atomicAdd(&cnt[dst[e]], 1);
}

__global__ void k_count2(const int* __restrict__ src, const int* __restrict__ dst,
                         const int* __restrict__ nid, int* __restrict__ cnt) {
  int e = blockIdx.x * 256 + threadIdx.x;
  int s = nid[src[e]], d = nid[dst[e]];
  if (s >= 0 && d >= 0) atomicAdd(&cnt[d], 1);
}

// single-block exclusive scan of cnt[n] -> ptr[n+1]; n divisible by 1024
__global__ __launch_bounds__(1024) void k_scan(const int* __restrict__ cnt,
                                               int* __restrict__ ptr, int n) {
  __shared__ int sums[1024];
  int t = threadIdx.x;
  int chunk = n / 1024;
  int base = t * chunk;
  int s = 0;
  for (int i = 0; i < chunk; ++i) s += cnt[base + i];
  sums[t] = s; __syncthreads();
  for (int off = 1; off < 1024; off <<= 1) {
    int v = (t >= off) ? sums[t - off] : 0;
    __syncthreads();
    sums[t] += v;
    __syncthreads();
  }
  int run = (t == 0) ? 0 : sums[t - 1];
  for (int i = 0; i < chunk; ++i) { ptr[base + i] = run; run += cnt[base + i]; }
  if (t == 1023) ptr[n] = run;
}

__global__ void k_fill(const int* __restrict__ src, const int* __restrict__ dst,
                       const int* __restrict__ ptr, int* __restrict__ fill,
                       int* __restrict__ csr) {
  int e = blockIdx.x * 256 + threadIdx.x;
  int d = dst[e];
  int pos = ptr[d] + atomicAdd(&fill[d], 1);
  csr[pos] = src[e];
}

__global__ void k_fill2(const int* __restrict__ src, const int* __restrict__ dst,
                        const int* __restrict__ nid, const int* __restrict__ ptr,
                        int* __restrict__ fill, int* __restrict__ csr) {
  int e = blockIdx.x * 256 + threadIdx.x;
  int s = nid[src[e]], d = nid[dst[e]];
  if (s >= 0 && d >= 0) {
    int pos = ptr[d] + atomicAdd(&fill[d], 1);
    csr[pos] = s;
  }
}

// column sums / sumsq (256 rows per block) -> bn[0..H) sum, bn[H..2H) sumsq
__global__ __launch_bounds__(256) void k_colstats(const float* __restrict__ X,
                                                  float* __restrict__ bn) {
  int col = blockIdx.x * 256 + threadIdx.x;
  size_t r0 = (size_t)blockIdx.y * 256;
  float s = 0.f, s2 = 0.f;
  for (int r = 0; r < 256; ++r) {
    float v = X[(r0 + r) * H_ + col];
    s += v; s2 += v * v;
  }
  atomicAdd(&bn[col], s);
  atomicAdd(&bn[H_ + col], s2);
}

__global__ void k_bn_finalize(float* __restrict__ bn, const float* __restrict__ g,
                              const float* __restrict__ be, float inv_n) {
  int c = blockIdx.x * 256 + threadIdx.x;
  float mean = bn[c] * inv_n;
  float var = bn[H_ + c] * inv_n - mean * mean;
  float a = g[c] * rsqrtf(var + EPS_);
  bn[c] = a;
  bn[H_ + c] = be[c] - mean * a;
}

// in-place BN+ReLU, plus score[v] = tanh(dot(h, p)/||p||)
__global__ __launch_bounds__(256) void k_bn_score(float* __restrict__ X,
                                                  const float* __restrict__ bn,
                                                  const float* __restrict__ p,
                                                  const float* __restrict__ pnorm,
                                                  float* __restrict__ score) {
  __shared__ float red[256];
  int v = blockIdx.x;
  int t = threadIdx.x;
  int c = t * 4;
  float4 x = *(float4*)&X[(size_t)v * H_ + c];
  float4 a = *(const float4*)&bn[c];
  float4 cc = *(const float4*)&bn[H_ + c];
  float4 h;
  h.x = fmaxf(x.x * a.x + cc.x, 0.f);
  h.y = fmaxf(x.y * a.y + cc.y, 0.f);
  h.z = fmaxf(x.z * a.z + cc.z, 0.f);
  h.w = fmaxf(x.w * a.w + cc.w, 0.f);
  *(float4*)&X[(size_t)v * H_ + c] = h;
  float4 p4 = *(const float4*)&p[c];
  red[t] = h.x * p4.x + h.y * p4.y + h.z * p4.z + h.w * p4.w;
  __syncthreads();
  for (int s = 128; s > 0; s >>= 1) { if (t < s) red[t] += red[t + s]; __syncthreads(); }
  if (t == 0) score[v] = tanhf(red[0] / pnorm[0]);
}

// per-graph exact descending bitonic sort (tie: smaller index first), keep top-k
__global__ __launch_bounds__(512) void k_topk(const float* __restrict__ score,
                                              int nper, int k,
                                              int* __restrict__ perm,
                                              float* __restrict__ val,
                                              int* __restrict__ newid) {
  __shared__ float sk[1024];
  __shared__ int si[1024];
  int g = blockIdx.x, t = threadIdx.x;
  for (int i = t; i < nper; i += blockDim.x) { sk[i] = score[g * nper + i]; si[i] = i; }
  __syncthreads();
  for (int k2 = 2; k2 <= nper; k2 <<= 1) {
    for (int j = k2 >> 1; j > 0; j >>= 1) {
      for (int i = t; i < nper; i += blockDim.x) {
        int ixj = i ^ j;
        if (ixj > i) {
          float a = sk[i], b = sk[ixj];
          int ia = si[i], ib = si[ixj];
          bool aFirst = (a > b) || (a == b && ia < ib);  // descending rank
          bool dirDesc = ((i & k2) == 0);
          bool doSwap = dirDesc ? (!aFirst) : aFirst;
          if (doSwap) { sk[i] = b; sk[ixj] = a; si[i] = ib; si[ixj] = ia; }
        }
      }
      __syncthreads();
    }
  }
  for (int i = t; i < k; i += blockDim.x) {
    perm[g * k + i] = g * nper + si[i];
    val[g * k + i] = sk[i];
    if (newid) newid[g * nper + si[i]] = g * k + i;
  }
}

// h_new[i] = h[perm[i]] * val[i]
__global__ __launch_bounds__(256) void k_pool(const float* __restrict__ Hm,
                                              const int* __restrict__ perm,
                                              const float* __restrict__ val,
                                              float* __restrict__ out) {
  int i = blockIdx.x;
  int c = threadIdx.x * 4;
  int old = perm[i];
  float vv = val[i];
  float4 x = *(const float4*)&Hm[(size_t)old * H_ + c];
  x.x *= vv; x.y *= vv; x.z *= vv; x.w *= vv;
  *(float4*)&out[(size_t)i * H_ + c] = x;
}

__global__ __launch_bounds__(256) void k_mean(const float* __restrict__ X,
                                              float* __restrict__ out, int k) {
  int g = blockIdx.x;
  int col = blockIdx.y * 256 + threadIdx.x;
  float s = 0.f;
  for (int j = 0; j < k; ++j) s += X[(size_t)(g * k + j) * H_ + col];
  out[g * H_ + col] = s / (float)k;
}

__global__ __launch_bounds__(256) void k_mean_scaled(const float* __restrict__ X,
                                                     const int* __restrict__ perm,
                                                     const float* __restrict__ val,
                                                     float* __restrict__ out, int k) {
  int g = blockIdx.x;
  int col = blockIdx.y * 256 + threadIdx.x;
  float s = 0.f;
  for (int j = 0; j < k; ++j) {
    int r = perm[g * k + j];
    s += val[g * k + j] * X[(size_t)r * H_ + col];
  }
  out[g * H_ + col] = s / (float)k;
}

// fused head: t = x1+x2 ; z = relu(t@Wf + bf) ; out = z@Wf1 + bf1
__global__ __launch_bounds__(512) void k_head(const float* __restrict__ x1,
                                              const float* __restrict__ x2,
                                              const float* __restrict__ Wf,
                                              const float* __restrict__ bf,
                                              const float* __restrict__ Wf1,
                                              const float* __restrict__ bf1,
                                              float* __restrict__ out) {
  __shared__ float tv[H_];
  __shared__ float zs[512];
  __shared__ float red[512];
  int g = blockIdx.x, t = threadIdx.x;
  for (int i = t; i < H_; i += 512) tv[i] = x1[g * H_ + i] + x2[g * H_ + i];
  __syncthreads();
  float acc = bf[t];
  for (int k = 0; k < H_; ++k) acc += tv[k] * Wf[(size_t)k * 512 + t];
  zs[t] = fmaxf(acc, 0.f);
  __syncthreads();
  for (int o = 0; o < OUT_; ++o) {
    red[t] = zs[t] * Wf1[t * OUT_ + o];
    __syncthreads();
    for (int s = 256; s > 0; s >>= 1) { if (t < s) red[t] += red[t + s]; __syncthreads(); }
    if (t == 0) out[g * OUT_ + o] = red[0] + bf1[o];
    __syncthreads();
  }
}

// ---------------- launch ----------------
extern "C" void kernel_launch(void* const* d_in, const int* in_sizes, int n_in,
                              void* d_out, int out_size, void* d_ws, size_t ws_size,
                              hipStream_t stream) {
  (void)in_sizes; (void)n_in; (void)out_size; (void)ws_size;
  const float* x   = (const float*)d_in[0];
  const int*   ei  = (const int*)d_in[1];
  const float* W1  = (const float*)d_in[3];
  const float* b1  = (const float*)d_in[4];
  const float* g1  = (const float*)d_in[5];
  const float* be1 = (const float*)d_in[6];
  const float* p1  = (const float*)d_in[7];
  const float* W2  = (const float*)d_in[8];
  const float* b2  = (const float*)d_in[9];
  const float* g2  = (const float*)d_in[10];
  const float* be2 = (const float*)d_in[11];
  const float* p2  = (const float*)d_in[12];
  const float* Wf  = (const float*)d_in[13];
  const float* bf  = (const float*)d_in[14];
  const float* Wf1 = (const float*)d_in[15];
  const float* bf1 = (const float*)d_in[16];
  const int* srcv = ei;
  const int* dstv = ei + E_;

  char* ws = (char*)d_ws;
  unsigned short* xagg = (unsigned short*)(ws + OFF_R1); // stage1 A (bf16)
  float* hpool = (float*)(ws + OFF_R1);                  // stage2 pooled h (fp32)
  float* r2    = (float*)(ws + OFF_R2);                  // h1 (fp32)
  unsigned short* hagg2 = (unsigned short*)(ws + OFF_R2);// stage2 A (bf16, h1 dead)
  float* h2    = r2 + (size_t)NN2_ * H_;                 // stage2 conv out (fp32)
  int* cnt1    = (int*)(ws + OFF_CNT1);
  int* fill1   = (int*)(ws + OFF_FILL1);
  int* cnt2    = (int*)(ws + OFF_CNT2);
  int* fill2   = (int*)(ws + OFF_FILL2);
  float* bn1   = (float*)(ws + OFF_BN1);
  float* bn2   = (float*)(ws + OFF_BN2);
  int* ptr1    = (int*)(ws + OFF_PTR1);
  int* ptr2    = (int*)(ws + OFF_PTR2);
  int* csr1    = (int*)(ws + OFF_CSR1);
  int* csr2    = (int*)(ws + OFF_CSR2);
  float* sc1   = (float*)(ws + OFF_SC1);
  float* sc2   = (float*)(ws + OFF_SC2);
  int* perm1   = (int*)(ws + OFF_PERM1);
  float* val1  = (float*)(ws + OFF_VAL1);
  int* perm2   = (int*)(ws + OFF_PERM2);
  float* val2  = (float*)(ws + OFF_VAL2);
  int* newid1  = (int*)(ws + OFF_NEWID);
  float* pnorm = (float*)(ws + OFF_PNORM);
  float* x1    = (float*)(ws + OFF_X1);
  float* x2    = (float*)(ws + OFF_X2);
  unsigned short* Wt1 = (unsigned short*)(ws + OFF_WT1);
  unsigned short* Wt2 = (unsigned short*)(ws + OFF_WT2);

  hipMemsetAsync(ws + ZERO_BASE, 0, ZERO_BYTES, stream);
  hipMemsetAsync(ws + OFF_NEWID, 0xFF, (size_t)NN1_ * 4, stream);  // new_id = -1

  k_pnorm<<<2, 256, 0, stream>>>(p1, p2, pnorm);
  k_wt<<<dim3(H_ / 32, FIN_ / 32), dim3(32, 8), 0, stream>>>(W1, Wt1, FIN_, H_);
  k_wt<<<dim3(H_ / 32, H_ / 32), dim3(32, 8), 0, stream>>>(W2, Wt2, H_, H_);

  // ---- stage 1 ----
  k_count<<<E_ / 256, 256, 0, stream>>>(dstv, cnt1);
  k_scan<<<1, 1024, 0, stream>>>(cnt1, ptr1, NN1_);
  k_fill<<<E_ / 256, 256, 0, stream>>>(srcv, dstv, ptr1, fill1, csr1);
  k_agg<<<NN1_, FIN_ / 4, 0, stream>>>(x, csr1, ptr1, cnt1, xagg, FIN_);
  k_gemm_bf<<<dim3(H_ / 128, NN1_ / 128), 256, 0, stream>>>(xagg, Wt1, b1, r2, NN1_, H_, FIN_);
  k_colstats<<<dim3(H_ / 256, NN1_ / 256), 256, 0, stream>>>(r2, bn1);
  k_bn_finalize<<<H_ / 256, 256, 0, stream>>>(bn1, g1, be1, 1.0f / (float)NN1_);
  k_bn_score<<<NN1_, 256, 0, stream>>>(r2, bn1, p1, pnorm + 0, sc1);
  k_topk<<<B_, 512, 0, stream>>>(sc1, N_, K1_, perm1, val1, newid1);
  k_pool<<<NN2_, 256, 0, stream>>>(r2, perm1, val1, hpool);
  k_mean<<<dim3(B_, H_ / 256), 256, 0, stream>>>(hpool, x1, K1_);

  // ---- stage 2 ----
  k_count2<<<E_ / 256, 256, 0, stream>>>(srcv, dstv, newid1, cnt2);
  k_scan<<<1, 1024, 0, stream>>>(cnt2, ptr2, NN2_);
  k_fill2<<<E_ / 256, 256, 0, stream>>>(srcv, dstv, newid1, ptr2, fill2, csr2);
  k_agg<<<NN2_, H_ / 4, 0, stream>>>(hpool, csr2, ptr2, cnt2, hagg2, H_);
  k_gemm_bf<<<dim3(H_ / 128, NN2_ / 128), 256, 0, stream>>>(hagg2, Wt2, b2, h2, NN2_, H_, H_);
  k_colstats<<<dim3(H_ / 256, NN2_ / 256), 256, 0, stream>>>(h2, bn2);
  k_bn_finalize<<<H_ / 256, 256, 0, stream>>>(bn2, g2, be2, 1.0f / (float)NN2_);
  k_bn_score<<<NN2_, 256, 0, stream>>>(h2, bn2, p2, pnorm + 1, sc2);
  k_topk<<<B_, 512, 0, stream>>>(sc2, K1_, K2_, perm2, val2, nullptr);
  k_mean_scaled<<<dim3(B_, H_ / 256), 256, 0, stream>>>(h2, perm2, val2, x2, K2_);

  // ---- head ----
  k_head<<<B_, 512, 0, stream>>>(x1, x2, Wf, bf, Wf1, bf1, (float*)d_out);
}

// Round 4
// 704.714 us; speedup vs baseline: 2.2753x; 1.2113x over previous
//
#include <hip/hip_runtime.h>
#include <hip/hip_bf16.h>
#include <cstdint>
#include <cstddef>

// Problem constants (from reference)
#define B_    32
#define N_    1024
#define DEG_  8
#define FIN_  512
#define H_    1024
#define OUT_  10
#define E_    (B_ * N_ * DEG_)   // 262144
#define NN1_  (B_ * N_)          // 32768
#define K1_   (N_ / 2)           // 512
#define NN2_  (B_ * K1_)         // 16384
#define K2_   (N_ / 4)           // 256
#define EPS_  1e-5f

// ---------------- workspace layout (bytes) ----------------
// R1 (64 MiB): Xagg bf16 [NN1 x FIN] in stage 1; hpool fp32 [NN2 x H] in stage 2
// R2 (128 MiB): convout1/h1 fp32 [NN1 x H]; stage2 reuse:
//               hagg2 bf16 [NN2 x H] (first half) + convout2/h2 fp32 [NN2 x H] (second half)
constexpr size_t SZ_R1    = (size_t)NN1_ * FIN_ * 4;           // 64 MiB (== NN2*H*4)
constexpr size_t SZ_R2    = (size_t)NN1_ * H_ * 4;             // 128 MiB
constexpr size_t OFF_R1   = 0;
constexpr size_t OFF_R2   = OFF_R1 + SZ_R1;
constexpr size_t OFF_CNT1 = OFF_R2 + SZ_R2;                    // NN1 ints (zeroed)
constexpr size_t OFF_FILL1= OFF_CNT1 + (size_t)NN1_ * 4;       // NN1 ints (zeroed)
constexpr size_t OFF_CNT2 = OFF_FILL1 + (size_t)NN1_ * 4;      // NN2 ints (zeroed)
constexpr size_t OFF_FILL2= OFF_CNT2 + (size_t)NN2_ * 4;       // NN2 ints (zeroed)
constexpr size_t OFF_BN1  = OFF_FILL2 + (size_t)NN2_ * 4;      // 2H floats (zeroed)
constexpr size_t OFF_BN2  = OFF_BN1 + (size_t)2 * H_ * 4;      // 2H floats (zeroed)
constexpr size_t OFF_X1   = OFF_BN2 + (size_t)2 * H_ * 4;      // B*H floats (zeroed - atomic dst)
constexpr size_t OFF_X2   = OFF_X1 + (size_t)B_ * H_ * 4;      // B*H floats (zeroed - atomic dst)
constexpr size_t ZERO_BASE = OFF_CNT1;
constexpr size_t ZERO_BYTES = OFF_X2 + (size_t)B_ * H_ * 4 - ZERO_BASE;
constexpr size_t OFF_PTR1 = OFF_X2 + (size_t)B_ * H_ * 4;      // NN1+64 ints
constexpr size_t OFF_PTR2 = OFF_PTR1 + (size_t)(NN1_ + 64) * 4;// NN2+64 ints
constexpr size_t OFF_CSR1 = OFF_PTR2 + (size_t)(NN2_ + 64) * 4;// E ints
constexpr size_t OFF_CSR2 = OFF_CSR1 + (size_t)E_ * 4;         // E ints
constexpr size_t OFF_SC1  = OFF_CSR2 + (size_t)E_ * 4;         // NN1 floats
constexpr size_t OFF_SC2  = OFF_SC1 + (size_t)NN1_ * 4;        // NN2 floats
constexpr size_t OFF_PERM1= OFF_SC2 + (size_t)NN2_ * 4;        // NN2 ints
constexpr size_t OFF_VAL1 = OFF_PERM1 + (size_t)NN2_ * 4;      // NN2 floats
constexpr size_t OFF_PERM2= OFF_VAL1 + (size_t)NN2_ * 4;       // B*K2 ints
constexpr size_t OFF_VAL2 = OFF_PERM2 + (size_t)(B_ * K2_) * 4;// B*K2 floats
constexpr size_t OFF_NEWID= OFF_VAL2 + (size_t)(B_ * K2_) * 4; // NN1 ints (memset 0xFF)
constexpr size_t OFF_PNORM= OFF_NEWID + (size_t)NN1_ * 4;      // 2 floats (padded)
constexpr size_t OFF_WT1  = OFF_PNORM + 256;                   // H*FIN ushort (W1^T bf16)
constexpr size_t OFF_WT2  = OFF_WT1 + (size_t)H_ * FIN_ * 2;   // H*H ushort  (W2^T bf16)
// total ≈ 199 MiB

// ---------------- helpers ----------------
typedef short short8 __attribute__((ext_vector_type(8)));
typedef float f32x4 __attribute__((ext_vector_type(4)));

__device__ inline unsigned short f2bf(float f) {
  uint32_t u = __float_as_uint(f);
  u += 0x7fffu + ((u >> 16) & 1u);   // RNE
  return (unsigned short)(u >> 16);
}

__device__ inline void load_lds16(const void* g, void* l) {
  __builtin_amdgcn_global_load_lds(
      (const __attribute__((address_space(1))) uint32_t*)g,
      (__attribute__((address_space(3))) uint32_t*)l, 16, 0, 0);
}

// ---------------- kernels ----------------

// Sparse symmetric-norm aggregation (pre-GEMM), fp32 in -> bf16 out:
// out[v,:] = sum_{s in csr} X[s,:]*dinv[s]*dinv[v] + X[v,:]/deg[v]
__global__ void k_agg(const float* __restrict__ X,
                      const int* __restrict__ csr,
                      const int* __restrict__ ptr,
                      const int* __restrict__ cnt,
                      unsigned short* __restrict__ out, int F) {
  int v = blockIdx.x;
  int c = threadIdx.x * 4;
  float degv = 1.0f + (float)cnt[v];
  float dinvv = rsqrtf(degv);
  float inv = 1.0f / degv;
  float4 xv = *(const float4*)&X[(size_t)v * F + c];
  float4 acc = {xv.x * inv, xv.y * inv, xv.z * inv, xv.w * inv};
  int e0 = ptr[v], e1 = ptr[v + 1];
  for (int e = e0; e < e1; ++e) {
    int s = csr[e];
    float w = dinvv * rsqrtf(1.0f + (float)cnt[s]);
    float4 xs = *(const float4*)&X[(size_t)s * F + c];
    acc.x += xs.x * w; acc.y += xs.y * w; acc.z += xs.z * w; acc.w += xs.w * w;
  }
  ushort4 o = {f2bf(acc.x), f2bf(acc.y), f2bf(acc.z), f2bf(acc.w)};
  *(ushort4*)&out[(size_t)v * F + c] = o;
}

// W [K][N] fp32 -> Wt [N][K] bf16
__global__ __launch_bounds__(256) void k_wt(const float* __restrict__ W,
                                            unsigned short* __restrict__ Wt,
                                            int K, int N) {
  __shared__ float t[32][33];
  int k0 = blockIdx.y * 32, n0 = blockIdx.x * 32;
  int tx = threadIdx.x, ty = threadIdx.y;
  for (int i = ty; i < 32; i += 8)
    t[i][tx] = W[(size_t)(k0 + i) * N + n0 + tx];
  __syncthreads();
  for (int i = ty; i < 32; i += 8)
    Wt[(size_t)(n0 + i) * K + k0 + tx] = f2bf(t[tx][i]);
}

// bf16 MFMA GEMM (m97 structure): C[M,N] = A[M,K](bf16) @ Bt[N,K](bf16)^T + bias
// 128x128 tile, BK=32, 256 threads = 4 waves (2x2), 4x4 16x16x32 frags/wave.
__global__ __launch_bounds__(256) void k_gemm_bf(const unsigned short* __restrict__ A,
                                                 const unsigned short* __restrict__ Bt,
                                                 const float* __restrict__ bias,
                                                 float* __restrict__ C,
                                                 int M, int N, int K) {
  __shared__ unsigned short sA[128 * 32];
  __shared__ unsigned short sB[128 * 32];
  const int tid = threadIdx.x;
  const int lane = tid & 63;
  const int w = tid >> 6;               // wave 0..3
  const int wy = w >> 1, wx = w & 1;    // 2x2 wave grid
  const int gm = blockIdx.y * 128, gn = blockIdx.x * 128;
  const int m_l = lane & 15, kq = lane >> 4;
  const int srow = lane >> 2;           // staging: row within 16-row chunk
  const int sseg = (lane & 3) * 8;      // staging: k-element offset (16B)

  f32x4 acc[4][4] = {};

  for (int k0 = 0; k0 < K; k0 += 32) {
    __syncthreads();   // prev iteration's LDS reads done
#pragma unroll
    for (int i = 0; i < 2; ++i) {
      int row = w * 32 + i * 16 + srow;
      load_lds16(&A[(size_t)(gm + row) * K + k0 + sseg],
                 (void*)&sA[(size_t)(w * 32 + i * 16) * 32 + (size_t)lane * 8]);
    }
#pragma unroll
    for (int i = 0; i < 2; ++i) {
      int row = w * 32 + i * 16 + srow;
      load_lds16(&Bt[(size_t)(gn + row) * K + k0 + sseg],
                 (void*)&sB[(size_t)(w * 32 + i * 16) * 32 + (size_t)lane * 8]);
    }
    __syncthreads();   // compiler drains vmcnt before barrier

    short8 af[4], bfr[4];
#pragma unroll
    for (int mi = 0; mi < 4; ++mi)
      af[mi] = *(const short8*)&sA[(size_t)(wy * 64 + mi * 16 + m_l) * 32 + kq * 8];
#pragma unroll
    for (int ni = 0; ni < 4; ++ni)
      bfr[ni] = *(const short8*)&sB[(size_t)(wx * 64 + ni * 16 + m_l) * 32 + kq * 8];
#pragma unroll
    for (int mi = 0; mi < 4; ++mi)
#pragma unroll
      for (int ni = 0; ni < 4; ++ni)
        acc[mi][ni] = __builtin_amdgcn_mfma_f32_16x16x32_bf16(af[mi], bfr[ni], acc[mi][ni], 0, 0, 0);
  }

  const int r0 = kq * 4;   // C/D: col = lane&15, row = (lane>>4)*4 + reg
#pragma unroll
  for (int ni = 0; ni < 4; ++ni) {
    int col = gn + wx * 64 + ni * 16 + m_l;
    float bv = bias[col];
#pragma unroll
    for (int mi = 0; mi < 4; ++mi) {
      int rowb = gm + wy * 64 + mi * 16 + r0;
#pragma unroll
      for (int r = 0; r < 4; ++r)
        C[(size_t)(rowb + r) * N + col] = acc[mi][ni][r] + bv;
    }
  }
}

__global__ void k_pnorm(const float* __restrict__ p1, const float* __restrict__ p2,
                        float* __restrict__ pn) {
  __shared__ float red[256];
  const float* p = (blockIdx.x == 0) ? p1 : p2;
  int t = threadIdx.x;
  float s = 0.f;
  for (int i = t; i < H_; i += 256) s += p[i] * p[i];
  red[t] = s; __syncthreads();
  for (int st = 128; st > 0; st >>= 1) { if (t < st) red[t] += red[t + st]; __syncthreads(); }
  if (t == 0) pn[blockIdx.x] = sqrtf(red[0]);
}

__global__ void k_count(const int* __restrict__ dst, int* __restrict__ cnt) {
  int e = blockIdx.x * 256 + threadIdx.x;
  atomicAdd(&cnt[dst[e]], 1);
}

__global__ void k_count2(const int* __restrict__ src, const int* __restrict__ dst,
                         const int* __restrict__ nid, int* __restrict__ cnt) {
  int e = blockIdx.x * 256 + threadIdx.x;
  int s = nid[src[e]], d = nid[dst[e]];
  if (s >= 0 && d >= 0) atomicAdd(&cnt[d], 1);
}

// single-block exclusive scan of cnt[n] -> ptr[n+1]; n divisible by 1024
__global__ __launch_bounds__(1024) void k_scan(const int* __restrict__ cnt,
                                               int* __restrict__ ptr, int n) {
  __shared__ int sums[1024];
  int t = threadIdx.x;
  int chunk = n / 1024;
  int base = t * chunk;
  int s = 0;
  for (int i = 0; i < chunk; ++i) s += cnt[base + i];
  sums[t] = s; __syncthreads();
  for (int off = 1; off < 1024; off <<= 1) {
    int v = (t >= off) ? sums[t - off] : 0;
    __syncthreads();
    sums[t] += v;
    __syncthreads();
  }
  int run = (t == 0) ? 0 : sums[t - 1];
  for (int i = 0; i < chunk; ++i) { ptr[base + i] = run; run += cnt[base + i]; }
  if (t == 1023) ptr[n] = run;
}

__global__ void k_fill(const int* __restrict__ src, const int* __restrict__ dst,
                       const int* __restrict__ ptr, int* __restrict__ fill,
                       int* __restrict__ csr) {
  int e = blockIdx.x * 256 + threadIdx.x;
  int d = dst[e];
  int pos = ptr[d] + atomicAdd(&fill[d], 1);
  csr[pos] = src[e];
}

__global__ void k_fill2(const int* __restrict__ src, const int* __restrict__ dst,
                        const int* __restrict__ nid, const int* __restrict__ ptr,
                        int* __restrict__ fill, int* __restrict__ csr) {
  int e = blockIdx.x * 256 + threadIdx.x;
  int s = nid[src[e]], d = nid[dst[e]];
  if (s >= 0 && d >= 0) {
    int pos = ptr[d] + atomicAdd(&fill[d], 1);
    csr[pos] = s;
  }
}

// column sums / sumsq (256 rows per block) -> bn[0..H) sum, bn[H..2H) sumsq
__global__ __launch_bounds__(256) void k_colstats(const float* __restrict__ X,
                                                  float* __restrict__ bn) {
  int col = blockIdx.x * 256 + threadIdx.x;
  size_t r0 = (size_t)blockIdx.y * 256;
  float s = 0.f, s2 = 0.f;
  for (int r = 0; r < 256; ++r) {
    float v = X[(r0 + r) * H_ + col];
    s += v; s2 += v * v;
  }
  atomicAdd(&bn[col], s);
  atomicAdd(&bn[H_ + col], s2);
}

__global__ void k_bn_finalize(float* __restrict__ bn, const float* __restrict__ g,
                              const float* __restrict__ be, float inv_n) {
  int c = blockIdx.x * 256 + threadIdx.x;
  float mean = bn[c] * inv_n;
  float var = bn[H_ + c] * inv_n - mean * mean;
  float a = g[c] * rsqrtf(var + EPS_);
  bn[c] = a;
  bn[H_ + c] = be[c] - mean * a;
}

// in-place BN+ReLU, plus score[v] = tanh(dot(h, p)/||p||)
__global__ __launch_bounds__(256) void k_bn_score(float* __restrict__ X,
                                                  const float* __restrict__ bn,
                                                  const float* __restrict__ p,
                                                  const float* __restrict__ pnorm,
                                                  float* __restrict__ score) {
  __shared__ float red[256];
  int v = blockIdx.x;
  int t = threadIdx.x;
  int c = t * 4;
  float4 x = *(float4*)&X[(size_t)v * H_ + c];
  float4 a = *(const float4*)&bn[c];
  float4 cc = *(const float4*)&bn[H_ + c];
  float4 h;
  h.x = fmaxf(x.x * a.x + cc.x, 0.f);
  h.y = fmaxf(x.y * a.y + cc.y, 0.f);
  h.z = fmaxf(x.z * a.z + cc.z, 0.f);
  h.w = fmaxf(x.w * a.w + cc.w, 0.f);
  *(float4*)&X[(size_t)v * H_ + c] = h;
  float4 p4 = *(const float4*)&p[c];
  red[t] = h.x * p4.x + h.y * p4.y + h.z * p4.z + h.w * p4.w;
  __syncthreads();
  for (int s = 128; s > 0; s >>= 1) { if (t < s) red[t] += red[t + s]; __syncthreads(); }
  if (t == 0) score[v] = tanhf(red[0] / pnorm[0]);
}

// per-graph exact descending bitonic sort (tie: smaller index first), keep top-k
__global__ __launch_bounds__(512) void k_topk(const float* __restrict__ score,
                                              int nper, int k,
                                              int* __restrict__ perm,
                                              float* __restrict__ val,
                                              int* __restrict__ newid) {
  __shared__ float sk[1024];
  __shared__ int si[1024];
  int g = blockIdx.x, t = threadIdx.x;
  for (int i = t; i < nper; i += blockDim.x) { sk[i] = score[g * nper + i]; si[i] = i; }
  __syncthreads();
  for (int k2 = 2; k2 <= nper; k2 <<= 1) {
    for (int j = k2 >> 1; j > 0; j >>= 1) {
      for (int i = t; i < nper; i += blockDim.x) {
        int ixj = i ^ j;
        if (ixj > i) {
          float a = sk[i], b = sk[ixj];
          int ia = si[i], ib = si[ixj];
          bool aFirst = (a > b) || (a == b && ia < ib);  // descending rank
          bool dirDesc = ((i & k2) == 0);
          bool doSwap = dirDesc ? (!aFirst) : aFirst;
          if (doSwap) { sk[i] = b; sk[ixj] = a; si[i] = ib; si[ixj] = ia; }
        }
      }
      __syncthreads();
    }
  }
  for (int i = t; i < k; i += blockDim.x) {
    perm[g * k + i] = g * nper + si[i];
    val[g * k + i] = sk[i];
    if (newid) newid[g * nper + si[i]] = g * k + i;
  }
}

// h_new[i] = h[perm[i]] * val[i]
__global__ __launch_bounds__(256) void k_pool(const float* __restrict__ Hm,
                                              const int* __restrict__ perm,
                                              const float* __restrict__ val,
                                              float* __restrict__ out) {
  int i = blockIdx.x;
  int c = threadIdx.x * 4;
  int old = perm[i];
  float vv = val[i];
  float4 x = *(const float4*)&Hm[(size_t)old * H_ + c];
  x.x *= vv; x.y *= vv; x.z *= vv; x.w *= vv;
  *(float4*)&out[(size_t)i * H_ + c] = x;
}

// partial column-mean with z-split over rows; out must be pre-zeroed.
// out[g,col] += (sum_{j in z-chunk} X[g*k+j, col]) / k
__global__ __launch_bounds__(256) void k_mean(const float* __restrict__ X,
                                              float* __restrict__ out,
                                              int k, int rows_per_blk) {
  int g = blockIdx.x;
  int col = blockIdx.y * 256 + threadIdx.x;
  int j0 = blockIdx.z * rows_per_blk;
  float s = 0.f;
  for (int j = j0; j < j0 + rows_per_blk; ++j)
    s += X[(size_t)(g * k + j) * H_ + col];
  atomicAdd(&out[g * H_ + col], s / (float)k);
}

// partial scaled column-mean (gathered rows), z-split; out pre-zeroed.
__global__ __launch_bounds__(256) void k_mean_scaled(const float* __restrict__ X,
                                                     const int* __restrict__ perm,
                                                     const float* __restrict__ val,
                                                     float* __restrict__ out,
                                                     int k, int rows_per_blk) {
  int g = blockIdx.x;
  int col = blockIdx.y * 256 + threadIdx.x;
  int j0 = blockIdx.z * rows_per_blk;
  float s = 0.f;
  for (int j = j0; j < j0 + rows_per_blk; ++j) {
    int r = perm[g * k + j];
    s += val[g * k + j] * X[(size_t)r * H_ + col];
  }
  atomicAdd(&out[g * H_ + col], s / (float)k);
}

// fused head: t = x1+x2 ; z = relu(t@Wf + bf) ; out = z@Wf1 + bf1
__global__ __launch_bounds__(512) void k_head(const float* __restrict__ x1,
                                              const float* __restrict__ x2,
                                              const float* __restrict__ Wf,
                                              const float* __restrict__ bf,
                                              const float* __restrict__ Wf1,
                                              const float* __restrict__ bf1,
                                              float* __restrict__ out) {
  __shared__ float tv[H_];
  __shared__ float zs[512];
  __shared__ float red[512];
  int g = blockIdx.x, t = threadIdx.x;
  for (int i = t; i < H_; i += 512) tv[i] = x1[g * H_ + i] + x2[g * H_ + i];
  __syncthreads();
  float acc = bf[t];
  for (int k = 0; k < H_; ++k) acc += tv[k] * Wf[(size_t)k * 512 + t];
  zs[t] = fmaxf(acc, 0.f);
  __syncthreads();
  for (int o = 0; o < OUT_; ++o) {
    red[t] = zs[t] * Wf1[t * OUT_ + o];
    __syncthreads();
    for (int s = 256; s > 0; s >>= 1) { if (t < s) red[t] += red[t + s]; __syncthreads(); }
    if (t == 0) out[g * OUT_ + o] = red[0] + bf1[o];
    __syncthreads();
  }
}

// ---------------- launch ----------------
extern "C" void kernel_launch(void* const* d_in, const int* in_sizes, int n_in,
                              void* d_out, int out_size, void* d_ws, size_t ws_size,
                              hipStream_t stream) {
  (void)in_sizes; (void)n_in; (void)out_size; (void)ws_size;
  const float* x   = (const float*)d_in[0];
  const int*   ei  = (const int*)d_in[1];
  const float* W1  = (const float*)d_in[3];
  const float* b1  = (const float*)d_in[4];
  const float* g1  = (const float*)d_in[5];
  const float* be1 = (const float*)d_in[6];
  const float* p1  = (const float*)d_in[7];
  const float* W2  = (const float*)d_in[8];
  const float* b2  = (const float*)d_in[9];
  const float* g2  = (const float*)d_in[10];
  const float* be2 = (const float*)d_in[11];
  const float* p2  = (const float*)d_in[12];
  const float* Wf  = (const float*)d_in[13];
  const float* bf  = (const float*)d_in[14];
  const float* Wf1 = (const float*)d_in[15];
  const float* bf1 = (const float*)d_in[16];
  const int* srcv = ei;
  const int* dstv = ei + E_;

  char* ws = (char*)d_ws;
  unsigned short* xagg = (unsigned short*)(ws + OFF_R1); // stage1 A (bf16)
  float* hpool = (float*)(ws + OFF_R1);                  // stage2 pooled h (fp32)
  float* r2    = (float*)(ws + OFF_R2);                  // h1 (fp32)
  unsigned short* hagg2 = (unsigned short*)(ws + OFF_R2);// stage2 A (bf16, h1 dead)
  float* h2    = r2 + (size_t)NN2_ * H_;                 // stage2 conv out (fp32)
  int* cnt1    = (int*)(ws + OFF_CNT1);
  int* fill1   = (int*)(ws + OFF_FILL1);
  int* cnt2    = (int*)(ws + OFF_CNT2);
  int* fill2   = (int*)(ws + OFF_FILL2);
  float* bn1   = (float*)(ws + OFF_BN1);
  float* bn2   = (float*)(ws + OFF_BN2);
  int* ptr1    = (int*)(ws + OFF_PTR1);
  int* ptr2    = (int*)(ws + OFF_PTR2);
  int* csr1    = (int*)(ws + OFF_CSR1);
  int* csr2    = (int*)(ws + OFF_CSR2);
  float* sc1   = (float*)(ws + OFF_SC1);
  float* sc2   = (float*)(ws + OFF_SC2);
  int* perm1   = (int*)(ws + OFF_PERM1);
  float* val1  = (float*)(ws + OFF_VAL1);
  int* perm2   = (int*)(ws + OFF_PERM2);
  float* val2  = (float*)(ws + OFF_VAL2);
  int* newid1  = (int*)(ws + OFF_NEWID);
  float* pnorm = (float*)(ws + OFF_PNORM);
  float* x1    = (float*)(ws + OFF_X1);
  float* x2    = (float*)(ws + OFF_X2);
  unsigned short* Wt1 = (unsigned short*)(ws + OFF_WT1);
  unsigned short* Wt2 = (unsigned short*)(ws + OFF_WT2);

  hipMemsetAsync(ws + ZERO_BASE, 0, ZERO_BYTES, stream);
  hipMemsetAsync(ws + OFF_NEWID, 0xFF, (size_t)NN1_ * 4, stream);  // new_id = -1

  k_pnorm<<<2, 256, 0, stream>>>(p1, p2, pnorm);
  k_wt<<<dim3(H_ / 32, FIN_ / 32), dim3(32, 8), 0, stream>>>(W1, Wt1, FIN_, H_);
  k_wt<<<dim3(H_ / 32, H_ / 32), dim3(32, 8), 0, stream>>>(W2, Wt2, H_, H_);

  // ---- stage 1 ----
  k_count<<<E_ / 256, 256, 0, stream>>>(dstv, cnt1);
  k_scan<<<1, 1024, 0, stream>>>(cnt1, ptr1, NN1_);
  k_fill<<<E_ / 256, 256, 0, stream>>>(srcv, dstv, ptr1, fill1, csr1);
  k_agg<<<NN1_, FIN_ / 4, 0, stream>>>(x, csr1, ptr1, cnt1, xagg, FIN_);
  k_gemm_bf<<<dim3(H_ / 128, NN1_ / 128), 256, 0, stream>>>(xagg, Wt1, b1, r2, NN1_, H_, FIN_);
  k_colstats<<<dim3(H_ / 256, NN1_ / 256), 256, 0, stream>>>(r2, bn1);
  k_bn_finalize<<<H_ / 256, 256, 0, stream>>>(bn1, g1, be1, 1.0f / (float)NN1_);
  k_bn_score<<<NN1_, 256, 0, stream>>>(r2, bn1, p1, pnorm + 0, sc1);
  k_topk<<<B_, 512, 0, stream>>>(sc1, N_, K1_, perm1, val1, newid1);
  k_pool<<<NN2_, 256, 0, stream>>>(r2, perm1, val1, hpool);
  k_mean<<<dim3(B_, H_ / 256, 8), 256, 0, stream>>>(hpool, x1, K1_, K1_ / 8);

  // ---- stage 2 ----
  k_count2<<<E_ / 256, 256, 0, stream>>>(srcv, dstv, newid1, cnt2);
  k_scan<<<1, 1024, 0, stream>>>(cnt2, ptr2, NN2_);
  k_fill2<<<E_ / 256, 256, 0, stream>>>(srcv, dstv, newid1, ptr2, fill2, csr2);
  k_agg<<<NN2_, H_ / 4, 0, stream>>>(hpool, csr2, ptr2, cnt2, hagg2, H_);
  k_gemm_bf<<<dim3(H_ / 128, NN2_ / 128), 256, 0, stream>>>(hagg2, Wt2, b2, h2, NN2_, H_, H_);
  k_colstats<<<dim3(H_ / 256, NN2_ / 256), 256, 0, stream>>>(h2, bn2);
  k_bn_finalize<<<H_ / 256, 256, 0, stream>>>(bn2, g2, be2, 1.0f / (float)NN2_);
  k_bn_score<<<NN2_, 256, 0, stream>>>(h2, bn2, p2, pnorm + 1, sc2);
  k_topk<<<B_, 512, 0, stream>>>(sc2, K1_, K2_, perm2, val2, nullptr);
  k_mean_scaled<<<dim3(B_, H_ / 256, 4), 256, 0, stream>>>(h2, perm2, val2, x2, K2_, K2_ / 4);

  // ---- head ----
  k_head<<<B_, 512, 0, stream>>>(x1, x2, Wf, bf, Wf1, bf1, (float*)d_out);
}

// Round 5
// 618.393 us; speedup vs baseline: 2.5929x; 1.1396x over previous
//
#include <hip/hip_runtime.h>
#include <hip/hip_bf16.h>
#include <cstdint>
#include <cstddef>

// Problem constants (from reference)
#define B_    32
#define N_    1024
#define DEG_  8
#define FIN_  512
#define H_    1024
#define OUT_  10
#define E_    (B_ * N_ * DEG_)   // 262144
#define NN1_  (B_ * N_)          // 32768
#define K1_   (N_ / 2)           // 512
#define NN2_  (B_ * K1_)         // 16384
#define K2_   (N_ / 4)           // 256
#define EPS_  1e-5f

// ---------------- workspace layout (bytes) ----------------
// conv1/h1 bf16 [NN1 x H] (in-place BN+ReLU)            64 MiB
// xagg bf16 [NN1 x FIN] stage1 A; aliased by hagg2 bf16 [NN2 x H] stage2 A (32 MiB)
// hpool bf16 [NN2 x H]                                   32 MiB
// conv2/h2 bf16 [NN2 x H]                                32 MiB
constexpr size_t OFF_CONV1 = 0;
constexpr size_t OFF_XAGG  = OFF_CONV1 + (size_t)NN1_ * H_ * 2;   // 64 MiB
constexpr size_t OFF_HPOOL = OFF_XAGG + (size_t)NN1_ * FIN_ * 2;  // +32
constexpr size_t OFF_CONV2 = OFF_HPOOL + (size_t)NN2_ * H_ * 2;   // +32
constexpr size_t OFF_CNT1  = OFF_CONV2 + (size_t)NN2_ * H_ * 2;   // NN1 ints (zeroed)
constexpr size_t OFF_FILL1 = OFF_CNT1 + (size_t)NN1_ * 4;
constexpr size_t OFF_CNT2  = OFF_FILL1 + (size_t)NN1_ * 4;
constexpr size_t OFF_FILL2 = OFF_CNT2 + (size_t)NN2_ * 4;
constexpr size_t OFF_BN1   = OFF_FILL2 + (size_t)NN2_ * 4;        // 2H floats (zeroed)
constexpr size_t OFF_BN2   = OFF_BN1 + (size_t)2 * H_ * 4;
constexpr size_t OFF_X1    = OFF_BN2 + (size_t)2 * H_ * 4;        // B*H floats (zeroed)
constexpr size_t OFF_X2    = OFF_X1 + (size_t)B_ * H_ * 4;
constexpr size_t ZERO_BASE = OFF_CNT1;
constexpr size_t ZERO_BYTES = OFF_X2 + (size_t)B_ * H_ * 4 - ZERO_BASE;
constexpr size_t OFF_PTR1  = OFF_X2 + (size_t)B_ * H_ * 4;
constexpr size_t OFF_PTR2  = OFF_PTR1 + (size_t)(NN1_ + 64) * 4;
constexpr size_t OFF_CSR1  = OFF_PTR2 + (size_t)(NN2_ + 64) * 4;
constexpr size_t OFF_CSR2  = OFF_CSR1 + (size_t)E_ * 4;
constexpr size_t OFF_SC1   = OFF_CSR2 + (size_t)E_ * 4;
constexpr size_t OFF_SC2   = OFF_SC1 + (size_t)NN1_ * 4;
constexpr size_t OFF_PERM1 = OFF_SC2 + (size_t)NN2_ * 4;
constexpr size_t OFF_VAL1  = OFF_PERM1 + (size_t)NN2_ * 4;
constexpr size_t OFF_PERM2 = OFF_VAL1 + (size_t)NN2_ * 4;
constexpr size_t OFF_VAL2  = OFF_PERM2 + (size_t)(B_ * K2_) * 4;
constexpr size_t OFF_NEWID = OFF_VAL2 + (size_t)(B_ * K2_) * 4;   // NN1 ints (0xFF)
constexpr size_t OFF_PNORM = OFF_NEWID + (size_t)NN1_ * 4;        // padded
constexpr size_t OFF_WT1   = OFF_PNORM + 256;                     // H*FIN bf16
constexpr size_t OFF_WT2   = OFF_WT1 + (size_t)H_ * FIN_ * 2;     // H*H bf16
// total ≈ 167 MiB

// ---------------- helpers ----------------
typedef short short8 __attribute__((ext_vector_type(8)));
typedef float f32x4 __attribute__((ext_vector_type(4)));

__device__ inline unsigned short f2bf(float f) {
  uint32_t u = __float_as_uint(f);
  u += 0x7fffu + ((u >> 16) & 1u);   // RNE
  return (unsigned short)(u >> 16);
}
__device__ inline float bf2f(unsigned short u) {
  return __uint_as_float(((uint32_t)u) << 16);
}

__device__ inline void load_lds16(const void* g, void* l) {
  __builtin_amdgcn_global_load_lds(
      (const __attribute__((address_space(1))) uint32_t*)g,
      (__attribute__((address_space(3))) uint32_t*)l, 16, 0, 0);
}

// ---------------- kernels ----------------

// Stage-1 aggregation: fp32 X in -> bf16 out. blockDim = F/4 = 128.
__global__ void k_agg(const float* __restrict__ X,
                      const int* __restrict__ csr,
                      const int* __restrict__ ptr,
                      const int* __restrict__ cnt,
                      unsigned short* __restrict__ out, int F) {
  int v = blockIdx.x;
  int c = threadIdx.x * 4;
  float degv = 1.0f + (float)cnt[v];
  float dinvv = rsqrtf(degv);
  float inv = 1.0f / degv;
  float4 xv = *(const float4*)&X[(size_t)v * F + c];
  float4 acc = {xv.x * inv, xv.y * inv, xv.z * inv, xv.w * inv};
  int e0 = ptr[v], e1 = ptr[v + 1];
  for (int e = e0; e < e1; ++e) {
    int s = csr[e];
    float w = dinvv * rsqrtf(1.0f + (float)cnt[s]);
    float4 xs = *(const float4*)&X[(size_t)s * F + c];
    acc.x += xs.x * w; acc.y += xs.y * w; acc.z += xs.z * w; acc.w += xs.w * w;
  }
  ushort4 o = {f2bf(acc.x), f2bf(acc.y), f2bf(acc.z), f2bf(acc.w)};
  *(ushort4*)&out[(size_t)v * F + c] = o;
}

// Stage-2 aggregation: bf16 in -> bf16 out. blockDim = F/4 = 256 (F=1024).
__global__ void k_agg_bf(const unsigned short* __restrict__ X,
                         const int* __restrict__ csr,
                         const int* __restrict__ ptr,
                         const int* __restrict__ cnt,
                         unsigned short* __restrict__ out, int F) {
  int v = blockIdx.x;
  int c = threadIdx.x * 4;
  float degv = 1.0f + (float)cnt[v];
  float dinvv = rsqrtf(degv);
  float inv = 1.0f / degv;
  ushort4 xu = *(const ushort4*)&X[(size_t)v * F + c];
  float4 acc = {bf2f(xu.x) * inv, bf2f(xu.y) * inv, bf2f(xu.z) * inv, bf2f(xu.w) * inv};
  int e0 = ptr[v], e1 = ptr[v + 1];
  for (int e = e0; e < e1; ++e) {
    int s = csr[e];
    float w = dinvv * rsqrtf(1.0f + (float)cnt[s]);
    ushort4 xs = *(const ushort4*)&X[(size_t)s * F + c];
    acc.x += bf2f(xs.x) * w; acc.y += bf2f(xs.y) * w;
    acc.z += bf2f(xs.z) * w; acc.w += bf2f(xs.w) * w;
  }
  ushort4 o = {f2bf(acc.x), f2bf(acc.y), f2bf(acc.z), f2bf(acc.w)};
  *(ushort4*)&out[(size_t)v * F + c] = o;
}

// W [K][N] fp32 -> Wt [N][K] bf16
__global__ __launch_bounds__(256) void k_wt(const float* __restrict__ W,
                                            unsigned short* __restrict__ Wt,
                                            int K, int N) {
  __shared__ float t[32][33];
  int k0 = blockIdx.y * 32, n0 = blockIdx.x * 32;
  int tx = threadIdx.x, ty = threadIdx.y;
  for (int i = ty; i < 32; i += 8)
    t[i][tx] = W[(size_t)(k0 + i) * N + n0 + tx];
  __syncthreads();
  for (int i = ty; i < 32; i += 8)
    Wt[(size_t)(n0 + i) * K + k0 + tx] = f2bf(t[tx][i]);
}

// bf16 MFMA GEMM, bf16 C out, fused per-column sum/sumsq (atomics into bn).
// XCD swizzle: each XCD owns a contiguous m-band, iterates n fast (A stays in L2).
// C[M,N] = A[M,K] @ Bt[N,K]^T + bias. 128x128 tile, BK=32, 4 waves.
__global__ __launch_bounds__(256) void k_gemm_bf(const unsigned short* __restrict__ A,
                                                 const unsigned short* __restrict__ Bt,
                                                 const float* __restrict__ bias,
                                                 unsigned short* __restrict__ C,
                                                 float* __restrict__ bn,
                                                 int M, int N, int K) {
  __shared__ unsigned short sA[128 * 32];
  __shared__ unsigned short sB[128 * 32];
  const int tid = threadIdx.x;
  const int lane = tid & 63;
  const int w = tid >> 6;
  const int wy = w >> 1, wx = w & 1;
  // --- XCD-aware remap (perf heuristic only) ---
  int lin = blockIdx.y * gridDim.x + blockIdx.x;
  int nt = gridDim.x;
  int mchunk = gridDim.y >> 3;          // m-tiles per XCD
  int xcd = lin & 7;
  int idx = lin >> 3;
  int mtile = xcd * mchunk + idx / nt;
  int ntile = idx % nt;
  const int gm = mtile * 128, gn = ntile * 128;

  const int m_l = lane & 15, kq = lane >> 4;
  const int sseg = (lane & 3) * 8;

  f32x4 acc[4][4] = {};

  for (int k0 = 0; k0 < K; k0 += 32) {
    __syncthreads();
#pragma unroll
    for (int i = 0; i < 2; ++i) {
      int row = w * 32 + i * 16 + (lane >> 2);
      load_lds16(&A[(size_t)(gm + row) * K + k0 + sseg],
                 (void*)&sA[(size_t)(w * 32 + i * 16) * 32 + (size_t)lane * 8]);
    }
#pragma unroll
    for (int i = 0; i < 2; ++i) {
      int row = w * 32 + i * 16 + (lane >> 2);
      load_lds16(&Bt[(size_t)(gn + row) * K + k0 + sseg],
                 (void*)&sB[(size_t)(w * 32 + i * 16) * 32 + (size_t)lane * 8]);
    }
    __syncthreads();

    short8 af[4], bfr[4];
#pragma unroll
    for (int mi = 0; mi < 4; ++mi)
      af[mi] = *(const short8*)&sA[(size_t)(wy * 64 + mi * 16 + m_l) * 32 + kq * 8];
#pragma unroll
    for (int ni = 0; ni < 4; ++ni)
      bfr[ni] = *(const short8*)&sB[(size_t)(wx * 64 + ni * 16 + m_l) * 32 + kq * 8];
#pragma unroll
    for (int mi = 0; mi < 4; ++mi)
#pragma unroll
      for (int ni = 0; ni < 4; ++ni)
        acc[mi][ni] = __builtin_amdgcn_mfma_f32_16x16x32_bf16(af[mi], bfr[ni], acc[mi][ni], 0, 0, 0);
  }

  const int r0 = kq * 4;   // C/D: col = lane&15, row = (lane>>4)*4 + reg
#pragma unroll
  for (int ni = 0; ni < 4; ++ni) {
    int col = gn + wx * 64 + ni * 16 + m_l;
    float bv = bias[col];
    float s = 0.f, s2 = 0.f;
#pragma unroll
    for (int mi = 0; mi < 4; ++mi) {
      int rowb = gm + wy * 64 + mi * 16 + r0;
#pragma unroll
      for (int r = 0; r < 4; ++r) {
        float v = acc[mi][ni][r] + bv;
        C[(size_t)(rowb + r) * N + col] = f2bf(v);
        s += v; s2 += v * v;
      }
    }
    // reduce across kq quads (lanes ^16, ^32 share m_l)
    s += __shfl_xor(s, 16, 64);  s2 += __shfl_xor(s2, 16, 64);
    s += __shfl_xor(s, 32, 64);  s2 += __shfl_xor(s2, 32, 64);
    if (kq == 0) {
      atomicAdd(&bn[col], s);
      atomicAdd(&bn[N + col], s2);
    }
  }
}

__global__ void k_pnorm(const float* __restrict__ p1, const float* __restrict__ p2,
                        float* __restrict__ pn) {
  __shared__ float red[256];
  const float* p = (blockIdx.x == 0) ? p1 : p2;
  int t = threadIdx.x;
  float s = 0.f;
  for (int i = t; i < H_; i += 256) s += p[i] * p[i];
  red[t] = s; __syncthreads();
  for (int st = 128; st > 0; st >>= 1) { if (t < st) red[t] += red[t + st]; __syncthreads(); }
  if (t == 0) pn[blockIdx.x] = sqrtf(red[0]);
}

__global__ void k_count(const int* __restrict__ dst, int* __restrict__ cnt) {
  int e = blockIdx.x * 256 + threadIdx.x;
  atomicAdd(&cnt[dst[e]], 1);
}

__global__ void k_count2(const int* __restrict__ src, const int* __restrict__ dst,
                         const int* __restrict__ nid, int* __restrict__ cnt) {
  int e = blockIdx.x * 256 + threadIdx.x;
  int s = nid[src[e]], d = nid[dst[e]];
  if (s >= 0 && d >= 0) atomicAdd(&cnt[d], 1);
}

// single-block exclusive scan of cnt[n] -> ptr[n+1]; n divisible by 1024
__global__ __launch_bounds__(1024) void k_scan(const int* __restrict__ cnt,
                                               int* __restrict__ ptr, int n) {
  __shared__ int sums[1024];
  int t = threadIdx.x;
  int chunk = n / 1024;
  int base = t * chunk;
  int s = 0;
  for (int i = 0; i < chunk; ++i) s += cnt[base + i];
  sums[t] = s; __syncthreads();
  for (int off = 1; off < 1024; off <<= 1) {
    int v = (t >= off) ? sums[t - off] : 0;
    __syncthreads();
    sums[t] += v;
    __syncthreads();
  }
  int run = (t == 0) ? 0 : sums[t - 1];
  for (int i = 0; i < chunk; ++i) { ptr[base + i] = run; run += cnt[base + i]; }
  if (t == 1023) ptr[n] = run;
}

__global__ void k_fill(const int* __restrict__ src, const int* __restrict__ dst,
                       const int* __restrict__ ptr, int* __restrict__ fill,
                       int* __restrict__ csr) {
  int e = blockIdx.x * 256 + threadIdx.x;
  int d = dst[e];
  int pos = ptr[d] + atomicAdd(&fill[d], 1);
  csr[pos] = src[e];
}

__global__ void k_fill2(const int* __restrict__ src, const int* __restrict__ dst,
                        const int* __restrict__ nid, const int* __restrict__ ptr,
                        int* __restrict__ fill, int* __restrict__ csr) {
  int e = blockIdx.x * 256 + threadIdx.x;
  int s = nid[src[e]], d = nid[dst[e]];
  if (s >= 0 && d >= 0) {
    int pos = ptr[d] + atomicAdd(&fill[d], 1);
    csr[pos] = s;
  }
}

__global__ void k_bn_finalize(float* __restrict__ bn, const float* __restrict__ g,
                              const float* __restrict__ be, float inv_n) {
  int c = blockIdx.x * 256 + threadIdx.x;
  float mean = bn[c] * inv_n;
  float var = bn[H_ + c] * inv_n - mean * mean;
  float a = g[c] * rsqrtf(var + EPS_);
  bn[c] = a;
  bn[H_ + c] = be[c] - mean * a;
}

// in-place BN+ReLU on bf16, plus score[v] = tanh(dot(h, p)/||p||)
__global__ __launch_bounds__(256) void k_bn_score(unsigned short* __restrict__ X,
                                                  const float* __restrict__ bn,
                                                  const float* __restrict__ p,
                                                  const float* __restrict__ pnorm,
                                                  float* __restrict__ score) {
  __shared__ float red[256];
  int v = blockIdx.x;
  int t = threadIdx.x;
  int c = t * 4;
  ushort4 xu = *(ushort4*)&X[(size_t)v * H_ + c];
  float4 a = *(const float4*)&bn[c];
  float4 cc = *(const float4*)&bn[H_ + c];
  float hx = fmaxf(bf2f(xu.x) * a.x + cc.x, 0.f);
  float hy = fmaxf(bf2f(xu.y) * a.y + cc.y, 0.f);
  float hz = fmaxf(bf2f(xu.z) * a.z + cc.z, 0.f);
  float hw = fmaxf(bf2f(xu.w) * a.w + cc.w, 0.f);
  ushort4 o = {f2bf(hx), f2bf(hy), f2bf(hz), f2bf(hw)};
  *(ushort4*)&X[(size_t)v * H_ + c] = o;
  float4 p4 = *(const float4*)&p[c];
  red[t] = hx * p4.x + hy * p4.y + hz * p4.z + hw * p4.w;
  __syncthreads();
  for (int s = 128; s > 0; s >>= 1) { if (t < s) red[t] += red[t + s]; __syncthreads(); }
  if (t == 0) score[v] = tanhf(red[0] / pnorm[0]);
}

// per-graph exact descending bitonic sort (tie: smaller index first), keep top-k
__global__ __launch_bounds__(512) void k_topk(const float* __restrict__ score,
                                              int nper, int k,
                                              int* __restrict__ perm,
                                              float* __restrict__ val,
                                              int* __restrict__ newid) {
  __shared__ float sk[1024];
  __shared__ int si[1024];
  int g = blockIdx.x, t = threadIdx.x;
  for (int i = t; i < nper; i += blockDim.x) { sk[i] = score[g * nper + i]; si[i] = i; }
  __syncthreads();
  for (int k2 = 2; k2 <= nper; k2 <<= 1) {
    for (int j = k2 >> 1; j > 0; j >>= 1) {
      for (int i = t; i < nper; i += blockDim.x) {
        int ixj = i ^ j;
        if (ixj > i) {
          float a = sk[i], b = sk[ixj];
          int ia = si[i], ib = si[ixj];
          bool aFirst = (a > b) || (a == b && ia < ib);
          bool dirDesc = ((i & k2) == 0);
          bool doSwap = dirDesc ? (!aFirst) : aFirst;
          if (doSwap) { sk[i] = b; sk[ixj] = a; si[i] = ib; si[ixj] = ia; }
        }
      }
      __syncthreads();
    }
  }
  for (int i = t; i < k; i += blockDim.x) {
    perm[g * k + i] = g * nper + si[i];
    val[g * k + i] = sk[i];
    if (newid) newid[g * nper + si[i]] = g * k + i;
  }
}

// h_new[i] = h[perm[i]] * val[i]   (bf16 -> bf16)
__global__ __launch_bounds__(256) void k_pool(const unsigned short* __restrict__ Hm,
                                              const int* __restrict__ perm,
                                              const float* __restrict__ val,
                                              unsigned short* __restrict__ out) {
  int i = blockIdx.x;
  int c = threadIdx.x * 4;
  int old = perm[i];
  float vv = val[i];
  ushort4 xu = *(const ushort4*)&Hm[(size_t)old * H_ + c];
  ushort4 o = {f2bf(bf2f(xu.x) * vv), f2bf(bf2f(xu.y) * vv),
               f2bf(bf2f(xu.z) * vv), f2bf(bf2f(xu.w) * vv)};
  *(ushort4*)&out[(size_t)i * H_ + c] = o;
}

// partial column-mean (bf16 in), z-split; out pre-zeroed fp32
__global__ __launch_bounds__(256) void k_mean(const unsigned short* __restrict__ X,
                                              float* __restrict__ out,
                                              int k, int rows_per_blk) {
  int g = blockIdx.x;
  int col = blockIdx.y * 256 + threadIdx.x;
  int j0 = blockIdx.z * rows_per_blk;
  float s = 0.f;
  for (int j = j0; j < j0 + rows_per_blk; ++j)
    s += bf2f(X[(size_t)(g * k + j) * H_ + col]);
  atomicAdd(&out[g * H_ + col], s / (float)k);
}

// partial scaled column-mean (gathered bf16 rows), z-split; out pre-zeroed
__global__ __launch_bounds__(256) void k_mean_scaled(const unsigned short* __restrict__ X,
                                                     const int* __restrict__ perm,
                                                     const float* __restrict__ val,
                                                     float* __restrict__ out,
                                                     int k, int rows_per_blk) {
  int g = blockIdx.x;
  int col = blockIdx.y * 256 + threadIdx.x;
  int j0 = blockIdx.z * rows_per_blk;
  float s = 0.f;
  for (int j = j0; j < j0 + rows_per_blk; ++j) {
    int r = perm[g * k + j];
    s += val[g * k + j] * bf2f(X[(size_t)r * H_ + col]);
  }
  atomicAdd(&out[g * H_ + col], s / (float)k);
}

// fused head: t = x1+x2 ; z = relu(t@Wf + bf) ; out = z@Wf1 + bf1
__global__ __launch_bounds__(512) void k_head(const float* __restrict__ x1,
                                              const float* __restrict__ x2,
                                              const float* __restrict__ Wf,
                                              const float* __restrict__ bf,
                                              const float* __restrict__ Wf1,
                                              const float* __restrict__ bf1,
                                              float* __restrict__ out) {
  __shared__ float tv[H_];
  __shared__ float zs[512];
  __shared__ float red[512];
  int g = blockIdx.x, t = threadIdx.x;
  for (int i = t; i < H_; i += 512) tv[i] = x1[g * H_ + i] + x2[g * H_ + i];
  __syncthreads();
  float acc = bf[t];
  for (int k = 0; k < H_; ++k) acc += tv[k] * Wf[(size_t)k * 512 + t];
  zs[t] = fmaxf(acc, 0.f);
  __syncthreads();
  for (int o = 0; o < OUT_; ++o) {
    red[t] = zs[t] * Wf1[t * OUT_ + o];
    __syncthreads();
    for (int s = 256; s > 0; s >>= 1) { if (t < s) red[t] += red[t + s]; __syncthreads(); }
    if (t == 0) out[g * OUT_ + o] = red[0] + bf1[o];
    __syncthreads();
  }
}

// ---------------- launch ----------------
extern "C" void kernel_launch(void* const* d_in, const int* in_sizes, int n_in,
                              void* d_out, int out_size, void* d_ws, size_t ws_size,
                              hipStream_t stream) {
  (void)in_sizes; (void)n_in; (void)out_size; (void)ws_size;
  const float* x   = (const float*)d_in[0];
  const int*   ei  = (const int*)d_in[1];
  const float* W1  = (const float*)d_in[3];
  const float* b1  = (const float*)d_in[4];
  const float* g1  = (const float*)d_in[5];
  const float* be1 = (const float*)d_in[6];
  const float* p1  = (const float*)d_in[7];
  const float* W2  = (const float*)d_in[8];
  const float* b2  = (const float*)d_in[9];
  const float* g2  = (const float*)d_in[10];
  const float* be2 = (const float*)d_in[11];
  const float* p2  = (const float*)d_in[12];
  const float* Wf  = (const float*)d_in[13];
  const float* bf  = (const float*)d_in[14];
  const float* Wf1 = (const float*)d_in[15];
  const float* bf1 = (const float*)d_in[16];
  const int* srcv = ei;
  const int* dstv = ei + E_;

  char* ws = (char*)d_ws;
  unsigned short* conv1 = (unsigned short*)(ws + OFF_CONV1); // conv1 -> h1 (in-place)
  unsigned short* xagg  = (unsigned short*)(ws + OFF_XAGG);  // stage1 A
  unsigned short* hagg2 = (unsigned short*)(ws + OFF_XAGG);  // stage2 A (aliases xagg)
  unsigned short* hpool = (unsigned short*)(ws + OFF_HPOOL);
  unsigned short* conv2 = (unsigned short*)(ws + OFF_CONV2); // conv2 -> h2 (in-place)
  int* cnt1    = (int*)(ws + OFF_CNT1);
  int* fill1   = (int*)(ws + OFF_FILL1);
  int* cnt2    = (int*)(ws + OFF_CNT2);
  int* fill2   = (int*)(ws + OFF_FILL2);
  float* bn1   = (float*)(ws + OFF_BN1);
  float* bn2   = (float*)(ws + OFF_BN2);
  int* ptr1    = (int*)(ws + OFF_PTR1);
  int* ptr2    = (int*)(ws + OFF_PTR2);
  int* csr1    = (int*)(ws + OFF_CSR1);
  int* csr2    = (int*)(ws + OFF_CSR2);
  float* sc1   = (float*)(ws + OFF_SC1);
  float* sc2   = (float*)(ws + OFF_SC2);
  int* perm1   = (int*)(ws + OFF_PERM1);
  float* val1  = (float*)(ws + OFF_VAL1);
  int* perm2   = (int*)(ws + OFF_PERM2);
  float* val2  = (float*)(ws + OFF_VAL2);
  int* newid1  = (int*)(ws + OFF_NEWID);
  float* pnorm = (float*)(ws + OFF_PNORM);
  float* x1    = (float*)(ws + OFF_X1);
  float* x2    = (float*)(ws + OFF_X2);
  unsigned short* Wt1 = (unsigned short*)(ws + OFF_WT1);
  unsigned short* Wt2 = (unsigned short*)(ws + OFF_WT2);

  hipMemsetAsync(ws + ZERO_BASE, 0, ZERO_BYTES, stream);
  hipMemsetAsync(ws + OFF_NEWID, 0xFF, (size_t)NN1_ * 4, stream);  // new_id = -1

  k_pnorm<<<2, 256, 0, stream>>>(p1, p2, pnorm);
  k_wt<<<dim3(H_ / 32, FIN_ / 32), dim3(32, 8), 0, stream>>>(W1, Wt1, FIN_, H_);
  k_wt<<<dim3(H_ / 32, H_ / 32), dim3(32, 8), 0, stream>>>(W2, Wt2, H_, H_);

  // ---- stage 1 ----
  k_count<<<E_ / 256, 256, 0, stream>>>(dstv, cnt1);
  k_scan<<<1, 1024, 0, stream>>>(cnt1, ptr1, NN1_);
  k_fill<<<E_ / 256, 256, 0, stream>>>(srcv, dstv, ptr1, fill1, csr1);
  k_agg<<<NN1_, FIN_ / 4, 0, stream>>>(x, csr1, ptr1, cnt1, xagg, FIN_);
  k_gemm_bf<<<dim3(H_ / 128, NN1_ / 128), 256, 0, stream>>>(xagg, Wt1, b1, conv1, bn1, NN1_, H_, FIN_);
  k_bn_finalize<<<H_ / 256, 256, 0, stream>>>(bn1, g1, be1, 1.0f / (float)NN1_);
  k_bn_score<<<NN1_, 256, 0, stream>>>(conv1, bn1, p1, pnorm + 0, sc1);
  k_topk<<<B_, 512, 0, stream>>>(sc1, N_, K1_, perm1, val1, newid1);
  k_pool<<<NN2_, 256, 0, stream>>>(conv1, perm1, val1, hpool);
  k_mean<<<dim3(B_, H_ / 256, 8), 256, 0, stream>>>(hpool, x1, K1_, K1_ / 8);

  // ---- stage 2 ----
  k_count2<<<E_ / 256, 256, 0, stream>>>(srcv, dstv, newid1, cnt2);
  k_scan<<<1, 1024, 0, stream>>>(cnt2, ptr2, NN2_);
  k_fill2<<<E_ / 256, 256, 0, stream>>>(srcv, dstv, newid1, ptr2, fill2, csr2);
  k_agg_bf<<<NN2_, H_ / 4, 0, stream>>>(hpool, csr2, ptr2, cnt2, hagg2, H_);
  k_gemm_bf<<<dim3(H_ / 128, NN2_ / 128), 256, 0, stream>>>(hagg2, Wt2, b2, conv2, bn2, NN2_, H_, H_);
  k_bn_finalize<<<H_ / 256, 256, 0, stream>>>(bn2, g2, be2, 1.0f / (float)NN2_);
  k_bn_score<<<NN2_, 256, 0, stream>>>(conv2, bn2, p2, pnorm + 1, sc2);
  k_topk<<<B_, 512, 0, stream>>>(sc2, K1_, K2_, perm2, val2, nullptr);
  k_mean_scaled<<<dim3(B_, H_ / 256, 4), 256, 0, stream>>>(conv2, perm2, val2, x2, K2_, K2_ / 4);

  // ---- head ----
  k_head<<<B_, 512, 0, stream>>>(x1, x2, Wf, bf, Wf1, bf1, (float*)d_out);
}

// Round 6
// 609.095 us; speedup vs baseline: 2.6325x; 1.0153x over previous
//
#include <hip/hip_runtime.h>
#include <hip/hip_bf16.h>
#include <cstdint>
#include <cstddef>

// Problem constants (from reference)
#define B_    32
#define N_    1024
#define DEG_  8
#define FIN_  512
#define H_    1024
#define OUT_  10
#define E_    (B_ * N_ * DEG_)   // 262144
#define NN1_  (B_ * N_)          // 32768
#define K1_   (N_ / 2)           // 512
#define NN2_  (B_ * K1_)         // 16384
#define K2_   (N_ / 4)           // 256
#define EPS_  1e-5f

// ---------------- workspace layout (bytes) ----------------
constexpr size_t OFF_CONV1 = 0;                                   // NN1 x H bf16 (64 MiB)
constexpr size_t OFF_XAGG  = OFF_CONV1 + (size_t)NN1_ * H_ * 2;   // NN1 x FIN bf16 (32 MiB); stage2: hagg2
constexpr size_t OFF_HPOOL = OFF_XAGG + (size_t)NN1_ * FIN_ * 2;  // NN2 x H bf16 (32 MiB)
constexpr size_t OFF_CONV2 = OFF_HPOOL + (size_t)NN2_ * H_ * 2;   // NN2 x H bf16 (32 MiB)
constexpr size_t OFF_CNT1  = OFF_CONV2 + (size_t)NN2_ * H_ * 2;   // NN1 ints (zeroed)
constexpr size_t OFF_FILL1 = OFF_CNT1 + (size_t)NN1_ * 4;
constexpr size_t OFF_CNT2  = OFF_FILL1 + (size_t)NN1_ * 4;
constexpr size_t OFF_FILL2 = OFF_CNT2 + (size_t)NN2_ * 4;
constexpr size_t OFF_BN1   = OFF_FILL2 + (size_t)NN2_ * 4;        // 2H floats (zeroed)
constexpr size_t OFF_BN2   = OFF_BN1 + (size_t)2 * H_ * 4;
constexpr size_t OFF_X1    = OFF_BN2 + (size_t)2 * H_ * 4;        // B*H floats (zeroed)
constexpr size_t OFF_X2    = OFF_X1 + (size_t)B_ * H_ * 4;
constexpr size_t ZERO_BASE = OFF_CNT1;
constexpr size_t ZERO_BYTES = OFF_X2 + (size_t)B_ * H_ * 4 - ZERO_BASE;
constexpr size_t OFF_PTR1  = OFF_X2 + (size_t)B_ * H_ * 4;
constexpr size_t OFF_PTR2  = OFF_PTR1 + (size_t)(NN1_ + 64) * 4;
constexpr size_t OFF_CSR1  = OFF_PTR2 + (size_t)(NN2_ + 64) * 4;
constexpr size_t OFF_CSR2  = OFF_CSR1 + (size_t)E_ * 4;
constexpr size_t OFF_SC1   = OFF_CSR2 + (size_t)E_ * 4;
constexpr size_t OFF_SC2   = OFF_SC1 + (size_t)NN1_ * 4;
constexpr size_t OFF_PERM1 = OFF_SC2 + (size_t)NN2_ * 4;
constexpr size_t OFF_VAL1  = OFF_PERM1 + (size_t)NN2_ * 4;
constexpr size_t OFF_PERM2 = OFF_VAL1 + (size_t)NN2_ * 4;
constexpr size_t OFF_VAL2  = OFF_PERM2 + (size_t)(B_ * K2_) * 4;
constexpr size_t OFF_NEWID = OFF_VAL2 + (size_t)(B_ * K2_) * 4;   // NN1 ints (0xFF)
constexpr size_t OFF_PNORM = OFF_NEWID + (size_t)NN1_ * 4;        // padded
constexpr size_t OFF_WT1   = OFF_PNORM + 256;                     // H*FIN bf16
constexpr size_t OFF_WT2   = OFF_WT1 + (size_t)H_ * FIN_ * 2;     // H*H bf16
constexpr size_t OFF_XBF   = OFF_WT2 + (size_t)H_ * H_ * 2;       // NN1 x FIN bf16 (32 MiB)
// total ≈ 231 MiB

// ---------------- helpers ----------------
typedef short short8 __attribute__((ext_vector_type(8)));
typedef float f32x4 __attribute__((ext_vector_type(4)));

__device__ inline unsigned short f2bf(float f) {
  uint32_t u = __float_as_uint(f);
  u += 0x7fffu + ((u >> 16) & 1u);   // RNE
  return (unsigned short)(u >> 16);
}
__device__ inline float bf2f(unsigned short u) {
  return __uint_as_float(((uint32_t)u) << 16);
}

__device__ inline void load_lds16(const void* g, void* l) {
  __builtin_amdgcn_global_load_lds(
      (const __attribute__((address_space(1))) uint32_t*)g,
      (__attribute__((address_space(3))) uint32_t*)l, 16, 0, 0);
}

// ---------------- kernels ----------------

// fp32 -> bf16 bulk convert (float4 / ushort4 per thread)
__global__ __launch_bounds__(256) void k_tobf(const float* __restrict__ X,
                                              unsigned short* __restrict__ Y) {
  size_t i = ((size_t)blockIdx.x * 256 + threadIdx.x) * 4;
  float4 v = *(const float4*)&X[i];
  ushort4 o = {f2bf(v.x), f2bf(v.y), f2bf(v.z), f2bf(v.w)};
  *(ushort4*)&Y[i] = o;
}

// Aggregation (bf16 in -> bf16 out), XCD-swizzled: block bid (round-robin
// bid&7 -> XCD) maps to node v = (bid&7)*(NN/8) + bid>>3 so each XCD gathers
// within its own ~4 MiB slab (graphs are contiguous in v).
// out[v,:] = sum_{s in csr} X[s,:]*dinv[s]*dinv[v] + X[v,:]/deg[v]
__global__ void k_agg_bf(const unsigned short* __restrict__ X,
                         const int* __restrict__ csr,
                         const int* __restrict__ ptr,
                         const int* __restrict__ cnt,
                         unsigned short* __restrict__ out, int F) {
  int bid = blockIdx.x;
  int slab = gridDim.x >> 3;
  int v = (bid & 7) * slab + (bid >> 3);
  int c = threadIdx.x * 4;
  float degv = 1.0f + (float)cnt[v];
  float dinvv = rsqrtf(degv);
  float inv = 1.0f / degv;
  ushort4 xu = *(const ushort4*)&X[(size_t)v * F + c];
  float4 acc = {bf2f(xu.x) * inv, bf2f(xu.y) * inv, bf2f(xu.z) * inv, bf2f(xu.w) * inv};
  int e0 = ptr[v], e1 = ptr[v + 1];
  for (int e = e0; e < e1; ++e) {
    int s = csr[e];
    float w = dinvv * rsqrtf(1.0f + (float)cnt[s]);
    ushort4 xs = *(const ushort4*)&X[(size_t)s * F + c];
    acc.x += bf2f(xs.x) * w; acc.y += bf2f(xs.y) * w;
    acc.z += bf2f(xs.z) * w; acc.w += bf2f(xs.w) * w;
  }
  ushort4 o = {f2bf(acc.x), f2bf(acc.y), f2bf(acc.z), f2bf(acc.w)};
  *(ushort4*)&out[(size_t)v * F + c] = o;
}

// W [K][N] fp32 -> Wt [N][K] bf16
__global__ __launch_bounds__(256) void k_wt(const float* __restrict__ W,
                                            unsigned short* __restrict__ Wt,
                                            int K, int N) {
  __shared__ float t[32][33];
  int k0 = blockIdx.y * 32, n0 = blockIdx.x * 32;
  int tx = threadIdx.x, ty = threadIdx.y;
  for (int i = ty; i < 32; i += 8)
    t[i][tx] = W[(size_t)(k0 + i) * N + n0 + tx];
  __syncthreads();
  for (int i = ty; i < 32; i += 8)
    Wt[(size_t)(n0 + i) * K + k0 + tx] = f2bf(t[tx][i]);
}

// bf16 MFMA GEMM, BK=64 (8 barrier-pairs for K=512), bf16 C out,
// fused per-column sum/sumsq, XCD-banded m-tiles.
__global__ __launch_bounds__(256) void k_gemm_bf(const unsigned short* __restrict__ A,
                                                 const unsigned short* __restrict__ Bt,
                                                 const float* __restrict__ bias,
                                                 unsigned short* __restrict__ C,
                                                 float* __restrict__ bn,
                                                 int M, int N, int K) {
  __shared__ unsigned short sA[128 * 64];
  __shared__ unsigned short sB[128 * 64];
  const int tid = threadIdx.x;
  const int lane = tid & 63;
  const int w = tid >> 6;
  const int wy = w >> 1, wx = w & 1;
  // --- XCD-aware remap: each XCD owns a contiguous m-band, iterates n fast ---
  int lin = blockIdx.y * gridDim.x + blockIdx.x;
  int nt = gridDim.x;
  int mchunk = gridDim.y >> 3;
  int xcd = lin & 7;
  int idx = lin >> 3;
  int mtile = xcd * mchunk + idx / nt;
  int ntile = idx % nt;
  const int gm = mtile * 128, gn = ntile * 128;

  const int m_l = lane & 15, kq = lane >> 4;
  const int srow = lane >> 3;          // 8 rows per load inst
  const int sseg = (lane & 7) * 8;     // 16B k-segment

  f32x4 acc[4][4] = {};

  for (int k0 = 0; k0 < K; k0 += 64) {
    __syncthreads();
#pragma unroll
    for (int i = 0; i < 4; ++i) {
      int row = w * 32 + i * 8 + srow;
      load_lds16(&A[(size_t)(gm + row) * K + k0 + sseg],
                 (void*)&sA[(size_t)(w * 32 + i * 8) * 64 + (size_t)lane * 8]);
    }
#pragma unroll
    for (int i = 0; i < 4; ++i) {
      int row = w * 32 + i * 8 + srow;
      load_lds16(&Bt[(size_t)(gn + row) * K + k0 + sseg],
                 (void*)&sB[(size_t)(w * 32 + i * 8) * 64 + (size_t)lane * 8]);
    }
    __syncthreads();

#pragma unroll
    for (int h = 0; h < 2; ++h) {
      short8 af[4], bfr[4];
#pragma unroll
      for (int mi = 0; mi < 4; ++mi)
        af[mi] = *(const short8*)&sA[(size_t)(wy * 64 + mi * 16 + m_l) * 64 + h * 32 + kq * 8];
#pragma unroll
      for (int ni = 0; ni < 4; ++ni)
        bfr[ni] = *(const short8*)&sB[(size_t)(wx * 64 + ni * 16 + m_l) * 64 + h * 32 + kq * 8];
#pragma unroll
      for (int mi = 0; mi < 4; ++mi)
#pragma unroll
        for (int ni = 0; ni < 4; ++ni)
          acc[mi][ni] = __builtin_amdgcn_mfma_f32_16x16x32_bf16(af[mi], bfr[ni], acc[mi][ni], 0, 0, 0);
    }
  }

  const int r0 = kq * 4;   // C/D: col = lane&15, row = (lane>>4)*4 + reg
#pragma unroll
  for (int ni = 0; ni < 4; ++ni) {
    int col = gn + wx * 64 + ni * 16 + m_l;
    float bv = bias[col];
    float s = 0.f, s2 = 0.f;
#pragma unroll
    for (int mi = 0; mi < 4; ++mi) {
      int rowb = gm + wy * 64 + mi * 16 + r0;
#pragma unroll
      for (int r = 0; r < 4; ++r) {
        float v = acc[mi][ni][r] + bv;
        C[(size_t)(rowb + r) * N + col] = f2bf(v);
        s += v; s2 += v * v;
      }
    }
    s += __shfl_xor(s, 16, 64);  s2 += __shfl_xor(s2, 16, 64);
    s += __shfl_xor(s, 32, 64);  s2 += __shfl_xor(s2, 32, 64);
    if (kq == 0) {
      atomicAdd(&bn[col], s);
      atomicAdd(&bn[N + col], s2);
    }
  }
}

__global__ void k_pnorm(const float* __restrict__ p1, const float* __restrict__ p2,
                        float* __restrict__ pn) {
  __shared__ float red[256];
  const float* p = (blockIdx.x == 0) ? p1 : p2;
  int t = threadIdx.x;
  float s = 0.f;
  for (int i = t; i < H_; i += 256) s += p[i] * p[i];
  red[t] = s; __syncthreads();
  for (int st = 128; st > 0; st >>= 1) { if (t < st) red[t] += red[t + st]; __syncthreads(); }
  if (t == 0) pn[blockIdx.x] = sqrtf(red[0]);
}

__global__ void k_count(const int* __restrict__ dst, int* __restrict__ cnt) {
  int e = blockIdx.x * 256 + threadIdx.x;
  atomicAdd(&cnt[dst[e]], 1);
}

__global__ void k_count2(const int* __restrict__ src, const int* __restrict__ dst,
                         const int* __restrict__ nid, int* __restrict__ cnt) {
  int e = blockIdx.x * 256 + threadIdx.x;
  int s = nid[src[e]], d = nid[dst[e]];
  if (s >= 0 && d >= 0) atomicAdd(&cnt[d], 1);
}

// single-block exclusive scan of cnt[n] -> ptr[n+1]; n divisible by 1024
__global__ __launch_bounds__(1024) void k_scan(const int* __restrict__ cnt,
                                               int* __restrict__ ptr, int n) {
  __shared__ int sums[1024];
  int t = threadIdx.x;
  int chunk = n / 1024;
  int base = t * chunk;
  int s = 0;
  for (int i = 0; i < chunk; ++i) s += cnt[base + i];
  sums[t] = s; __syncthreads();
  for (int off = 1; off < 1024; off <<= 1) {
    int v = (t >= off) ? sums[t - off] : 0;
    __syncthreads();
    sums[t] += v;
    __syncthreads();
  }
  int run = (t == 0) ? 0 : sums[t - 1];
  for (int i = 0; i < chunk; ++i) { ptr[base + i] = run; run += cnt[base + i]; }
  if (t == 1023) ptr[n] = run;
}

__global__ void k_fill(const int* __restrict__ src, const int* __restrict__ dst,
                       const int* __restrict__ ptr, int* __restrict__ fill,
                       int* __restrict__ csr) {
  int e = blockIdx.x * 256 + threadIdx.x;
  int d = dst[e];
  int pos = ptr[d] + atomicAdd(&fill[d], 1);
  csr[pos] = src[e];
}

__global__ void k_fill2(const int* __restrict__ src, const int* __restrict__ dst,
                        const int* __restrict__ nid, const int* __restrict__ ptr,
                        int* __restrict__ fill, int* __restrict__ csr) {
  int e = blockIdx.x * 256 + threadIdx.x;
  int s = nid[src[e]], d = nid[dst[e]];
  if (s >= 0 && d >= 0) {
    int pos = ptr[d] + atomicAdd(&fill[d], 1);
    csr[pos] = s;
  }
}

__global__ void k_bn_finalize(float* __restrict__ bn, const float* __restrict__ g,
                              const float* __restrict__ be, float inv_n) {
  int c = blockIdx.x * 256 + threadIdx.x;
  float mean = bn[c] * inv_n;
  float var = bn[H_ + c] * inv_n - mean * mean;
  float a = g[c] * rsqrtf(var + EPS_);
  bn[c] = a;
  bn[H_ + c] = be[c] - mean * a;
}

// in-place BN+ReLU on bf16, plus score[v] = tanh(dot(h, p)/||p||)
__global__ __launch_bounds__(256) void k_bn_score(unsigned short* __restrict__ X,
                                                  const float* __restrict__ bn,
                                                  const float* __restrict__ p,
                                                  const float* __restrict__ pnorm,
                                                  float* __restrict__ score) {
  __shared__ float red[256];
  int v = blockIdx.x;
  int t = threadIdx.x;
  int c = t * 4;
  ushort4 xu = *(ushort4*)&X[(size_t)v * H_ + c];
  float4 a = *(const float4*)&bn[c];
  float4 cc = *(const float4*)&bn[H_ + c];
  float hx = fmaxf(bf2f(xu.x) * a.x + cc.x, 0.f);
  float hy = fmaxf(bf2f(xu.y) * a.y + cc.y, 0.f);
  float hz = fmaxf(bf2f(xu.z) * a.z + cc.z, 0.f);
  float hw = fmaxf(bf2f(xu.w) * a.w + cc.w, 0.f);
  ushort4 o = {f2bf(hx), f2bf(hy), f2bf(hz), f2bf(hw)};
  *(ushort4*)&X[(size_t)v * H_ + c] = o;
  float4 p4 = *(const float4*)&p[c];
  red[t] = hx * p4.x + hy * p4.y + hz * p4.z + hw * p4.w;
  __syncthreads();
  for (int s = 128; s > 0; s >>= 1) { if (t < s) red[t] += red[t + s]; __syncthreads(); }
  if (t == 0) score[v] = tanhf(red[0] / pnorm[0]);
}

// per-graph exact descending bitonic sort (tie: smaller index first), keep top-k
__global__ __launch_bounds__(512) void k_topk(const float* __restrict__ score,
                                              int nper, int k,
                                              int* __restrict__ perm,
                                              float* __restrict__ val,
                                              int* __restrict__ newid) {
  __shared__ float sk[1024];
  __shared__ int si[1024];
  int g = blockIdx.x, t = threadIdx.x;
  for (int i = t; i < nper; i += blockDim.x) { sk[i] = score[g * nper + i]; si[i] = i; }
  __syncthreads();
  for (int k2 = 2; k2 <= nper; k2 <<= 1) {
    for (int j = k2 >> 1; j > 0; j >>= 1) {
      for (int i = t; i < nper; i += blockDim.x) {
        int ixj = i ^ j;
        if (ixj > i) {
          float a = sk[i], b = sk[ixj];
          int ia = si[i], ib = si[ixj];
          bool aFirst = (a > b) || (a == b && ia < ib);
          bool dirDesc = ((i & k2) == 0);
          bool doSwap = dirDesc ? (!aFirst) : aFirst;
          if (doSwap) { sk[i] = b; sk[ixj] = a; si[i] = ib; si[ixj] = ia; }
        }
      }
      __syncthreads();
    }
  }
  for (int i = t; i < k; i += blockDim.x) {
    perm[g * k + i] = g * nper + si[i];
    val[g * k + i] = sk[i];
    if (newid) newid[g * nper + si[i]] = g * k + i;
  }
}

// h_new[i] = h[perm[i]] * val[i]   (bf16 -> bf16)
__global__ __launch_bounds__(256) void k_pool(const unsigned short* __restrict__ Hm,
                                              const int* __restrict__ perm,
                                              const float* __restrict__ val,
                                              unsigned short* __restrict__ out) {
  int i = blockIdx.x;
  int c = threadIdx.x * 4;
  int old = perm[i];
  float vv = val[i];
  ushort4 xu = *(const ushort4*)&Hm[(size_t)old * H_ + c];
  ushort4 o = {f2bf(bf2f(xu.x) * vv), f2bf(bf2f(xu.y) * vv),
               f2bf(bf2f(xu.z) * vv), f2bf(bf2f(xu.w) * vv)};
  *(ushort4*)&out[(size_t)i * H_ + c] = o;
}

// partial column-mean (bf16 in), z-split; out pre-zeroed fp32
__global__ __launch_bounds__(256) void k_mean(const unsigned short* __restrict__ X,
                                              float* __restrict__ out,
                                              int k, int rows_per_blk) {
  int g = blockIdx.x;
  int col = blockIdx.y * 256 + threadIdx.x;
  int j0 = blockIdx.z * rows_per_blk;
  float s = 0.f;
  for (int j = j0; j < j0 + rows_per_blk; ++j)
    s += bf2f(X[(size_t)(g * k + j) * H_ + col]);
  atomicAdd(&out[g * H_ + col], s / (float)k);
}

// partial scaled column-mean (gathered bf16 rows), z-split; out pre-zeroed
__global__ __launch_bounds__(256) void k_mean_scaled(const unsigned short* __restrict__ X,
                                                     const int* __restrict__ perm,
                                                     const float* __restrict__ val,
                                                     float* __restrict__ out,
                                                     int k, int rows_per_blk) {
  int g = blockIdx.x;
  int col = blockIdx.y * 256 + threadIdx.x;
  int j0 = blockIdx.z * rows_per_blk;
  float s = 0.f;
  for (int j = j0; j < j0 + rows_per_blk; ++j) {
    int r = perm[g * k + j];
    s += val[g * k + j] * bf2f(X[(size_t)r * H_ + col]);
  }
  atomicAdd(&out[g * H_ + col], s / (float)k);
}

// fused head: t = x1+x2 ; z = relu(t@Wf + bf) ; out = z@Wf1 + bf1
__global__ __launch_bounds__(512) void k_head(const float* __restrict__ x1,
                                              const float* __restrict__ x2,
                                              const float* __restrict__ Wf,
                                              const float* __restrict__ bf,
                                              const float* __restrict__ Wf1,
                                              const float* __restrict__ bf1,
                                              float* __restrict__ out) {
  __shared__ float tv[H_];
  __shared__ float zs[512];
  __shared__ float red[512];
  int g = blockIdx.x, t = threadIdx.x;
  for (int i = t; i < H_; i += 512) tv[i] = x1[g * H_ + i] + x2[g * H_ + i];
  __syncthreads();
  float acc = bf[t];
  for (int k = 0; k < H_; ++k) acc += tv[k] * Wf[(size_t)k * 512 + t];
  zs[t] = fmaxf(acc, 0.f);
  __syncthreads();
  for (int o = 0; o < OUT_; ++o) {
    red[t] = zs[t] * Wf1[t * OUT_ + o];
    __syncthreads();
    for (int s = 256; s > 0; s >>= 1) { if (t < s) red[t] += red[t + s]; __syncthreads(); }
    if (t == 0) out[g * OUT_ + o] = red[0] + bf1[o];
    __syncthreads();
  }
}

// ---------------- launch ----------------
extern "C" void kernel_launch(void* const* d_in, const int* in_sizes, int n_in,
                              void* d_out, int out_size, void* d_ws, size_t ws_size,
                              hipStream_t stream) {
  (void)in_sizes; (void)n_in; (void)out_size; (void)ws_size;
  const float* x   = (const float*)d_in[0];
  const int*   ei  = (const int*)d_in[1];
  const float* W1  = (const float*)d_in[3];
  const float* b1  = (const float*)d_in[4];
  const float* g1  = (const float*)d_in[5];
  const float* be1 = (const float*)d_in[6];
  const float* p1  = (const float*)d_in[7];
  const float* W2  = (const float*)d_in[8];
  const float* b2  = (const float*)d_in[9];
  const float* g2  = (const float*)d_in[10];
  const float* be2 = (const float*)d_in[11];
  const float* p2  = (const float*)d_in[12];
  const float* Wf  = (const float*)d_in[13];
  const float* bf  = (const float*)d_in[14];
  const float* Wf1 = (const float*)d_in[15];
  const float* bf1 = (const float*)d_in[16];
  const int* srcv = ei;
  const int* dstv = ei + E_;

  char* ws = (char*)d_ws;
  unsigned short* conv1 = (unsigned short*)(ws + OFF_CONV1);
  unsigned short* xagg  = (unsigned short*)(ws + OFF_XAGG);
  unsigned short* hagg2 = (unsigned short*)(ws + OFF_XAGG);  // aliases xagg (dead by then)
  unsigned short* hpool = (unsigned short*)(ws + OFF_HPOOL);
  unsigned short* conv2 = (unsigned short*)(ws + OFF_CONV2);
  unsigned short* xbf   = (unsigned short*)(ws + OFF_XBF);
  int* cnt1    = (int*)(ws + OFF_CNT1);
  int* fill1   = (int*)(ws + OFF_FILL1);
  int* cnt2    = (int*)(ws + OFF_CNT2);
  int* fill2   = (int*)(ws + OFF_FILL2);
  float* bn1   = (float*)(ws + OFF_BN1);
  float* bn2   = (float*)(ws + OFF_BN2);
  int* ptr1    = (int*)(ws + OFF_PTR1);
  int* ptr2    = (int*)(ws + OFF_PTR2);
  int* csr1    = (int*)(ws + OFF_CSR1);
  int* csr2    = (int*)(ws + OFF_CSR2);
  float* sc1   = (float*)(ws + OFF_SC1);
  float* sc2   = (float*)(ws + OFF_SC2);
  int* perm1   = (int*)(ws + OFF_PERM1);
  float* val1  = (float*)(ws + OFF_VAL1);
  int* perm2   = (int*)(ws + OFF_PERM2);
  float* val2  = (float*)(ws + OFF_VAL2);
  int* newid1  = (int*)(ws + OFF_NEWID);
  float* pnorm = (float*)(ws + OFF_PNORM);
  float* x1    = (float*)(ws + OFF_X1);
  float* x2    = (float*)(ws + OFF_X2);
  unsigned short* Wt1 = (unsigned short*)(ws + OFF_WT1);
  unsigned short* Wt2 = (unsigned short*)(ws + OFF_WT2);

  hipMemsetAsync(ws + ZERO_BASE, 0, ZERO_BYTES, stream);
  hipMemsetAsync(ws + OFF_NEWID, 0xFF, (size_t)NN1_ * 4, stream);  // new_id = -1

  k_pnorm<<<2, 256, 0, stream>>>(p1, p2, pnorm);
  k_wt<<<dim3(H_ / 32, FIN_ / 32), dim3(32, 8), 0, stream>>>(W1, Wt1, FIN_, H_);
  k_wt<<<dim3(H_ / 32, H_ / 32), dim3(32, 8), 0, stream>>>(W2, Wt2, H_, H_);
  k_tobf<<<(NN1_ * FIN_) / 1024, 256, 0, stream>>>(x, xbf);

  // ---- stage 1 ----
  k_count<<<E_ / 256, 256, 0, stream>>>(dstv, cnt1);
  k_scan<<<1, 1024, 0, stream>>>(cnt1, ptr1, NN1_);
  k_fill<<<E_ / 256, 256, 0, stream>>>(srcv, dstv, ptr1, fill1, csr1);
  k_agg_bf<<<NN1_, FIN_ / 4, 0, stream>>>(xbf, csr1, ptr1, cnt1, xagg, FIN_);
  k_gemm_bf<<<dim3(H_ / 128, NN1_ / 128), 256, 0, stream>>>(xagg, Wt1, b1, conv1, bn1, NN1_, H_, FIN_);
  k_bn_finalize<<<H_ / 256, 256, 0, stream>>>(bn1, g1, be1, 1.0f / (float)NN1_);
  k_bn_score<<<NN1_, 256, 0, stream>>>(conv1, bn1, p1, pnorm + 0, sc1);
  k_topk<<<B_, 512, 0, stream>>>(sc1, N_, K1_, perm1, val1, newid1);
  k_pool<<<NN2_, 256, 0, stream>>>(conv1, perm1, val1, hpool);
  k_mean<<<dim3(B_, H_ / 256, 8), 256, 0, stream>>>(hpool, x1, K1_, K1_ / 8);

  // ---- stage 2 ----
  k_count2<<<E_ / 256, 256, 0, stream>>>(srcv, dstv, newid1, cnt2);
  k_scan<<<1, 1024, 0, stream>>>(cnt2, ptr2, NN2_);
  k_fill2<<<E_ / 256, 256, 0, stream>>>(srcv, dstv, newid1, ptr2, fill2, csr2);
  k_agg_bf<<<NN2_, H_ / 4, 0, stream>>>(hpool, csr2, ptr2, cnt2, hagg2, H_);
  k_gemm_bf<<<dim3(H_ / 128, NN2_ / 128), 256, 0, stream>>>(hagg2, Wt2, b2, conv2, bn2, NN2_, H_, H_);
  k_bn_finalize<<<H_ / 256, 256, 0, stream>>>(bn2, g2, be2, 1.0f / (float)NN2_);
  k_bn_score<<<NN2_, 256, 0, stream>>>(conv2, bn2, p2, pnorm + 1, sc2);
  k_topk<<<B_, 512, 0, stream>>>(sc2, K1_, K2_, perm2, val2, nullptr);
  k_mean_scaled<<<dim3(B_, H_ / 256, 4), 256, 0, stream>>>(conv2, perm2, val2, x2, K2_, K2_ / 4);

  // ---- head ----
  k_head<<<B_, 512, 0, stream>>>(x1, x2, Wf, bf, Wf1, bf1, (float*)d_out);
}

// Round 7
// 571.288 us; speedup vs baseline: 2.8067x; 1.0662x over previous
//
#include <hip/hip_runtime.h>
#include <hip/hip_bf16.h>
#include <cstdint>
#include <cstddef>

// Problem constants (from reference)
#define B_    32
#define N_    1024
#define DEG_  8
#define FIN_  512
#define H_    1024
#define OUT_  10
#define E_    (B_ * N_ * DEG_)   // 262144
#define NN1_  (B_ * N_)          // 32768
#define K1_   (N_ / 2)           // 512
#define NN2_  (B_ * K1_)         // 16384
#define K2_   (N_ / 4)           // 256
#define EPS_  1e-5f

// ---------------- workspace layout (bytes) ----------------
constexpr size_t OFF_CONV1 = 0;                                   // NN1 x H bf16 (64 MiB)
constexpr size_t OFF_XAGG  = OFF_CONV1 + (size_t)NN1_ * H_ * 2;   // NN1 x FIN bf16 (32 MiB); stage2: hagg2
constexpr size_t OFF_HPOOL = OFF_XAGG + (size_t)NN1_ * FIN_ * 2;  // NN2 x H bf16 (32 MiB)
constexpr size_t OFF_CONV2 = OFF_HPOOL + (size_t)NN2_ * H_ * 2;   // NN2 x H bf16 (32 MiB)
constexpr size_t OFF_CNT1  = OFF_CONV2 + (size_t)NN2_ * H_ * 2;   // NN1 ints (zeroed)
constexpr size_t OFF_FILL1 = OFF_CNT1 + (size_t)NN1_ * 4;
constexpr size_t OFF_CNT2  = OFF_FILL1 + (size_t)NN1_ * 4;
constexpr size_t OFF_FILL2 = OFF_CNT2 + (size_t)NN2_ * 4;
constexpr size_t OFF_BN1   = OFF_FILL2 + (size_t)NN2_ * 4;        // 2H floats (zeroed)
constexpr size_t OFF_BN2   = OFF_BN1 + (size_t)2 * H_ * 4;
constexpr size_t OFF_X1    = OFF_BN2 + (size_t)2 * H_ * 4;        // B*H floats (zeroed)
constexpr size_t OFF_X2    = OFF_X1 + (size_t)B_ * H_ * 4;
constexpr size_t ZERO_BASE = OFF_CNT1;
constexpr size_t ZERO_BYTES = OFF_X2 + (size_t)B_ * H_ * 4 - ZERO_BASE;
constexpr size_t OFF_PTR1  = OFF_X2 + (size_t)B_ * H_ * 4;
constexpr size_t OFF_PTR2  = OFF_PTR1 + (size_t)(NN1_ + 64) * 4;
constexpr size_t OFF_CSR1  = OFF_PTR2 + (size_t)(NN2_ + 64) * 4;
constexpr size_t OFF_CSR2  = OFF_CSR1 + (size_t)E_ * 4;
constexpr size_t OFF_SC1   = OFF_CSR2 + (size_t)E_ * 4;
constexpr size_t OFF_SC2   = OFF_SC1 + (size_t)NN1_ * 4;
constexpr size_t OFF_PERM1 = OFF_SC2 + (size_t)NN2_ * 4;
constexpr size_t OFF_VAL1  = OFF_PERM1 + (size_t)NN2_ * 4;
constexpr size_t OFF_PERM2 = OFF_VAL1 + (size_t)NN2_ * 4;
constexpr size_t OFF_VAL2  = OFF_PERM2 + (size_t)(B_ * K2_) * 4;
constexpr size_t OFF_NEWID = OFF_VAL2 + (size_t)(B_ * K2_) * 4;   // NN1 ints (0xFF)
constexpr size_t OFF_PNORM = OFF_NEWID + (size_t)NN1_ * 4;        // padded
constexpr size_t OFF_WT1   = OFF_PNORM + 256;                     // H*FIN bf16
constexpr size_t OFF_WT2   = OFF_WT1 + (size_t)H_ * FIN_ * 2;     // H*H bf16
constexpr size_t OFF_XBF   = OFF_WT2 + (size_t)H_ * H_ * 2;       // NN1 x FIN bf16 (32 MiB)
// total ≈ 231 MiB

// ---------------- helpers ----------------
typedef short short8 __attribute__((ext_vector_type(8)));
typedef float f32x4 __attribute__((ext_vector_type(4)));

__device__ inline unsigned short f2bf(float f) {
  uint32_t u = __float_as_uint(f);
  u += 0x7fffu + ((u >> 16) & 1u);   // RNE
  return (unsigned short)(u >> 16);
}
__device__ inline float bf2f(unsigned short u) {
  return __uint_as_float(((uint32_t)u) << 16);
}

__device__ inline void load_lds16(const void* g, void* l) {
  __builtin_amdgcn_global_load_lds(
      (const __attribute__((address_space(1))) uint32_t*)g,
      (__attribute__((address_space(3))) uint32_t*)l, 16, 0, 0);
}

// ---------------- kernels ----------------

// fp32 -> bf16 bulk convert
__global__ __launch_bounds__(256) void k_tobf(const float* __restrict__ X,
                                              unsigned short* __restrict__ Y) {
  size_t i = ((size_t)blockIdx.x * 256 + threadIdx.x) * 4;
  float4 v = *(const float4*)&X[i];
  ushort4 o = {f2bf(v.x), f2bf(v.y), f2bf(v.z), f2bf(v.w)};
  *(ushort4*)&Y[i] = o;
}

// Aggregation (bf16 in -> bf16 out), XCD-swizzled slabs.
__global__ void k_agg_bf(const unsigned short* __restrict__ X,
                         const int* __restrict__ csr,
                         const int* __restrict__ ptr,
                         const int* __restrict__ cnt,
                         unsigned short* __restrict__ out, int F) {
  int bid = blockIdx.x;
  int slab = gridDim.x >> 3;
  int v = (bid & 7) * slab + (bid >> 3);
  int c = threadIdx.x * 4;
  float degv = 1.0f + (float)cnt[v];
  float dinvv = rsqrtf(degv);
  float inv = 1.0f / degv;
  ushort4 xu = *(const ushort4*)&X[(size_t)v * F + c];
  float4 acc = {bf2f(xu.x) * inv, bf2f(xu.y) * inv, bf2f(xu.z) * inv, bf2f(xu.w) * inv};
  int e0 = ptr[v], e1 = ptr[v + 1];
  for (int e = e0; e < e1; ++e) {
    int s = csr[e];
    float w = dinvv * rsqrtf(1.0f + (float)cnt[s]);
    ushort4 xs = *(const ushort4*)&X[(size_t)s * F + c];
    acc.x += bf2f(xs.x) * w; acc.y += bf2f(xs.y) * w;
    acc.z += bf2f(xs.z) * w; acc.w += bf2f(xs.w) * w;
  }
  ushort4 o = {f2bf(acc.x), f2bf(acc.y), f2bf(acc.z), f2bf(acc.w)};
  *(ushort4*)&out[(size_t)v * F + c] = o;
}

// W [K][N] fp32 -> Wt [N][K] bf16
__global__ __launch_bounds__(256) void k_wt(const float* __restrict__ W,
                                            unsigned short* __restrict__ Wt,
                                            int K, int N) {
  __shared__ float t[32][33];
  int k0 = blockIdx.y * 32, n0 = blockIdx.x * 32;
  int tx = threadIdx.x, ty = threadIdx.y;
  for (int i = ty; i < 32; i += 8)
    t[i][tx] = W[(size_t)(k0 + i) * N + n0 + tx];
  __syncthreads();
  for (int i = ty; i < 32; i += 8)
    Wt[(size_t)(n0 + i) * K + k0 + tx] = f2bf(t[tx][i]);
}

// bf16 MFMA GEMM: 256(m) x 128(n) tile, BK=32, 512 threads = 8 waves (4x2).
// bf16 C out, fused per-column sum/sumsq, XCD-banded m-tiles.
__global__ __launch_bounds__(512) void k_gemm_bf(const unsigned short* __restrict__ A,
                                                 const unsigned short* __restrict__ Bt,
                                                 const float* __restrict__ bias,
                                                 unsigned short* __restrict__ C,
                                                 float* __restrict__ bn,
                                                 int M, int N, int K) {
  __shared__ unsigned short sA[256 * 32];   // 16 KiB
  __shared__ unsigned short sB[128 * 32];   // 8 KiB
  const int tid = threadIdx.x;
  const int lane = tid & 63;
  const int w = tid >> 6;               // 0..7
  const int wy = w >> 1, wx = w & 1;    // 4x2 wave grid (wy: 64-row band, wx: 64-col band)
  // --- XCD-aware remap: each XCD owns a contiguous m-band, iterates n fast ---
  int lin = blockIdx.y * gridDim.x + blockIdx.x;
  int nt = gridDim.x;
  int mchunk = gridDim.y >> 3;
  int xcd = lin & 7;
  int idx = lin >> 3;
  int mtile = xcd * mchunk + idx / nt;
  int ntile = idx % nt;
  const int gm = mtile * 256, gn = ntile * 128;

  const int m_l = lane & 15, kq = lane >> 4;
  const int srow = lane >> 2;           // 16 rows per load inst
  const int sseg = (lane & 3) * 8;      // 16B k-segment

  f32x4 acc[4][4] = {};

  for (int k0 = 0; k0 < K; k0 += 32) {
    __syncthreads();
    // A-tile: 256 rows; wave w stages rows w*32 .. w*32+31 (2 insts)
#pragma unroll
    for (int i = 0; i < 2; ++i) {
      int row = w * 32 + i * 16 + srow;
      load_lds16(&A[(size_t)(gm + row) * K + k0 + sseg],
                 (void*)&sA[(size_t)(w * 32 + i * 16) * 32 + (size_t)lane * 8]);
    }
    // B-tile: 128 rows; wave w stages rows w*16 .. w*16+15 (1 inst)
    {
      int row = w * 16 + srow;
      load_lds16(&Bt[(size_t)(gn + row) * K + k0 + sseg],
                 (void*)&sB[(size_t)(w * 16) * 32 + (size_t)lane * 8]);
    }
    __syncthreads();

    short8 af[4], bfr[4];
#pragma unroll
    for (int mi = 0; mi < 4; ++mi)
      af[mi] = *(const short8*)&sA[(size_t)(wy * 64 + mi * 16 + m_l) * 32 + kq * 8];
#pragma unroll
    for (int ni = 0; ni < 4; ++ni)
      bfr[ni] = *(const short8*)&sB[(size_t)(wx * 64 + ni * 16 + m_l) * 32 + kq * 8];
#pragma unroll
    for (int mi = 0; mi < 4; ++mi)
#pragma unroll
      for (int ni = 0; ni < 4; ++ni)
        acc[mi][ni] = __builtin_amdgcn_mfma_f32_16x16x32_bf16(af[mi], bfr[ni], acc[mi][ni], 0, 0, 0);
  }

  const int r0 = kq * 4;   // C/D: col = lane&15, row = (lane>>4)*4 + reg
#pragma unroll
  for (int ni = 0; ni < 4; ++ni) {
    int col = gn + wx * 64 + ni * 16 + m_l;
    float bv = bias[col];
    float s = 0.f, s2 = 0.f;
#pragma unroll
    for (int mi = 0; mi < 4; ++mi) {
      int rowb = gm + wy * 64 + mi * 16 + r0;
#pragma unroll
      for (int r = 0; r < 4; ++r) {
        float v = acc[mi][ni][r] + bv;
        C[(size_t)(rowb + r) * N + col] = f2bf(v);
        s += v; s2 += v * v;
      }
    }
    s += __shfl_xor(s, 16, 64);  s2 += __shfl_xor(s2, 16, 64);
    s += __shfl_xor(s, 32, 64);  s2 += __shfl_xor(s2, 32, 64);
    if (kq == 0) {
      atomicAdd(&bn[col], s);
      atomicAdd(&bn[N + col], s2);
    }
  }
}

__global__ void k_pnorm(const float* __restrict__ p1, const float* __restrict__ p2,
                        float* __restrict__ pn) {
  __shared__ float red[256];
  const float* p = (blockIdx.x == 0) ? p1 : p2;
  int t = threadIdx.x;
  float s = 0.f;
  for (int i = t; i < H_; i += 256) s += p[i] * p[i];
  red[t] = s; __syncthreads();
  for (int st = 128; st > 0; st >>= 1) { if (t < st) red[t] += red[t + st]; __syncthreads(); }
  if (t == 0) pn[blockIdx.x] = sqrtf(red[0]);
}

__global__ void k_count(const int* __restrict__ dst, int* __restrict__ cnt) {
  int e = blockIdx.x * 256 + threadIdx.x;
  atomicAdd(&cnt[dst[e]], 1);
}

__global__ void k_count2(const int* __restrict__ src, const int* __restrict__ dst,
                         const int* __restrict__ nid, int* __restrict__ cnt) {
  int e = blockIdx.x * 256 + threadIdx.x;
  int s = nid[src[e]], d = nid[dst[e]];
  if (s >= 0 && d >= 0) atomicAdd(&cnt[d], 1);
}

// single-block exclusive scan of cnt[n] -> ptr[n+1]; n divisible by 1024
__global__ __launch_bounds__(1024) void k_scan(const int* __restrict__ cnt,
                                               int* __restrict__ ptr, int n) {
  __shared__ int sums[1024];
  int t = threadIdx.x;
  int chunk = n / 1024;
  int base = t * chunk;
  int s = 0;
  for (int i = 0; i < chunk; ++i) s += cnt[base + i];
  sums[t] = s; __syncthreads();
  for (int off = 1; off < 1024; off <<= 1) {
    int v = (t >= off) ? sums[t - off] : 0;
    __syncthreads();
    sums[t] += v;
    __syncthreads();
  }
  int run = (t == 0) ? 0 : sums[t - 1];
  for (int i = 0; i < chunk; ++i) { ptr[base + i] = run; run += cnt[base + i]; }
  if (t == 1023) ptr[n] = run;
}

__global__ void k_fill(const int* __restrict__ src, const int* __restrict__ dst,
                       const int* __restrict__ ptr, int* __restrict__ fill,
                       int* __restrict__ csr) {
  int e = blockIdx.x * 256 + threadIdx.x;
  int d = dst[e];
  int pos = ptr[d] + atomicAdd(&fill[d], 1);
  csr[pos] = src[e];
}

__global__ void k_fill2(const int* __restrict__ src, const int* __restrict__ dst,
                        const int* __restrict__ nid, const int* __restrict__ ptr,
                        int* __restrict__ fill, int* __restrict__ csr) {
  int e = blockIdx.x * 256 + threadIdx.x;
  int s = nid[src[e]], d = nid[dst[e]];
  if (s >= 0 && d >= 0) {
    int pos = ptr[d] + atomicAdd(&fill[d], 1);
    csr[pos] = s;
  }
}

__global__ void k_bn_finalize(float* __restrict__ bn, const float* __restrict__ g,
                              const float* __restrict__ be, float inv_n) {
  int c = blockIdx.x * 256 + threadIdx.x;
  float mean = bn[c] * inv_n;
  float var = bn[H_ + c] * inv_n - mean * mean;
  float a = g[c] * rsqrtf(var + EPS_);
  bn[c] = a;
  bn[H_ + c] = be[c] - mean * a;
}

// in-place BN+ReLU on bf16, plus score[v] = tanh(dot(h, p)/||p||)
__global__ __launch_bounds__(256) void k_bn_score(unsigned short* __restrict__ X,
                                                  const float* __restrict__ bn,
                                                  const float* __restrict__ p,
                                                  const float* __restrict__ pnorm,
                                                  float* __restrict__ score) {
  __shared__ float red[256];
  int v = blockIdx.x;
  int t = threadIdx.x;
  int c = t * 4;
  ushort4 xu = *(ushort4*)&X[(size_t)v * H_ + c];
  float4 a = *(const float4*)&bn[c];
  float4 cc = *(const float4*)&bn[H_ + c];
  float hx = fmaxf(bf2f(xu.x) * a.x + cc.x, 0.f);
  float hy = fmaxf(bf2f(xu.y) * a.y + cc.y, 0.f);
  float hz = fmaxf(bf2f(xu.z) * a.z + cc.z, 0.f);
  float hw = fmaxf(bf2f(xu.w) * a.w + cc.w, 0.f);
  ushort4 o = {f2bf(hx), f2bf(hy), f2bf(hz), f2bf(hw)};
  *(ushort4*)&X[(size_t)v * H_ + c] = o;
  float4 p4 = *(const float4*)&p[c];
  red[t] = hx * p4.x + hy * p4.y + hz * p4.z + hw * p4.w;
  __syncthreads();
  for (int s = 128; s > 0; s >>= 1) { if (t < s) red[t] += red[t + s]; __syncthreads(); }
  if (t == 0) score[v] = tanhf(red[0] / pnorm[0]);
}

// per-graph exact descending bitonic sort, one element per thread (blockDim = nper)
__global__ __launch_bounds__(1024) void k_topk(const float* __restrict__ score,
                                               int nper, int k,
                                               int* __restrict__ perm,
                                               float* __restrict__ val,
                                               int* __restrict__ newid) {
  __shared__ float sk[1024];
  __shared__ int si[1024];
  int g = blockIdx.x, t = threadIdx.x;
  sk[t] = score[g * nper + t];
  si[t] = t;
  for (int k2 = 2; k2 <= nper; k2 <<= 1) {
    for (int j = k2 >> 1; j > 0; j >>= 1) {
      __syncthreads();
      int ixj = t ^ j;
      if (ixj > t) {
        float a = sk[t], b = sk[ixj];
        int ia = si[t], ib = si[ixj];
        bool aFirst = (a > b) || (a == b && ia < ib);
        bool dirDesc = ((t & k2) == 0);
        if (dirDesc ? (!aFirst) : aFirst) {
          sk[t] = b; sk[ixj] = a; si[t] = ib; si[ixj] = ia;
        }
      }
    }
  }
  __syncthreads();
  if (t < k) {
    perm[g * k + t] = g * nper + si[t];
    val[g * k + t] = sk[t];
    if (newid) newid[g * nper + si[t]] = g * k + t;
  }
}

// h_new[i] = h[perm[i]] * val[i]   (bf16 -> bf16)
__global__ __launch_bounds__(256) void k_pool(const unsigned short* __restrict__ Hm,
                                              const int* __restrict__ perm,
                                              const float* __restrict__ val,
                                              unsigned short* __restrict__ out) {
  int i = blockIdx.x;
  int c = threadIdx.x * 4;
  int old = perm[i];
  float vv = val[i];
  ushort4 xu = *(const ushort4*)&Hm[(size_t)old * H_ + c];
  ushort4 o = {f2bf(bf2f(xu.x) * vv), f2bf(bf2f(xu.y) * vv),
               f2bf(bf2f(xu.z) * vv), f2bf(bf2f(xu.w) * vv)};
  *(ushort4*)&out[(size_t)i * H_ + c] = o;
}

// partial column-mean (bf16 in), z-split; out pre-zeroed fp32
__global__ __launch_bounds__(256) void k_mean(const unsigned short* __restrict__ X,
                                              float* __restrict__ out,
                                              int k, int rows_per_blk) {
  int g = blockIdx.x;
  int col = blockIdx.y * 256 + threadIdx.x;
  int j0 = blockIdx.z * rows_per_blk;
  float s = 0.f;
  for (int j = j0; j < j0 + rows_per_blk; ++j)
    s += bf2f(X[(size_t)(g * k + j) * H_ + col]);
  atomicAdd(&out[g * H_ + col], s / (float)k);
}

// partial scaled column-mean (gathered bf16 rows), z-split; out pre-zeroed
__global__ __launch_bounds__(256) void k_mean_scaled(const unsigned short* __restrict__ X,
                                                     const int* __restrict__ perm,
                                                     const float* __restrict__ val,
                                                     float* __restrict__ out,
                                                     int k, int rows_per_blk) {
  int g = blockIdx.x;
  int col = blockIdx.y * 256 + threadIdx.x;
  int j0 = blockIdx.z * rows_per_blk;
  float s = 0.f;
  for (int j = j0; j < j0 + rows_per_blk; ++j) {
    int r = perm[g * k + j];
    s += val[g * k + j] * bf2f(X[(size_t)r * H_ + col]);
  }
  atomicAdd(&out[g * H_ + col], s / (float)k);
}

// fused head: t = x1+x2 ; z = relu(t@Wf + bf) ; out = z@Wf1 + bf1
__global__ __launch_bounds__(512) void k_head(const float* __restrict__ x1,
                                              const float* __restrict__ x2,
                                              const float* __restrict__ Wf,
                                              const float* __restrict__ bf,
                                              const float* __restrict__ Wf1,
                                              const float* __restrict__ bf1,
                                              float* __restrict__ out) {
  __shared__ float tv[H_];
  __shared__ float zs[512];
  __shared__ float red[512];
  int g = blockIdx.x, t = threadIdx.x;
  for (int i = t; i < H_; i += 512) tv[i] = x1[g * H_ + i] + x2[g * H_ + i];
  __syncthreads();
  float acc = bf[t];
  for (int k = 0; k < H_; ++k) acc += tv[k] * Wf[(size_t)k * 512 + t];
  zs[t] = fmaxf(acc, 0.f);
  __syncthreads();
  for (int o = 0; o < OUT_; ++o) {
    red[t] = zs[t] * Wf1[t * OUT_ + o];
    __syncthreads();
    for (int s = 256; s > 0; s >>= 1) { if (t < s) red[t] += red[t + s]; __syncthreads(); }
    if (t == 0) out[g * OUT_ + o] = red[0] + bf1[o];
    __syncthreads();
  }
}

// ---------------- launch ----------------
extern "C" void kernel_launch(void* const* d_in, const int* in_sizes, int n_in,
                              void* d_out, int out_size, void* d_ws, size_t ws_size,
                              hipStream_t stream) {
  (void)in_sizes; (void)n_in; (void)out_size; (void)ws_size;
  const float* x   = (const float*)d_in[0];
  const int*   ei  = (const int*)d_in[1];
  const float* W1  = (const float*)d_in[3];
  const float* b1  = (const float*)d_in[4];
  const float* g1  = (const float*)d_in[5];
  const float* be1 = (const float*)d_in[6];
  const float* p1  = (const float*)d_in[7];
  const float* W2  = (const float*)d_in[8];
  const float* b2  = (const float*)d_in[9];
  const float* g2  = (const float*)d_in[10];
  const float* be2 = (const float*)d_in[11];
  const float* p2  = (const float*)d_in[12];
  const float* Wf  = (const float*)d_in[13];
  const float* bf  = (const float*)d_in[14];
  const float* Wf1 = (const float*)d_in[15];
  const float* bf1 = (const float*)d_in[16];
  const int* srcv = ei;
  const int* dstv = ei + E_;

  char* ws = (char*)d_ws;
  unsigned short* conv1 = (unsigned short*)(ws + OFF_CONV1);
  unsigned short* xagg  = (unsigned short*)(ws + OFF_XAGG);
  unsigned short* hagg2 = (unsigned short*)(ws + OFF_XAGG);  // aliases xagg (dead by then)
  unsigned short* hpool = (unsigned short*)(ws + OFF_HPOOL);
  unsigned short* conv2 = (unsigned short*)(ws + OFF_CONV2);
  unsigned short* xbf   = (unsigned short*)(ws + OFF_XBF);
  int* cnt1    = (int*)(ws + OFF_CNT1);
  int* fill1   = (int*)(ws + OFF_FILL1);
  int* cnt2    = (int*)(ws + OFF_CNT2);
  int* fill2   = (int*)(ws + OFF_FILL2);
  float* bn1   = (float*)(ws + OFF_BN1);
  float* bn2   = (float*)(ws + OFF_BN2);
  int* ptr1    = (int*)(ws + OFF_PTR1);
  int* ptr2    = (int*)(ws + OFF_PTR2);
  int* csr1    = (int*)(ws + OFF_CSR1);
  int* csr2    = (int*)(ws + OFF_CSR2);
  float* sc1   = (float*)(ws + OFF_SC1);
  float* sc2   = (float*)(ws + OFF_SC2);
  int* perm1   = (int*)(ws + OFF_PERM1);
  float* val1  = (float*)(ws + OFF_VAL1);
  int* perm2   = (int*)(ws + OFF_PERM2);
  float* val2  = (float*)(ws + OFF_VAL2);
  int* newid1  = (int*)(ws + OFF_NEWID);
  float* pnorm = (float*)(ws + OFF_PNORM);
  float* x1    = (float*)(ws + OFF_X1);
  float* x2    = (float*)(ws + OFF_X2);
  unsigned short* Wt1 = (unsigned short*)(ws + OFF_WT1);
  unsigned short* Wt2 = (unsigned short*)(ws + OFF_WT2);

  hipMemsetAsync(ws + ZERO_BASE, 0, ZERO_BYTES, stream);
  hipMemsetAsync(ws + OFF_NEWID, 0xFF, (size_t)NN1_ * 4, stream);  // new_id = -1

  k_pnorm<<<2, 256, 0, stream>>>(p1, p2, pnorm);
  k_wt<<<dim3(H_ / 32, FIN_ / 32), dim3(32, 8), 0, stream>>>(W1, Wt1, FIN_, H_);
  k_wt<<<dim3(H_ / 32, H_ / 32), dim3(32, 8), 0, stream>>>(W2, Wt2, H_, H_);
  k_tobf<<<(NN1_ * FIN_) / 1024, 256, 0, stream>>>(x, xbf);

  // ---- stage 1 ----
  k_count<<<E_ / 256, 256, 0, stream>>>(dstv, cnt1);
  k_scan<<<1, 1024, 0, stream>>>(cnt1, ptr1, NN1_);
  k_fill<<<E_ / 256, 256, 0, stream>>>(srcv, dstv, ptr1, fill1, csr1);
  k_agg_bf<<<NN1_, FIN_ / 4, 0, stream>>>(xbf, csr1, ptr1, cnt1, xagg, FIN_);
  k_gemm_bf<<<dim3(H_ / 128, NN1_ / 256), 512, 0, stream>>>(xagg, Wt1, b1, conv1, bn1, NN1_, H_, FIN_);
  k_bn_finalize<<<H_ / 256, 256, 0, stream>>>(bn1, g1, be1, 1.0f / (float)NN1_);
  k_bn_score<<<NN1_, 256, 0, stream>>>(conv1, bn1, p1, pnorm + 0, sc1);
  k_topk<<<B_, N_, 0, stream>>>(sc1, N_, K1_, perm1, val1, newid1);
  k_pool<<<NN2_, 256, 0, stream>>>(conv1, perm1, val1, hpool);
  k_mean<<<dim3(B_, H_ / 256, 8), 256, 0, stream>>>(hpool, x1, K1_, K1_ / 8);

  // ---- stage 2 ----
  k_count2<<<E_ / 256, 256, 0, stream>>>(srcv, dstv, newid1, cnt2);
  k_scan<<<1, 1024, 0, stream>>>(cnt2, ptr2, NN2_);
  k_fill2<<<E_ / 256, 256, 0, stream>>>(srcv, dstv, newid1, ptr2, fill2, csr2);
  k_agg_bf<<<NN2_, H_ / 4, 0, stream>>>(hpool, csr2, ptr2, cnt2, hagg2, H_);
  k_gemm_bf<<<dim3(H_ / 128, NN2_ / 256), 512, 0, stream>>>(hagg2, Wt2, b2, conv2, bn2, NN2_, H_, H_);
  k_bn_finalize<<<H_ / 256, 256, 0, stream>>>(bn2, g2, be2, 1.0f / (float)NN2_);
  k_bn_score<<<NN2_, 256, 0, stream>>>(conv2, bn2, p2, pnorm + 1, sc2);
  k_topk<<<B_, K1_, 0, stream>>>(sc2, K1_, K2_, perm2, val2, nullptr);
  k_mean_scaled<<<dim3(B_, H_ / 256, 4), 256, 0, stream>>>(conv2, perm2, val2, x2, K2_, K2_ / 4);

  // ---- head ----
  k_head<<<B_, 512, 0, stream>>>(x1, x2, Wf, bf, Wf1, bf1, (float*)d_out);
}

// Round 8
// 555.029 us; speedup vs baseline: 2.8889x; 1.0293x over previous
//
#include <hip/hip_runtime.h>
#include <hip/hip_bf16.h>
#include <cstdint>
#include <cstddef>

// Problem constants (from reference)
#define B_    32
#define N_    1024
#define DEG_  8
#define FIN_  512
#define H_    1024
#define OUT_  10
#define E_    (B_ * N_ * DEG_)   // 262144
#define NN1_  (B_ * N_)          // 32768
#define K1_   (N_ / 2)           // 512
#define NN2_  (B_ * K1_)         // 16384
#define K2_   (N_ / 4)           // 256
#define EPS_  1e-5f

// ---------------- workspace layout (bytes) ----------------
constexpr size_t OFF_CONV1 = 0;                                   // NN1 x H bf16 (64 MiB)
constexpr size_t OFF_XAGG  = OFF_CONV1 + (size_t)NN1_ * H_ * 2;   // NN1 x FIN bf16 (32 MiB); stage2: hagg2
constexpr size_t OFF_HPOOL = OFF_XAGG + (size_t)NN1_ * FIN_ * 2;  // NN2 x H bf16 (32 MiB)
constexpr size_t OFF_CONV2 = OFF_HPOOL + (size_t)NN2_ * H_ * 2;   // NN2 x H bf16 (32 MiB)
constexpr size_t OFF_CNT1  = OFF_CONV2 + (size_t)NN2_ * H_ * 2;   // NN1 ints (zeroed)
constexpr size_t OFF_FILL1 = OFF_CNT1 + (size_t)NN1_ * 4;
constexpr size_t OFF_CNT2  = OFF_FILL1 + (size_t)NN1_ * 4;
constexpr size_t OFF_FILL2 = OFF_CNT2 + (size_t)NN2_ * 4;
constexpr size_t OFF_BN1   = OFF_FILL2 + (size_t)NN2_ * 4;        // 2H floats (zeroed)
constexpr size_t OFF_BN2   = OFF_BN1 + (size_t)2 * H_ * 4;
constexpr size_t OFF_X1    = OFF_BN2 + (size_t)2 * H_ * 4;        // B*H floats (zeroed)
constexpr size_t OFF_X2    = OFF_X1 + (size_t)B_ * H_ * 4;
constexpr size_t ZERO_BASE = OFF_CNT1;
constexpr size_t ZERO_BYTES = OFF_X2 + (size_t)B_ * H_ * 4 - ZERO_BASE;
constexpr size_t OFF_PTR1  = OFF_X2 + (size_t)B_ * H_ * 4;
constexpr size_t OFF_PTR2  = OFF_PTR1 + (size_t)(NN1_ + 64) * 4;
constexpr size_t OFF_CSR1  = OFF_PTR2 + (size_t)(NN2_ + 64) * 4;
constexpr size_t OFF_CSR2  = OFF_CSR1 + (size_t)E_ * 4;
constexpr size_t OFF_SC1   = OFF_CSR2 + (size_t)E_ * 4;
constexpr size_t OFF_SC2   = OFF_SC1 + (size_t)NN1_ * 4;
constexpr size_t OFF_PERM1 = OFF_SC2 + (size_t)NN2_ * 4;
constexpr size_t OFF_VAL1  = OFF_PERM1 + (size_t)NN2_ * 4;
constexpr size_t OFF_PERM2 = OFF_VAL1 + (size_t)NN2_ * 4;
constexpr size_t OFF_VAL2  = OFF_PERM2 + (size_t)(B_ * K2_) * 4;
constexpr size_t OFF_NEWID = OFF_VAL2 + (size_t)(B_ * K2_) * 4;   // NN1 ints (0xFF)
constexpr size_t OFF_PNORM = OFF_NEWID + (size_t)NN1_ * 4;        // padded
constexpr size_t OFF_WT1   = OFF_PNORM + 256;                     // H*FIN bf16
constexpr size_t OFF_WT2   = OFF_WT1 + (size_t)H_ * FIN_ * 2;     // H*H bf16
constexpr size_t OFF_XBF   = OFF_WT2 + (size_t)H_ * H_ * 2;       // NN1 x FIN bf16 (32 MiB)
// total ≈ 231 MiB

// ---------------- helpers ----------------
typedef short short8 __attribute__((ext_vector_type(8)));
typedef float f32x4 __attribute__((ext_vector_type(4)));

__device__ inline unsigned short f2bf(float f) {
  uint32_t u = __float_as_uint(f);
  u += 0x7fffu + ((u >> 16) & 1u);   // RNE
  return (unsigned short)(u >> 16);
}
__device__ inline float bf2f(unsigned short u) {
  return __uint_as_float(((uint32_t)u) << 16);
}

__device__ inline void load_lds16(const void* g, void* l) {
  __builtin_amdgcn_global_load_lds(
      (const __attribute__((address_space(1))) uint32_t*)g,
      (__attribute__((address_space(3))) uint32_t*)l, 16, 0, 0);
}

// ---------------- kernels ----------------

// fp32 -> bf16 bulk convert
__global__ __launch_bounds__(256) void k_tobf(const float* __restrict__ X,
                                              unsigned short* __restrict__ Y) {
  size_t i = ((size_t)blockIdx.x * 256 + threadIdx.x) * 4;
  float4 v = *(const float4*)&X[i];
  ushort4 o = {f2bf(v.x), f2bf(v.y), f2bf(v.z), f2bf(v.w)};
  *(ushort4*)&Y[i] = o;
}

// Aggregation (bf16 in -> bf16 out), XCD-swizzled slabs.
__global__ void k_agg_bf(const unsigned short* __restrict__ X,
                         const int* __restrict__ csr,
                         const int* __restrict__ ptr,
                         const int* __restrict__ cnt,
                         unsigned short* __restrict__ out, int F) {
  int bid = blockIdx.x;
  int slab = gridDim.x >> 3;
  int v = (bid & 7) * slab + (bid >> 3);
  int c = threadIdx.x * 4;
  float degv = 1.0f + (float)cnt[v];
  float dinvv = rsqrtf(degv);
  float inv = 1.0f / degv;
  ushort4 xu = *(const ushort4*)&X[(size_t)v * F + c];
  float4 acc = {bf2f(xu.x) * inv, bf2f(xu.y) * inv, bf2f(xu.z) * inv, bf2f(xu.w) * inv};
  int e0 = ptr[v], e1 = ptr[v + 1];
  for (int e = e0; e < e1; ++e) {
    int s = csr[e];
    float w = dinvv * rsqrtf(1.0f + (float)cnt[s]);
    ushort4 xs = *(const ushort4*)&X[(size_t)s * F + c];
    acc.x += bf2f(xs.x) * w; acc.y += bf2f(xs.y) * w;
    acc.z += bf2f(xs.z) * w; acc.w += bf2f(xs.w) * w;
  }
  ushort4 o = {f2bf(acc.x), f2bf(acc.y), f2bf(acc.z), f2bf(acc.w)};
  *(ushort4*)&out[(size_t)v * F + c] = o;
}

// W [K][N] fp32 -> Wt [N][K] bf16
__global__ __launch_bounds__(256) void k_wt(const float* __restrict__ W,
                                            unsigned short* __restrict__ Wt,
                                            int K, int N) {
  __shared__ float t[32][33];
  int k0 = blockIdx.y * 32, n0 = blockIdx.x * 32;
  int tx = threadIdx.x, ty = threadIdx.y;
  for (int i = ty; i < 32; i += 8)
    t[i][tx] = W[(size_t)(k0 + i) * N + n0 + tx];
  __syncthreads();
  for (int i = ty; i < 32; i += 8)
    Wt[(size_t)(n0 + i) * K + k0 + tx] = f2bf(t[tx][i]);
}

// bf16 MFMA GEMM: 256(m) x 128(n) tile, BK=32, 512 threads = 8 waves (4x2).
// bf16 C out via LDS-staged coalesced stores; fused per-column sum/sumsq;
// XCD-banded m-tiles.
__global__ __launch_bounds__(512) void k_gemm_bf(const unsigned short* __restrict__ A,
                                                 const unsigned short* __restrict__ Bt,
                                                 const float* __restrict__ bias,
                                                 unsigned short* __restrict__ C,
                                                 float* __restrict__ bn,
                                                 int M, int N, int K) {
  __shared__ __align__(16) char smem[128 * 136 * 2];   // 34 KiB (>= 24 KiB K-loop use)
  unsigned short* sA  = (unsigned short*)smem;          // 256x32 = 16 KiB
  unsigned short* sB  = (unsigned short*)(smem + 256 * 32 * 2);  // 128x32 = 8 KiB
  unsigned short* epi = (unsigned short*)smem;          // 128x136 bf16 (epilogue)

  const int tid = threadIdx.x;
  const int lane = tid & 63;
  const int w = tid >> 6;               // 0..7
  const int wy = w >> 1, wx = w & 1;    // 4x2 wave grid
  // --- XCD-aware remap: each XCD owns a contiguous m-band, iterates n fast ---
  int lin = blockIdx.y * gridDim.x + blockIdx.x;
  int nt = gridDim.x;
  int mchunk = gridDim.y >> 3;
  int xcd = lin & 7;
  int idx = lin >> 3;
  int mtile = xcd * mchunk + idx / nt;
  int ntile = idx % nt;
  const int gm = mtile * 256, gn = ntile * 128;

  const int m_l = lane & 15, kq = lane >> 4;
  const int srow = lane >> 2;           // 16 rows per load inst
  const int sseg = (lane & 3) * 8;      // 16B k-segment

  f32x4 acc[4][4] = {};

  for (int k0 = 0; k0 < K; k0 += 32) {
    __syncthreads();
#pragma unroll
    for (int i = 0; i < 2; ++i) {
      int row = w * 32 + i * 16 + srow;
      load_lds16(&A[(size_t)(gm + row) * K + k0 + sseg],
                 (void*)&sA[(size_t)(w * 32 + i * 16) * 32 + (size_t)lane * 8]);
    }
    {
      int row = w * 16 + srow;
      load_lds16(&Bt[(size_t)(gn + row) * K + k0 + sseg],
                 (void*)&sB[(size_t)(w * 16) * 32 + (size_t)lane * 8]);
    }
    __syncthreads();

    short8 af[4], bfr[4];
#pragma unroll
    for (int mi = 0; mi < 4; ++mi)
      af[mi] = *(const short8*)&sA[(size_t)(wy * 64 + mi * 16 + m_l) * 32 + kq * 8];
#pragma unroll
    for (int ni = 0; ni < 4; ++ni)
      bfr[ni] = *(const short8*)&sB[(size_t)(wx * 64 + ni * 16 + m_l) * 32 + kq * 8];
#pragma unroll
    for (int mi = 0; mi < 4; ++mi)
#pragma unroll
      for (int ni = 0; ni < 4; ++ni)
        acc[mi][ni] = __builtin_amdgcn_mfma_f32_16x16x32_bf16(af[mi], bfr[ni], acc[mi][ni], 0, 0, 0);
  }

  const int r0 = kq * 4;   // C/D: col = lane&15, row = (lane>>4)*4 + reg
  float bvv[4];
#pragma unroll
  for (int ni = 0; ni < 4; ++ni) {
    int col = gn + wx * 64 + ni * 16 + m_l;
    bvv[ni] = bias[col];
    float s = 0.f, s2 = 0.f;
#pragma unroll
    for (int mi = 0; mi < 4; ++mi)
#pragma unroll
      for (int r = 0; r < 4; ++r) {
        float v = acc[mi][ni][r] + bvv[ni];
        s += v; s2 += v * v;
      }
    s += __shfl_xor(s, 16, 64);  s2 += __shfl_xor(s2, 16, 64);
    s += __shfl_xor(s, 32, 64);  s2 += __shfl_xor(s2, 32, 64);
    if (kq == 0) {
      atomicAdd(&bn[col], s);
      atomicAdd(&bn[N + col], s2);
    }
  }

  // two-phase LDS-staged coalesced C write (rows gm+p*128 .. +127)
#pragma unroll
  for (int p = 0; p < 2; ++p) {
    __syncthreads();
    if ((wy >> 1) == p) {
      int lr = (wy & 1) * 64;
#pragma unroll
      for (int ni = 0; ni < 4; ++ni) {
        int lcol = wx * 64 + ni * 16 + m_l;
#pragma unroll
        for (int mi = 0; mi < 4; ++mi)
#pragma unroll
          for (int r = 0; r < 4; ++r)
            epi[(size_t)(lr + mi * 16 + r0 + r) * 136 + lcol] = f2bf(acc[mi][ni][r] + bvv[ni]);
      }
    }
    __syncthreads();
#pragma unroll
    for (int i = 0; i < 4; ++i) {
      int cch = tid + i * 512;          // 0..2047
      int row = cch >> 4, seg = cch & 15;
      uint4 v = *(const uint4*)&epi[(size_t)row * 136 + seg * 8];
      *(uint4*)&C[(size_t)(gm + p * 128 + row) * N + gn + seg * 8] = v;
    }
  }
}

__global__ void k_pnorm(const float* __restrict__ p1, const float* __restrict__ p2,
                        float* __restrict__ pn) {
  __shared__ float red[256];
  const float* p = (blockIdx.x == 0) ? p1 : p2;
  int t = threadIdx.x;
  float s = 0.f;
  for (int i = t; i < H_; i += 256) s += p[i] * p[i];
  red[t] = s; __syncthreads();
  for (int st = 128; st > 0; st >>= 1) { if (t < st) red[t] += red[t + st]; __syncthreads(); }
  if (t == 0) pn[blockIdx.x] = sqrtf(red[0]);
}

__global__ void k_count(const int* __restrict__ dst, int* __restrict__ cnt) {
  int e = blockIdx.x * 256 + threadIdx.x;
  atomicAdd(&cnt[dst[e]], 1);
}

__global__ void k_count2(const int* __restrict__ src, const int* __restrict__ dst,
                         const int* __restrict__ nid, int* __restrict__ cnt) {
  int e = blockIdx.x * 256 + threadIdx.x;
  int s = nid[src[e]], d = nid[dst[e]];
  if (s >= 0 && d >= 0) atomicAdd(&cnt[d], 1);
}

// single-block exclusive scan of cnt[n] -> ptr[n+1]; n divisible by 1024
__global__ __launch_bounds__(1024) void k_scan(const int* __restrict__ cnt,
                                               int* __restrict__ ptr, int n) {
  __shared__ int sums[1024];
  int t = threadIdx.x;
  int chunk = n / 1024;
  int base = t * chunk;
  int s = 0;
  for (int i = 0; i < chunk; ++i) s += cnt[base + i];
  sums[t] = s; __syncthreads();
  for (int off = 1; off < 1024; off <<= 1) {
    int v = (t >= off) ? sums[t - off] : 0;
    __syncthreads();
    sums[t] += v;
    __syncthreads();
  }
  int run = (t == 0) ? 0 : sums[t - 1];
  for (int i = 0; i < chunk; ++i) { ptr[base + i] = run; run += cnt[base + i]; }
  if (t == 1023) ptr[n] = run;
}

__global__ void k_fill(const int* __restrict__ src, const int* __restrict__ dst,
                       const int* __restrict__ ptr, int* __restrict__ fill,
                       int* __restrict__ csr) {
  int e = blockIdx.x * 256 + threadIdx.x;
  int d = dst[e];
  int pos = ptr[d] + atomicAdd(&fill[d], 1);
  csr[pos] = src[e];
}

__global__ void k_fill2(const int* __restrict__ src, const int* __restrict__ dst,
                        const int* __restrict__ nid, const int* __restrict__ ptr,
                        int* __restrict__ fill, int* __restrict__ csr) {
  int e = blockIdx.x * 256 + threadIdx.x;
  int s = nid[src[e]], d = nid[dst[e]];
  if (s >= 0 && d >= 0) {
    int pos = ptr[d] + atomicAdd(&fill[d], 1);
    csr[pos] = s;
  }
}

__global__ void k_bn_finalize(float* __restrict__ bn, const float* __restrict__ g,
                              const float* __restrict__ be, float inv_n) {
  int c = blockIdx.x * 256 + threadIdx.x;
  float mean = bn[c] * inv_n;
  float var = bn[H_ + c] * inv_n - mean * mean;
  float a = g[c] * rsqrtf(var + EPS_);
  bn[c] = a;
  bn[H_ + c] = be[c] - mean * a;
}

// score[v] = tanh(dot(relu(x*a+c), p)/||p||)  -- no h write
__global__ __launch_bounds__(256) void k_score(const unsigned short* __restrict__ X,
                                               const float* __restrict__ bn,
                                               const float* __restrict__ p,
                                               const float* __restrict__ pnorm,
                                               float* __restrict__ score) {
  __shared__ float red[256];
  int v = blockIdx.x;
  int t = threadIdx.x;
  int c = t * 4;
  ushort4 xu = *(const ushort4*)&X[(size_t)v * H_ + c];
  float4 a = *(const float4*)&bn[c];
  float4 cc = *(const float4*)&bn[H_ + c];
  float hx = fmaxf(bf2f(xu.x) * a.x + cc.x, 0.f);
  float hy = fmaxf(bf2f(xu.y) * a.y + cc.y, 0.f);
  float hz = fmaxf(bf2f(xu.z) * a.z + cc.z, 0.f);
  float hw = fmaxf(bf2f(xu.w) * a.w + cc.w, 0.f);
  float4 p4 = *(const float4*)&p[c];
  red[t] = hx * p4.x + hy * p4.y + hz * p4.z + hw * p4.w;
  __syncthreads();
  for (int s = 128; s > 0; s >>= 1) { if (t < s) red[t] += red[t + s]; __syncthreads(); }
  if (t == 0) score[v] = tanhf(red[0] / pnorm[0]);
}

// per-graph exact descending bitonic sort, one element per thread (blockDim = nper)
__global__ __launch_bounds__(1024) void k_topk(const float* __restrict__ score,
                                               int nper, int k,
                                               int* __restrict__ perm,
                                               float* __restrict__ val,
                                               int* __restrict__ newid) {
  __shared__ float sk[1024];
  __shared__ int si[1024];
  int g = blockIdx.x, t = threadIdx.x;
  sk[t] = score[g * nper + t];
  si[t] = t;
  for (int k2 = 2; k2 <= nper; k2 <<= 1) {
    for (int j = k2 >> 1; j > 0; j >>= 1) {
      __syncthreads();
      int ixj = t ^ j;
      if (ixj > t) {
        float a = sk[t], b = sk[ixj];
        int ia = si[t], ib = si[ixj];
        bool aFirst = (a > b) || (a == b && ia < ib);
        bool dirDesc = ((t & k2) == 0);
        if (dirDesc ? (!aFirst) : aFirst) {
          sk[t] = b; sk[ixj] = a; si[t] = ib; si[ixj] = ia;
        }
      }
    }
  }
  __syncthreads();
  if (t < k) {
    perm[g * k + t] = g * nper + si[t];
    val[g * k + t] = sk[t];
    if (newid) newid[g * nper + si[t]] = g * k + t;
  }
}

// hpool[i] = relu(conv[perm[i]]*a+c) * val[i]   (bf16 -> bf16, BN fused)
__global__ __launch_bounds__(256) void k_pool_bn(const unsigned short* __restrict__ Hm,
                                                 const float* __restrict__ bn,
                                                 const int* __restrict__ perm,
                                                 const float* __restrict__ val,
                                                 unsigned short* __restrict__ out) {
  int i = blockIdx.x;
  int c = threadIdx.x * 4;
  int old = perm[i];
  float vv = val[i];
  ushort4 xu = *(const ushort4*)&Hm[(size_t)old * H_ + c];
  float4 a = *(const float4*)&bn[c];
  float4 cc = *(const float4*)&bn[H_ + c];
  ushort4 o = {f2bf(fmaxf(bf2f(xu.x) * a.x + cc.x, 0.f) * vv),
               f2bf(fmaxf(bf2f(xu.y) * a.y + cc.y, 0.f) * vv),
               f2bf(fmaxf(bf2f(xu.z) * a.z + cc.z, 0.f) * vv),
               f2bf(fmaxf(bf2f(xu.w) * a.w + cc.w, 0.f) * vv)};
  *(ushort4*)&out[(size_t)i * H_ + c] = o;
}

// partial column-mean (bf16 in), z-split; out pre-zeroed fp32
__global__ __launch_bounds__(256) void k_mean(const unsigned short* __restrict__ X,
                                              float* __restrict__ out,
                                              int k, int rows_per_blk) {
  int g = blockIdx.x;
  int col = blockIdx.y * 256 + threadIdx.x;
  int j0 = blockIdx.z * rows_per_blk;
  float s = 0.f;
  for (int j = j0; j < j0 + rows_per_blk; ++j)
    s += bf2f(X[(size_t)(g * k + j) * H_ + col]);
  atomicAdd(&out[g * H_ + col], s / (float)k);
}

// partial scaled column-mean with fused BN+ReLU (gathered bf16 rows), z-split
__global__ __launch_bounds__(256) void k_mean_scaled_bn(const unsigned short* __restrict__ X,
                                                        const float* __restrict__ bn,
                                                        const int* __restrict__ perm,
                                                        const float* __restrict__ val,
                                                        float* __restrict__ out,
                                                        int k, int rows_per_blk) {
  int g = blockIdx.x;
  int col = blockIdx.y * 256 + threadIdx.x;
  int j0 = blockIdx.z * rows_per_blk;
  float a = bn[col], cc = bn[H_ + col];
  float s = 0.f;
  for (int j = j0; j < j0 + rows_per_blk; ++j) {
    int r = perm[g * k + j];
    float h = fmaxf(bf2f(X[(size_t)r * H_ + col]) * a + cc, 0.f);
    s += val[g * k + j] * h;
  }
  atomicAdd(&out[g * H_ + col], s / (float)k);
}

// fused head: t = x1+x2 ; z = relu(t@Wf + bf) ; out = z@Wf1 + bf1
__global__ __launch_bounds__(512) void k_head(const float* __restrict__ x1,
                                              const float* __restrict__ x2,
                                              const float* __restrict__ Wf,
                                              const float* __restrict__ bf,
                                              const float* __restrict__ Wf1,
                                              const float* __restrict__ bf1,
                                              float* __restrict__ out) {
  __shared__ float tv[H_];
  __shared__ float zs[512];
  __shared__ float red[512];
  int g = blockIdx.x, t = threadIdx.x;
  for (int i = t; i < H_; i += 512) tv[i] = x1[g * H_ + i] + x2[g * H_ + i];
  __syncthreads();
  float acc = bf[t];
  for (int k = 0; k < H_; ++k) acc += tv[k] * Wf[(size_t)k * 512 + t];
  zs[t] = fmaxf(acc, 0.f);
  __syncthreads();
  for (int o = 0; o < OUT_; ++o) {
    red[t] = zs[t] * Wf1[t * OUT_ + o];
    __syncthreads();
    for (int s = 256; s > 0; s >>= 1) { if (t < s) red[t] += red[t + s]; __syncthreads(); }
    if (t == 0) out[g * OUT_ + o] = red[0] + bf1[o];
    __syncthreads();
  }
}

// ---------------- launch ----------------
extern "C" void kernel_launch(void* const* d_in, const int* in_sizes, int n_in,
                              void* d_out, int out_size, void* d_ws, size_t ws_size,
                              hipStream_t stream) {
  (void)in_sizes; (void)n_in; (void)out_size; (void)ws_size;
  const float* x   = (const float*)d_in[0];
  const int*   ei  = (const int*)d_in[1];
  const float* W1  = (const float*)d_in[3];
  const float* b1  = (const float*)d_in[4];
  const float* g1  = (const float*)d_in[5];
  const float* be1 = (const float*)d_in[6];
  const float* p1  = (const float*)d_in[7];
  const float* W2  = (const float*)d_in[8];
  const float* b2  = (const float*)d_in[9];
  const float* g2  = (const float*)d_in[10];
  const float* be2 = (const float*)d_in[11];
  const float* p2  = (const float*)d_in[12];
  const float* Wf  = (const float*)d_in[13];
  const float* bf  = (const float*)d_in[14];
  const float* Wf1 = (const float*)d_in[15];
  const float* bf1 = (const float*)d_in[16];
  const int* srcv = ei;
  const int* dstv = ei + E_;

  char* ws = (char*)d_ws;
  unsigned short* conv1 = (unsigned short*)(ws + OFF_CONV1);
  unsigned short* xagg  = (unsigned short*)(ws + OFF_XAGG);
  unsigned short* hagg2 = (unsigned short*)(ws + OFF_XAGG);  // aliases xagg (dead by then)
  unsigned short* hpool = (unsigned short*)(ws + OFF_HPOOL);
  unsigned short* conv2 = (unsigned short*)(ws + OFF_CONV2);
  unsigned short* xbf   = (unsigned short*)(ws + OFF_XBF);
  int* cnt1    = (int*)(ws + OFF_CNT1);
  int* fill1   = (int*)(ws + OFF_FILL1);
  int* cnt2    = (int*)(ws + OFF_CNT2);
  int* fill2   = (int*)(ws + OFF_FILL2);
  float* bn1   = (float*)(ws + OFF_BN1);
  float* bn2   = (float*)(ws + OFF_BN2);
  int* ptr1    = (int*)(ws + OFF_PTR1);
  int* ptr2    = (int*)(ws + OFF_PTR2);
  int* csr1    = (int*)(ws + OFF_CSR1);
  int* csr2    = (int*)(ws + OFF_CSR2);
  float* sc1   = (float*)(ws + OFF_SC1);
  float* sc2   = (float*)(ws + OFF_SC2);
  int* perm1   = (int*)(ws + OFF_PERM1);
  float* val1  = (float*)(ws + OFF_VAL1);
  int* perm2   = (int*)(ws + OFF_PERM2);
  float* val2  = (float*)(ws + OFF_VAL2);
  int* newid1  = (int*)(ws + OFF_NEWID);
  float* pnorm = (float*)(ws + OFF_PNORM);
  float* x1    = (float*)(ws + OFF_X1);
  float* x2    = (float*)(ws + OFF_X2);
  unsigned short* Wt1 = (unsigned short*)(ws + OFF_WT1);
  unsigned short* Wt2 = (unsigned short*)(ws + OFF_WT2);

  hipMemsetAsync(ws + ZERO_BASE, 0, ZERO_BYTES, stream);
  hipMemsetAsync(ws + OFF_NEWID, 0xFF, (size_t)NN1_ * 4, stream);  // new_id = -1

  k_pnorm<<<2, 256, 0, stream>>>(p1, p2, pnorm);
  k_wt<<<dim3(H_ / 32, FIN_ / 32), dim3(32, 8), 0, stream>>>(W1, Wt1, FIN_, H_);
  k_wt<<<dim3(H_ / 32, H_ / 32), dim3(32, 8), 0, stream>>>(W2, Wt2, H_, H_);
  k_tobf<<<(NN1_ * FIN_) / 1024, 256, 0, stream>>>(x, xbf);

  // ---- stage 1 ----
  k_count<<<E_ / 256, 256, 0, stream>>>(dstv, cnt1);
  k_scan<<<1, 1024, 0, stream>>>(cnt1, ptr1, NN1_);
  k_fill<<<E_ / 256, 256, 0, stream>>>(srcv, dstv, ptr1, fill1, csr1);
  k_agg_bf<<<NN1_, FIN_ / 4, 0, stream>>>(xbf, csr1, ptr1, cnt1, xagg, FIN_);
  k_gemm_bf<<<dim3(H_ / 128, NN1_ / 256), 512, 0, stream>>>(xagg, Wt1, b1, conv1, bn1, NN1_, H_, FIN_);
  k_bn_finalize<<<H_ / 256, 256, 0, stream>>>(bn1, g1, be1, 1.0f / (float)NN1_);
  k_score<<<NN1_, 256, 0, stream>>>(conv1, bn1, p1, pnorm + 0, sc1);
  k_topk<<<B_, N_, 0, stream>>>(sc1, N_, K1_, perm1, val1, newid1);
  k_pool_bn<<<NN2_, 256, 0, stream>>>(conv1, bn1, perm1, val1, hpool);
  k_mean<<<dim3(B_, H_ / 256, 8), 256, 0, stream>>>(hpool, x1, K1_, K1_ / 8);

  // ---- stage 2 ----
  k_count2<<<E_ / 256, 256, 0, stream>>>(srcv, dstv, newid1, cnt2);
  k_scan<<<1, 1024, 0, stream>>>(cnt2, ptr2, NN2_);
  k_fill2<<<E_ / 256, 256, 0, stream>>>(srcv, dstv, newid1, ptr2, fill2, csr2);
  k_agg_bf<<<NN2_, H_ / 4, 0, stream>>>(hpool, csr2, ptr2, cnt2, hagg2, H_);
  k_gemm_bf<<<dim3(H_ / 128, NN2_ / 256), 512, 0, stream>>>(hagg2, Wt2, b2, conv2, bn2, NN2_, H_, H_);
  k_bn_finalize<<<H_ / 256, 256, 0, stream>>>(bn2, g2, be2, 1.0f / (float)NN2_);
  k_score<<<NN2_, 256, 0, stream>>>(conv2, bn2, p2, pnorm + 1, sc2);
  k_topk<<<B_, K1_, 0, stream>>>(sc2, K1_, K2_, perm2, val2, nullptr);
  k_mean_scaled_bn<<<dim3(B_, H_ / 256, 4), 256, 0, stream>>>(conv2, bn2, perm2, val2, x2, K2_, K2_ / 4);

  // ---- head ----
  k_head<<<B_, 512, 0, stream>>>(x1, x2, Wf, bf, Wf1, bf1, (float*)d_out);
}

// Round 9
// 529.029 us; speedup vs baseline: 3.0309x; 1.0491x over previous
//
#include <hip/hip_runtime.h>
#include <hip/hip_bf16.h>
#include <cstdint>
#include <cstddef>

// Problem constants (from reference)
#define B_    32
#define N_    1024
#define DEG_  8
#define FIN_  512
#define H_    1024
#define OUT_  10
#define E_    (B_ * N_ * DEG_)   // 262144
#define NN1_  (B_ * N_)          // 32768
#define K1_   (N_ / 2)           // 512
#define NN2_  (B_ * K1_)         // 16384
#define K2_   (N_ / 4)           // 256
#define EPS_  1e-5f

// ---------------- workspace layout (bytes) ----------------
constexpr size_t OFF_CONV1 = 0;                                   // NN1 x H bf16 (64 MiB)
constexpr size_t OFF_XAGG  = OFF_CONV1 + (size_t)NN1_ * H_ * 2;   // NN1 x FIN bf16; stage2: hagg2
constexpr size_t OFF_HPOOL = OFF_XAGG + (size_t)NN1_ * FIN_ * 2;  // NN2 x H bf16
constexpr size_t OFF_CONV2 = OFF_HPOOL + (size_t)NN2_ * H_ * 2;   // NN2 x H bf16
constexpr size_t OFF_CNT1  = OFF_CONV2 + (size_t)NN2_ * H_ * 2;   // NN1 ints (zeroed)
constexpr size_t OFF_FILL1 = OFF_CNT1 + (size_t)NN1_ * 4;
constexpr size_t OFF_CNT2  = OFF_FILL1 + (size_t)NN1_ * 4;
constexpr size_t OFF_FILL2 = OFF_CNT2 + (size_t)NN2_ * 4;
constexpr size_t OFF_BN1   = OFF_FILL2 + (size_t)NN2_ * 4;        // 2H floats raw sums (zeroed)
constexpr size_t OFF_BN2   = OFF_BN1 + (size_t)2 * H_ * 4;
constexpr size_t OFF_X1    = OFF_BN2 + (size_t)2 * H_ * 4;        // B*H floats (zeroed)
constexpr size_t OFF_X2    = OFF_X1 + (size_t)B_ * H_ * 4;
constexpr size_t OFF_ZWS   = OFF_X2 + (size_t)B_ * H_ * 4;        // B*512 floats (zeroed)
constexpr size_t ZERO_BASE = OFF_CNT1;
constexpr size_t ZERO_BYTES = OFF_ZWS + (size_t)B_ * 512 * 4 - ZERO_BASE;
constexpr size_t OFF_PTR1  = OFF_ZWS + (size_t)B_ * 512 * 4;
constexpr size_t OFF_PTR2  = OFF_PTR1 + (size_t)(NN1_ + 64) * 4;
constexpr size_t OFF_CSR1  = OFF_PTR2 + (size_t)(NN2_ + 64) * 4;
constexpr size_t OFF_CSR2  = OFF_CSR1 + (size_t)E_ * 4;
constexpr size_t OFF_SC1   = OFF_CSR2 + (size_t)E_ * 4;
constexpr size_t OFF_SC2   = OFF_SC1 + (size_t)NN1_ * 4;
constexpr size_t OFF_PERM1 = OFF_SC2 + (size_t)NN2_ * 4;
constexpr size_t OFF_VAL1  = OFF_PERM1 + (size_t)NN2_ * 4;
constexpr size_t OFF_PERM2 = OFF_VAL1 + (size_t)NN2_ * 4;
constexpr size_t OFF_VAL2  = OFF_PERM2 + (size_t)(B_ * K2_) * 4;
constexpr size_t OFF_NEWID = OFF_VAL2 + (size_t)(B_ * K2_) * 4;   // NN1 ints (0xFF)
constexpr size_t OFF_PNORM = OFF_NEWID + (size_t)NN1_ * 4;        // padded
constexpr size_t OFF_WT1   = OFF_PNORM + 256;                     // H*FIN bf16
constexpr size_t OFF_WT2   = OFF_WT1 + (size_t)H_ * FIN_ * 2;     // H*H bf16
constexpr size_t OFF_XBF   = OFF_WT2 + (size_t)H_ * H_ * 2;       // NN1 x FIN bf16
// total ≈ 231 MiB

// ---------------- helpers ----------------
typedef short short8 __attribute__((ext_vector_type(8)));
typedef float f32x4 __attribute__((ext_vector_type(4)));

__device__ inline unsigned short f2bf(float f) {
  uint32_t u = __float_as_uint(f);
  u += 0x7fffu + ((u >> 16) & 1u);   // RNE
  return (unsigned short)(u >> 16);
}
__device__ inline float bf2f(unsigned short u) {
  return __uint_as_float(((uint32_t)u) << 16);
}

__device__ inline void load_lds16(const void* g, void* l) {
  __builtin_amdgcn_global_load_lds(
      (const __attribute__((address_space(1))) uint32_t*)g,
      (__attribute__((address_space(3))) uint32_t*)l, 16, 0, 0);
}

// bn affine from raw sums: a = g*rsqrt(var+eps), c = be - mean*a
__device__ inline void bn_affine(float sum, float sumsq, float g, float be,
                                 float inv_n, float& a, float& c) {
  float mean = sum * inv_n;
  float var = sumsq * inv_n - mean * mean;
  a = g * rsqrtf(var + EPS_);
  c = be - mean * a;
}

// ---------------- kernels ----------------

// Fused prep: tobf [0,16384) | count [16384,17408) | wt1 [17408,17920)
//             wt2 [17920,18944) | pnorm [18944,18946)
#define PREP_BLOCKS 18946
__global__ __launch_bounds__(256) void k_prep(const float* __restrict__ x,
                                              const int* __restrict__ dstv,
                                              const float* __restrict__ W1,
                                              const float* __restrict__ W2,
                                              const float* __restrict__ p1,
                                              const float* __restrict__ p2,
                                              unsigned short* __restrict__ xbf,
                                              int* __restrict__ cnt,
                                              unsigned short* __restrict__ Wt1,
                                              unsigned short* __restrict__ Wt2,
                                              float* __restrict__ pn) {
  __shared__ float sh[32][33];
  __shared__ float red[256];
  int bid = blockIdx.x, t = threadIdx.x;
  if (bid < 16384) {                      // fp32 -> bf16 convert of x
    size_t i = ((size_t)bid * 256 + t) * 4;
    float4 v = *(const float4*)&x[i];
    ushort4 o = {f2bf(v.x), f2bf(v.y), f2bf(v.z), f2bf(v.w)};
    *(ushort4*)&xbf[i] = o;
  } else if (bid < 17408) {               // edge dst count
    int e = (bid - 16384) * 256 + t;
    atomicAdd(&cnt[dstv[e]], 1);
  } else if (bid < 18944) {               // weight transpose -> bf16
    const float* W; unsigned short* Wt; int K, N, r;
    if (bid < 17920) { W = W1; Wt = Wt1; K = FIN_; N = H_; r = bid - 17408; }
    else             { W = W2; Wt = Wt2; K = H_;   N = H_; r = bid - 17920; }
    int bx = r & 31, by = r >> 5;
    int k0 = by * 32, n0 = bx * 32;
    int tx = t & 31, ty = t >> 5;
    for (int i = ty; i < 32; i += 8)
      sh[i][tx] = W[(size_t)(k0 + i) * N + n0 + tx];
    __syncthreads();
    for (int i = ty; i < 32; i += 8)
      Wt[(size_t)(n0 + i) * K + k0 + tx] = f2bf(sh[tx][i]);
  } else {                                // pnorm
    const float* p = (bid == 18944) ? p1 : p2;
    float s = 0.f;
    for (int i = t; i < H_; i += 256) s += p[i] * p[i];
    red[t] = s; __syncthreads();
    for (int st = 128; st > 0; st >>= 1) { if (t < st) red[t] += red[t + st]; __syncthreads(); }
    if (t == 0) pn[bid - 18944] = sqrtf(red[0]);
  }
}

// Aggregation (bf16 in -> bf16 out), XCD-swizzled slabs.
__global__ void k_agg_bf(const unsigned short* __restrict__ X,
                         const int* __restrict__ csr,
                         const int* __restrict__ ptr,
                         const int* __restrict__ cnt,
                         unsigned short* __restrict__ out, int F) {
  int bid = blockIdx.x;
  int slab = gridDim.x >> 3;
  int v = (bid & 7) * slab + (bid >> 3);
  int c = threadIdx.x * 4;
  float degv = 1.0f + (float)cnt[v];
  float dinvv = rsqrtf(degv);
  float inv = 1.0f / degv;
  ushort4 xu = *(const ushort4*)&X[(size_t)v * F + c];
  float4 acc = {bf2f(xu.x) * inv, bf2f(xu.y) * inv, bf2f(xu.z) * inv, bf2f(xu.w) * inv};
  int e0 = ptr[v], e1 = ptr[v + 1];
  for (int e = e0; e < e1; ++e) {
    int s = csr[e];
    float w = dinvv * rsqrtf(1.0f + (float)cnt[s]);
    ushort4 xs = *(const ushort4*)&X[(size_t)s * F + c];
    acc.x += bf2f(xs.x) * w; acc.y += bf2f(xs.y) * w;
    acc.z += bf2f(xs.z) * w; acc.w += bf2f(xs.w) * w;
  }
  ushort4 o = {f2bf(acc.x), f2bf(acc.y), f2bf(acc.z), f2bf(acc.w)};
  *(ushort4*)&out[(size_t)v * F + c] = o;
}

// bf16 MFMA GEMM: 256(m) x 128(n) tile, BK=32, 512 threads = 8 waves (4x2).
// bf16 C out via LDS-staged coalesced stores; fused per-column sum/sumsq;
// XCD-banded m-tiles.
__global__ __launch_bounds__(512) void k_gemm_bf(const unsigned short* __restrict__ A,
                                                 const unsigned short* __restrict__ Bt,
                                                 const float* __restrict__ bias,
                                                 unsigned short* __restrict__ C,
                                                 float* __restrict__ bn,
                                                 int M, int N, int K) {
  __shared__ __align__(16) char smem[128 * 136 * 2];   // 34 KiB
  unsigned short* sA  = (unsigned short*)smem;          // 256x32
  unsigned short* sB  = (unsigned short*)(smem + 256 * 32 * 2);  // 128x32
  unsigned short* epi = (unsigned short*)smem;          // 128x136 (epilogue)

  const int tid = threadIdx.x;
  const int lane = tid & 63;
  const int w = tid >> 6;
  const int wy = w >> 1, wx = w & 1;
  int lin = blockIdx.y * gridDim.x + blockIdx.x;
  int nt = gridDim.x;
  int mchunk = gridDim.y >> 3;
  int xcd = lin & 7;
  int idx = lin >> 3;
  int mtile = xcd * mchunk + idx / nt;
  int ntile = idx % nt;
  const int gm = mtile * 256, gn = ntile * 128;

  const int m_l = lane & 15, kq = lane >> 4;
  const int srow = lane >> 2;
  const int sseg = (lane & 3) * 8;

  f32x4 acc[4][4] = {};

  for (int k0 = 0; k0 < K; k0 += 32) {
    __syncthreads();
#pragma unroll
    for (int i = 0; i < 2; ++i) {
      int row = w * 32 + i * 16 + srow;
      load_lds16(&A[(size_t)(gm + row) * K + k0 + sseg],
                 (void*)&sA[(size_t)(w * 32 + i * 16) * 32 + (size_t)lane * 8]);
    }
    {
      int row = w * 16 + srow;
      load_lds16(&Bt[(size_t)(gn + row) * K + k0 + sseg],
                 (void*)&sB[(size_t)(w * 16) * 32 + (size_t)lane * 8]);
    }
    __syncthreads();

    short8 af[4], bfr[4];
#pragma unroll
    for (int mi = 0; mi < 4; ++mi)
      af[mi] = *(const short8*)&sA[(size_t)(wy * 64 + mi * 16 + m_l) * 32 + kq * 8];
#pragma unroll
    for (int ni = 0; ni < 4; ++ni)
      bfr[ni] = *(const short8*)&sB[(size_t)(wx * 64 + ni * 16 + m_l) * 32 + kq * 8];
#pragma unroll
    for (int mi = 0; mi < 4; ++mi)
#pragma unroll
      for (int ni = 0; ni < 4; ++ni)
        acc[mi][ni] = __builtin_amdgcn_mfma_f32_16x16x32_bf16(af[mi], bfr[ni], acc[mi][ni], 0, 0, 0);
  }

  const int r0 = kq * 4;   // C/D: col = lane&15, row = (lane>>4)*4 + reg
  float bvv[4];
#pragma unroll
  for (int ni = 0; ni < 4; ++ni) {
    int col = gn + wx * 64 + ni * 16 + m_l;
    bvv[ni] = bias[col];
    float s = 0.f, s2 = 0.f;
#pragma unroll
    for (int mi = 0; mi < 4; ++mi)
#pragma unroll
      for (int r = 0; r < 4; ++r) {
        float v = acc[mi][ni][r] + bvv[ni];
        s += v; s2 += v * v;
      }
    s += __shfl_xor(s, 16, 64);  s2 += __shfl_xor(s2, 16, 64);
    s += __shfl_xor(s, 32, 64);  s2 += __shfl_xor(s2, 32, 64);
    if (kq == 0) {
      atomicAdd(&bn[col], s);
      atomicAdd(&bn[N + col], s2);
    }
  }

  // two-phase LDS-staged coalesced C write
#pragma unroll
  for (int p = 0; p < 2; ++p) {
    __syncthreads();
    if ((wy >> 1) == p) {
      int lr = (wy & 1) * 64;
#pragma unroll
      for (int ni = 0; ni < 4; ++ni) {
        int lcol = wx * 64 + ni * 16 + m_l;
#pragma unroll
        for (int mi = 0; mi < 4; ++mi)
#pragma unroll
          for (int r = 0; r < 4; ++r)
            epi[(size_t)(lr + mi * 16 + r0 + r) * 136 + lcol] = f2bf(acc[mi][ni][r] + bvv[ni]);
      }
    }
    __syncthreads();
#pragma unroll
    for (int i = 0; i < 4; ++i) {
      int cch = tid + i * 512;
      int row = cch >> 4, seg = cch & 15;
      uint4 v = *(const uint4*)&epi[(size_t)row * 136 + seg * 8];
      *(uint4*)&C[(size_t)(gm + p * 128 + row) * N + gn + seg * 8] = v;
    }
  }
}

__global__ void k_count2(const int* __restrict__ src, const int* __restrict__ dst,
                         const int* __restrict__ nid, int* __restrict__ cnt) {
  int e = blockIdx.x * 256 + threadIdx.x;
  int s = nid[src[e]], d = nid[dst[e]];
  if (s >= 0 && d >= 0) atomicAdd(&cnt[d], 1);
}

// single-block exclusive scan of cnt[n] -> ptr[n+1]; n divisible by 1024
__global__ __launch_bounds__(1024) void k_scan(const int* __restrict__ cnt,
                                               int* __restrict__ ptr, int n) {
  __shared__ int sums[1024];
  int t = threadIdx.x;
  int chunk = n / 1024;
  int base = t * chunk;
  int s = 0;
  for (int i = 0; i < chunk; ++i) s += cnt[base + i];
  sums[t] = s; __syncthreads();
  for (int off = 1; off < 1024; off <<= 1) {
    int v = (t >= off) ? sums[t - off] : 0;
    __syncthreads();
    sums[t] += v;
    __syncthreads();
  }
  int run = (t == 0) ? 0 : sums[t - 1];
  for (int i = 0; i < chunk; ++i) { ptr[base + i] = run; run += cnt[base + i]; }
  if (t == 1023) ptr[n] = run;
}

__global__ void k_fill(const int* __restrict__ src, const int* __restrict__ dst,
                       const int* __restrict__ ptr, int* __restrict__ fill,
                       int* __restrict__ csr) {
  int e = blockIdx.x * 256 + threadIdx.x;
  int d = dst[e];
  int pos = ptr[d] + atomicAdd(&fill[d], 1);
  csr[pos] = src[e];
}

__global__ void k_fill2(const int* __restrict__ src, const int* __restrict__ dst,
                        const int* __restrict__ nid, const int* __restrict__ ptr,
                        int* __restrict__ fill, int* __restrict__ csr) {
  int e = blockIdx.x * 256 + threadIdx.x;
  int s = nid[src[e]], d = nid[dst[e]];
  if (s >= 0 && d >= 0) {
    int pos = ptr[d] + atomicAdd(&fill[d], 1);
    csr[pos] = s;
  }
}

// score[v] = tanh(dot(relu(x*a+c), p)/||p||); bn affine computed from raw sums
__global__ __launch_bounds__(256) void k_score(const unsigned short* __restrict__ X,
                                               const float* __restrict__ bnsum,
                                               const float* __restrict__ gam,
                                               const float* __restrict__ bet,
                                               float inv_n,
                                               const float* __restrict__ p,
                                               const float* __restrict__ pnorm,
                                               float* __restrict__ score) {
  __shared__ float wred[4];
  int v = blockIdx.x;
  int t = threadIdx.x;
  int c = t * 4;
  float4 sm = *(const float4*)&bnsum[c];
  float4 sq = *(const float4*)&bnsum[H_ + c];
  float4 gg = *(const float4*)&gam[c];
  float4 bb = *(const float4*)&bet[c];
  float a0, c0, a1, c1, a2, c2, a3, c3;
  bn_affine(sm.x, sq.x, gg.x, bb.x, inv_n, a0, c0);
  bn_affine(sm.y, sq.y, gg.y, bb.y, inv_n, a1, c1);
  bn_affine(sm.z, sq.z, gg.z, bb.z, inv_n, a2, c2);
  bn_affine(sm.w, sq.w, gg.w, bb.w, inv_n, a3, c3);
  ushort4 xu = *(const ushort4*)&X[(size_t)v * H_ + c];
  float hx = fmaxf(bf2f(xu.x) * a0 + c0, 0.f);
  float hy = fmaxf(bf2f(xu.y) * a1 + c1, 0.f);
  float hz = fmaxf(bf2f(xu.z) * a2 + c2, 0.f);
  float hw = fmaxf(bf2f(xu.w) * a3 + c3, 0.f);
  float4 p4 = *(const float4*)&p[c];
  float s = hx * p4.x + hy * p4.y + hz * p4.z + hw * p4.w;
#pragma unroll
  for (int off = 1; off < 64; off <<= 1) s += __shfl_xor(s, off, 64);
  if ((t & 63) == 0) wred[t >> 6] = s;
  __syncthreads();
  if (t == 0) score[v] = tanhf((wred[0] + wred[1] + wred[2] + wred[3]) / pnorm[0]);
}

// per-graph exact descending bitonic sort (tie: smaller index first), 256 threads
__global__ __launch_bounds__(256) void k_topk(const float* __restrict__ score,
                                              int nper, int k,
                                              int* __restrict__ perm,
                                              float* __restrict__ val,
                                              int* __restrict__ newid) {
  __shared__ float sk[1024];
  __shared__ int si[1024];
  int g = blockIdx.x, t = threadIdx.x;
  for (int i = t; i < nper; i += 256) { sk[i] = score[g * nper + i]; si[i] = i; }
  __syncthreads();
  int pairs = nper >> 1;
  for (int k2 = 2; k2 <= nper; k2 <<= 1) {
    for (int j = k2 >> 1; j > 0; j >>= 1) {
      for (int p = t; p < pairs; p += 256) {
        int i = ((p & ~(j - 1)) << 1) | (p & (j - 1));
        int ix = i | j;
        float a = sk[i], b = sk[ix];
        int ia = si[i], ib = si[ix];
        bool aFirst = (a > b) || (a == b && ia < ib);
        bool dirDesc = ((i & k2) == 0);
        if (dirDesc ? (!aFirst) : aFirst) {
          sk[i] = b; sk[ix] = a; si[i] = ib; si[ix] = ia;
        }
      }
      __syncthreads();
    }
  }
  for (int i = t; i < k; i += 256) {
    perm[g * k + i] = g * nper + si[i];
    val[g * k + i] = sk[i];
    if (newid) newid[g * nper + si[i]] = g * k + i;
  }
}

// hpool[i] = relu(conv[perm[i]]*a+c) * val[i]   (bf16 -> bf16, BN fused from raw sums)
__global__ __launch_bounds__(256) void k_pool_bn(const unsigned short* __restrict__ Hm,
                                                 const float* __restrict__ bnsum,
                                                 const float* __restrict__ gam,
                                                 const float* __restrict__ bet,
                                                 float inv_n,
                                                 const int* __restrict__ perm,
                                                 const float* __restrict__ val,
                                                 unsigned short* __restrict__ out) {
  int i = blockIdx.x;
  int c = threadIdx.x * 4;
  int old = perm[i];
  float vv = val[i];
  float4 sm = *(const float4*)&bnsum[c];
  float4 sq = *(const float4*)&bnsum[H_ + c];
  float4 gg = *(const float4*)&gam[c];
  float4 bb = *(const float4*)&bet[c];
  float a0, c0, a1, c1, a2, c2, a3, c3;
  bn_affine(sm.x, sq.x, gg.x, bb.x, inv_n, a0, c0);
  bn_affine(sm.y, sq.y, gg.y, bb.y, inv_n, a1, c1);
  bn_affine(sm.z, sq.z, gg.z, bb.z, inv_n, a2, c2);
  bn_affine(sm.w, sq.w, gg.w, bb.w, inv_n, a3, c3);
  ushort4 xu = *(const ushort4*)&Hm[(size_t)old * H_ + c];
  ushort4 o = {f2bf(fmaxf(bf2f(xu.x) * a0 + c0, 0.f) * vv),
               f2bf(fmaxf(bf2f(xu.y) * a1 + c1, 0.f) * vv),
               f2bf(fmaxf(bf2f(xu.z) * a2 + c2, 0.f) * vv),
               f2bf(fmaxf(bf2f(xu.w) * a3 + c3, 0.f) * vv)};
  *(ushort4*)&out[(size_t)i * H_ + c] = o;
}

// partial column-mean (bf16 in), z-split; out pre-zeroed fp32
__global__ __launch_bounds__(256) void k_mean(const unsigned short* __restrict__ X,
                                              float* __restrict__ out,
                                              int k, int rows_per_blk) {
  int g = blockIdx.x;
  int col = blockIdx.y * 256 + threadIdx.x;
  int j0 = blockIdx.z * rows_per_blk;
  float s = 0.f;
  for (int j = j0; j < j0 + rows_per_blk; ++j)
    s += bf2f(X[(size_t)(g * k + j) * H_ + col]);
  atomicAdd(&out[g * H_ + col], s / (float)k);
}

// partial scaled column-mean with fused BN+ReLU, z-split; out pre-zeroed
__global__ __launch_bounds__(256) void k_mean_scaled_bn(const unsigned short* __restrict__ X,
                                                        const float* __restrict__ bnsum,
                                                        const float* __restrict__ gam,
                                                        const float* __restrict__ bet,
                                                        float inv_n,
                                                        const int* __restrict__ perm,
                                                        const float* __restrict__ val,
                                                        float* __restrict__ out,
                                                        int k, int rows_per_blk) {
  int g = blockIdx.x;
  int col = blockIdx.y * 256 + threadIdx.x;
  int j0 = blockIdx.z * rows_per_blk;
  float a, cc;
  bn_affine(bnsum[col], bnsum[H_ + col], gam[col], bet[col], inv_n, a, cc);
  float s = 0.f;
  for (int j = j0; j < j0 + rows_per_blk; ++j) {
    int r = perm[g * k + j];
    float h = fmaxf(bf2f(X[(size_t)r * H_ + col]) * a + cc, 0.f);
    s += val[g * k + j] * h;
  }
  atomicAdd(&out[g * H_ + col], s / (float)k);
}

// head part 1: zws[g,t] += sum_{k in z-chunk} (x1+x2)[g,k] * Wf[k,t]
__global__ __launch_bounds__(512) void k_head1(const float* __restrict__ x1,
                                               const float* __restrict__ x2,
                                               const float* __restrict__ Wf,
                                               float* __restrict__ zws) {
  __shared__ float tv[128];
  int g = blockIdx.x, z = blockIdx.y, t = threadIdx.x;
  int k0 = z * 128;
  if (t < 128) tv[t] = x1[g * H_ + k0 + t] + x2[g * H_ + k0 + t];
  __syncthreads();
  float acc = 0.f;
#pragma unroll 8
  for (int k = 0; k < 128; ++k) acc += tv[k] * Wf[(size_t)(k0 + k) * 512 + t];
  atomicAdd(&zws[g * 512 + t], acc);
}

// head part 2: z = relu(zws+bf); out = z@Wf1 + bf1
__global__ __launch_bounds__(512) void k_head2(const float* __restrict__ zws,
                                               const float* __restrict__ bf,
                                               const float* __restrict__ Wf1,
                                               const float* __restrict__ bf1,
                                               float* __restrict__ out) {
  __shared__ float red[512];
  int g = blockIdx.x, t = threadIdx.x;
  float zv = fmaxf(zws[g * 512 + t] + bf[t], 0.f);
  for (int o = 0; o < OUT_; ++o) {
    red[t] = zv * Wf1[t * OUT_ + o];
    __syncthreads();
    for (int s = 256; s > 0; s >>= 1) { if (t < s) red[t] += red[t + s]; __syncthreads(); }
    if (t == 0) out[g * OUT_ + o] = red[0] + bf1[o];
    __syncthreads();
  }
}

// ---------------- launch ----------------
extern "C" void kernel_launch(void* const* d_in, const int* in_sizes, int n_in,
                              void* d_out, int out_size, void* d_ws, size_t ws_size,
                              hipStream_t stream) {
  (void)in_sizes; (void)n_in; (void)out_size; (void)ws_size;
  const float* x   = (const float*)d_in[0];
  const int*   ei  = (const int*)d_in[1];
  const float* W1  = (const float*)d_in[3];
  const float* b1  = (const float*)d_in[4];
  const float* g1  = (const float*)d_in[5];
  const float* be1 = (const float*)d_in[6];
  const float* p1  = (const float*)d_in[7];
  const float* W2  = (const float*)d_in[8];
  const float* b2  = (const float*)d_in[9];
  const float* g2  = (const float*)d_in[10];
  const float* be2 = (const float*)d_in[11];
  const float* p2  = (const float*)d_in[12];
  const float* Wf  = (const float*)d_in[13];
  const float* bf  = (const float*)d_in[14];
  const float* Wf1 = (const float*)d_in[15];
  const float* bf1 = (const float*)d_in[16];
  const int* srcv = ei;
  const int* dstv = ei + E_;

  char* ws = (char*)d_ws;
  unsigned short* conv1 = (unsigned short*)(ws + OFF_CONV1);
  unsigned short* xagg  = (unsigned short*)(ws + OFF_XAGG);
  unsigned short* hagg2 = (unsigned short*)(ws + OFF_XAGG);  // aliases xagg (dead by then)
  unsigned short* hpool = (unsigned short*)(ws + OFF_HPOOL);
  unsigned short* conv2 = (unsigned short*)(ws + OFF_CONV2);
  unsigned short* xbf   = (unsigned short*)(ws + OFF_XBF);
  int* cnt1    = (int*)(ws + OFF_CNT1);
  int* fill1   = (int*)(ws + OFF_FILL1);
  int* cnt2    = (int*)(ws + OFF_CNT2);
  int* fill2   = (int*)(ws + OFF_FILL2);
  float* bn1   = (float*)(ws + OFF_BN1);
  float* bn2   = (float*)(ws + OFF_BN2);
  int* ptr1    = (int*)(ws + OFF_PTR1);
  int* ptr2    = (int*)(ws + OFF_PTR2);
  int* csr1    = (int*)(ws + OFF_CSR1);
  int* csr2    = (int*)(ws + OFF_CSR2);
  float* sc1   = (float*)(ws + OFF_SC1);
  float* sc2   = (float*)(ws + OFF_SC2);
  int* perm1   = (int*)(ws + OFF_PERM1);
  float* val1  = (float*)(ws + OFF_VAL1);
  int* perm2   = (int*)(ws + OFF_PERM2);
  float* val2  = (float*)(ws + OFF_VAL2);
  int* newid1  = (int*)(ws + OFF_NEWID);
  float* pnorm = (float*)(ws + OFF_PNORM);
  float* x1    = (float*)(ws + OFF_X1);
  float* x2    = (float*)(ws + OFF_X2);
  float* zws   = (float*)(ws + OFF_ZWS);
  unsigned short* Wt1 = (unsigned short*)(ws + OFF_WT1);
  unsigned short* Wt2 = (unsigned short*)(ws + OFF_WT2);

  hipMemsetAsync(ws + ZERO_BASE, 0, ZERO_BYTES, stream);
  hipMemsetAsync(ws + OFF_NEWID, 0xFF, (size_t)NN1_ * 4, stream);  // new_id = -1

  // fused prep: x->bf16, dst count, W1^T, W2^T, pnorms
  k_prep<<<PREP_BLOCKS, 256, 0, stream>>>(x, dstv, W1, W2, p1, p2,
                                          xbf, cnt1, Wt1, Wt2, pnorm);

  // ---- stage 1 ----
  k_scan<<<1, 1024, 0, stream>>>(cnt1, ptr1, NN1_);
  k_fill<<<E_ / 256, 256, 0, stream>>>(srcv, dstv, ptr1, fill1, csr1);
  k_agg_bf<<<NN1_, FIN_ / 4, 0, stream>>>(xbf, csr1, ptr1, cnt1, xagg, FIN_);
  k_gemm_bf<<<dim3(H_ / 128, NN1_ / 256), 512, 0, stream>>>(xagg, Wt1, b1, conv1, bn1, NN1_, H_, FIN_);
  k_score<<<NN1_, 256, 0, stream>>>(conv1, bn1, g1, be1, 1.0f / (float)NN1_, p1, pnorm + 0, sc1);
  k_topk<<<B_, 256, 0, stream>>>(sc1, N_, K1_, perm1, val1, newid1);
  k_pool_bn<<<NN2_, 256, 0, stream>>>(conv1, bn1, g1, be1, 1.0f / (float)NN1_, perm1, val1, hpool);
  k_mean<<<dim3(B_, H_ / 256, 8), 256, 0, stream>>>(hpool, x1, K1_, K1_ / 8);

  // ---- stage 2 ----
  k_count2<<<E_ / 256, 256, 0, stream>>>(srcv, dstv, newid1, cnt2);
  k_scan<<<1, 1024, 0, stream>>>(cnt2, ptr2, NN2_);
  k_fill2<<<E_ / 256, 256, 0, stream>>>(srcv, dstv, newid1, ptr2, fill2, csr2);
  k_agg_bf<<<NN2_, H_ / 4, 0, stream>>>(hpool, csr2, ptr2, cnt2, hagg2, H_);
  k_gemm_bf<<<dim3(H_ / 128, NN2_ / 256), 512, 0, stream>>>(hagg2, Wt2, b2, conv2, bn2, NN2_, H_, H_);
  k_score<<<NN2_, 256, 0, stream>>>(conv2, bn2, g2, be2, 1.0f / (float)NN2_, p2, pnorm + 1, sc2);
  k_topk<<<B_, 256, 0, stream>>>(sc2, K1_, K2_, perm2, val2, nullptr);
  k_mean_scaled_bn<<<dim3(B_, H_ / 256, 4), 256, 0, stream>>>(conv2, bn2, g2, be2, 1.0f / (float)NN2_,
                                                              perm2, val2, x2, K2_, K2_ / 4);

  // ---- head ----
  k_head1<<<dim3(B_, 8), 512, 0, stream>>>(x1, x2, Wf, zws);
  k_head2<<<B_, 512, 0, stream>>>(zws, bf, Wf1, bf1, (float*)d_out);
}

// Round 10
// 512.445 us; speedup vs baseline: 3.1290x; 1.0324x over previous
//
#include <hip/hip_runtime.h>
#include <hip/hip_bf16.h>
#include <cstdint>
#include <cstddef>

// Problem constants (from reference)
#define B_    32
#define N_    1024
#define DEG_  8
#define FIN_  512
#define H_    1024
#define OUT_  10
#define E_    (B_ * N_ * DEG_)   // 262144
#define NN1_  (B_ * N_)          // 32768
#define K1_   (N_ / 2)           // 512
#define NN2_  (B_ * K1_)         // 16384
#define K2_   (N_ / 4)           // 256
#define EPS_  1e-5f

// ---------------- workspace layout (bytes) ----------------
constexpr size_t OFF_CONV1 = 0;                                   // NN1 x H bf16 (64 MiB)
constexpr size_t OFF_XAGG  = OFF_CONV1 + (size_t)NN1_ * H_ * 2;   // NN1 x FIN bf16; stage2: hagg2
constexpr size_t OFF_HPOOL = OFF_XAGG + (size_t)NN1_ * FIN_ * 2;  // NN2 x H bf16
constexpr size_t OFF_CONV2 = OFF_HPOOL + (size_t)NN2_ * H_ * 2;   // NN2 x H bf16
constexpr size_t OFF_CNT1  = OFF_CONV2 + (size_t)NN2_ * H_ * 2;   // NN1 ints (zeroed)
constexpr size_t OFF_FILL1 = OFF_CNT1 + (size_t)NN1_ * 4;
constexpr size_t OFF_CNT2  = OFF_FILL1 + (size_t)NN1_ * 4;
constexpr size_t OFF_FILL2 = OFF_CNT2 + (size_t)NN2_ * 4;
constexpr size_t OFF_BN1   = OFF_FILL2 + (size_t)NN2_ * 4;        // 2H floats raw sums (zeroed)
constexpr size_t OFF_BN2   = OFF_BN1 + (size_t)2 * H_ * 4;
constexpr size_t OFF_X1    = OFF_BN2 + (size_t)2 * H_ * 4;        // B*H floats (zeroed)
constexpr size_t OFF_X2    = OFF_X1 + (size_t)B_ * H_ * 4;
constexpr size_t OFF_ZWS   = OFF_X2 + (size_t)B_ * H_ * 4;        // B*512 floats (zeroed)
constexpr size_t ZERO_BASE = OFF_CNT1;
constexpr size_t ZERO_BYTES = OFF_ZWS + (size_t)B_ * 512 * 4 - ZERO_BASE;
constexpr size_t OFF_PTR1  = OFF_ZWS + (size_t)B_ * 512 * 4;
constexpr size_t OFF_PTR2  = OFF_PTR1 + (size_t)(NN1_ + 64) * 4;
constexpr size_t OFF_CSR1  = OFF_PTR2 + (size_t)(NN2_ + 64) * 4;
constexpr size_t OFF_CSR2  = OFF_CSR1 + (size_t)E_ * 4;
constexpr size_t OFF_SC1   = OFF_CSR2 + (size_t)E_ * 4;
constexpr size_t OFF_SC2   = OFF_SC1 + (size_t)NN1_ * 4;
constexpr size_t OFF_PERM1 = OFF_SC2 + (size_t)NN2_ * 4;
constexpr size_t OFF_VAL1  = OFF_PERM1 + (size_t)NN2_ * 4;
constexpr size_t OFF_PERM2 = OFF_VAL1 + (size_t)NN2_ * 4;
constexpr size_t OFF_VAL2  = OFF_PERM2 + (size_t)(B_ * K2_) * 4;
constexpr size_t OFF_NEWID = OFF_VAL2 + (size_t)(B_ * K2_) * 4;   // NN1 ints (0xFF)
constexpr size_t OFF_PNORM = OFF_NEWID + (size_t)NN1_ * 4;        // padded
constexpr size_t OFF_WT1   = OFF_PNORM + 256;                     // H*FIN bf16
constexpr size_t OFF_WT2   = OFF_WT1 + (size_t)H_ * FIN_ * 2;     // H*H bf16
constexpr size_t OFF_XBF   = OFF_WT2 + (size_t)H_ * H_ * 2;       // NN1 x FIN bf16
// total ≈ 231 MiB

// ---------------- helpers ----------------
typedef short short8 __attribute__((ext_vector_type(8)));
typedef float f32x4 __attribute__((ext_vector_type(4)));

__device__ inline unsigned short f2bf(float f) {
  uint32_t u = __float_as_uint(f);
  u += 0x7fffu + ((u >> 16) & 1u);   // RNE
  return (unsigned short)(u >> 16);
}
__device__ inline float bf2f(unsigned short u) {
  return __uint_as_float(((uint32_t)u) << 16);
}

__device__ inline void load_lds16(const void* g, void* l) {
  __builtin_amdgcn_global_load_lds(
      (const __attribute__((address_space(1))) uint32_t*)g,
      (__attribute__((address_space(3))) uint32_t*)l, 16, 0, 0);
}

// bn affine from raw sums: a = g*rsqrt(var+eps), c = be - mean*a
__device__ inline void bn_affine(float sum, float sumsq, float g, float be,
                                 float inv_n, float& a, float& c) {
  float mean = sum * inv_n;
  float var = sumsq * inv_n - mean * mean;
  a = g * rsqrtf(var + EPS_);
  c = be - mean * a;
}

// ---------------- kernels ----------------

// Fused prep: tobf [0,16384) | count [16384,17408) | wt1 [17408,17920)
//             wt2 [17920,18944) | pnorm [18944,18946)
#define PREP_BLOCKS 18946
__global__ __launch_bounds__(256) void k_prep(const float* __restrict__ x,
                                              const int* __restrict__ dstv,
                                              const float* __restrict__ W1,
                                              const float* __restrict__ W2,
                                              const float* __restrict__ p1,
                                              const float* __restrict__ p2,
                                              unsigned short* __restrict__ xbf,
                                              int* __restrict__ cnt,
                                              unsigned short* __restrict__ Wt1,
                                              unsigned short* __restrict__ Wt2,
                                              float* __restrict__ pn) {
  __shared__ float sh[32][33];
  __shared__ float red[256];
  int bid = blockIdx.x, t = threadIdx.x;
  if (bid < 16384) {                      // fp32 -> bf16 convert of x
    size_t i = ((size_t)bid * 256 + t) * 4;
    float4 v = *(const float4*)&x[i];
    ushort4 o = {f2bf(v.x), f2bf(v.y), f2bf(v.z), f2bf(v.w)};
    *(ushort4*)&xbf[i] = o;
  } else if (bid < 17408) {               // edge dst count
    int e = (bid - 16384) * 256 + t;
    atomicAdd(&cnt[dstv[e]], 1);
  } else if (bid < 18944) {               // weight transpose -> bf16
    const float* W; unsigned short* Wt; int K, N, r;
    if (bid < 17920) { W = W1; Wt = Wt1; K = FIN_; N = H_; r = bid - 17408; }
    else             { W = W2; Wt = Wt2; K = H_;   N = H_; r = bid - 17920; }
    int bx = r & 31, by = r >> 5;
    int k0 = by * 32, n0 = bx * 32;
    int tx = t & 31, ty = t >> 5;
    for (int i = ty; i < 32; i += 8)
      sh[i][tx] = W[(size_t)(k0 + i) * N + n0 + tx];
    __syncthreads();
    for (int i = ty; i < 32; i += 8)
      Wt[(size_t)(n0 + i) * K + k0 + tx] = f2bf(sh[tx][i]);
  } else {                                // pnorm
    const float* p = (bid == 18944) ? p1 : p2;
    float s = 0.f;
    for (int i = t; i < H_; i += 256) s += p[i] * p[i];
    red[t] = s; __syncthreads();
    for (int st = 128; st > 0; st >>= 1) { if (t < st) red[t] += red[t + st]; __syncthreads(); }
    if (t == 0) pn[bid - 18944] = sqrtf(red[0]);
  }
}

// Aggregation (bf16 in -> bf16 out), XCD-swizzled slabs.
__global__ void k_agg_bf(const unsigned short* __restrict__ X,
                         const int* __restrict__ csr,
                         const int* __restrict__ ptr,
                         const int* __restrict__ cnt,
                         unsigned short* __restrict__ out, int F) {
  int bid = blockIdx.x;
  int slab = gridDim.x >> 3;
  int v = (bid & 7) * slab + (bid >> 3);
  int c = threadIdx.x * 4;
  float degv = 1.0f + (float)cnt[v];
  float dinvv = rsqrtf(degv);
  float inv = 1.0f / degv;
  ushort4 xu = *(const ushort4*)&X[(size_t)v * F + c];
  float4 acc = {bf2f(xu.x) * inv, bf2f(xu.y) * inv, bf2f(xu.z) * inv, bf2f(xu.w) * inv};
  int e0 = ptr[v], e1 = ptr[v + 1];
  for (int e = e0; e < e1; ++e) {
    int s = csr[e];
    float w = dinvv * rsqrtf(1.0f + (float)cnt[s]);
    ushort4 xs = *(const ushort4*)&X[(size_t)s * F + c];
    acc.x += bf2f(xs.x) * w; acc.y += bf2f(xs.y) * w;
    acc.z += bf2f(xs.z) * w; acc.w += bf2f(xs.w) * w;
  }
  ushort4 o = {f2bf(acc.x), f2bf(acc.y), f2bf(acc.z), f2bf(acc.w)};
  *(ushort4*)&out[(size_t)v * F + c] = o;
}

// bf16 MFMA GEMM: 256(m) x 128(n) tile, BK=64 (XOR-swizzled segments),
// 512 threads = 8 waves (4x2). bf16 C via LDS-staged coalesced stores;
// fused per-column sum/sumsq; XCD-banded m-tiles.
// Swizzle: LDS segment slot s of row r holds global k-segment (s ^ (r&7));
// ds_read applies inverse: slot = gseg ^ (r&7). Keeps global_load_lds's
// contiguous wave-uniform+lane*16B destination while breaking the 128B-row
// bank alignment that caused R6's 16-way conflicts.
__global__ __launch_bounds__(512) void k_gemm_bf(const unsigned short* __restrict__ A,
                                                 const unsigned short* __restrict__ Bt,
                                                 const float* __restrict__ bias,
                                                 unsigned short* __restrict__ C,
                                                 float* __restrict__ bn,
                                                 int M, int N, int K) {
  __shared__ __align__(16) char smem[49152];            // 48 KiB
  unsigned short* sA  = (unsigned short*)smem;          // 256x64 = 32 KiB
  unsigned short* sB  = (unsigned short*)(smem + 256 * 64 * 2);  // 128x64 = 16 KiB
  unsigned short* epi = (unsigned short*)smem;          // 128x136 (epilogue, 34 KiB)

  const int tid = threadIdx.x;
  const int lane = tid & 63;
  const int w = tid >> 6;
  const int wy = w >> 1, wx = w & 1;
  int lin = blockIdx.y * gridDim.x + blockIdx.x;
  int nt = gridDim.x;
  int mchunk = gridDim.y >> 3;
  int xcd = lin & 7;
  int idx = lin >> 3;
  int mtile = xcd * mchunk + idx / nt;
  int ntile = idx % nt;
  const int gm = mtile * 256, gn = ntile * 128;

  const int m_l = lane & 15, kq = lane >> 4;
  const int srow = lane >> 3;           // 0..7: row within 8-row chunk
  const int ssegi = lane & 7;           // 0..7: LDS segment slot

  f32x4 acc[4][4] = {};

  for (int k0 = 0; k0 < K; k0 += 64) {
    __syncthreads();
    // A-tile: wave w stages rows w*32..w*32+31 (4 insts x 8 rows)
#pragma unroll
    for (int i = 0; i < 4; ++i) {
      int row = w * 32 + i * 8 + srow;
      int gseg = ssegi ^ (row & 7);
      load_lds16(&A[(size_t)(gm + row) * K + k0 + gseg * 8],
                 (void*)&sA[(size_t)(w * 32 + i * 8) * 64 + (size_t)lane * 8]);
    }
    // B-tile: wave w stages rows w*16..w*16+15 (2 insts x 8 rows)
#pragma unroll
    for (int i = 0; i < 2; ++i) {
      int row = w * 16 + i * 8 + srow;
      int gseg = ssegi ^ (row & 7);
      load_lds16(&Bt[(size_t)(gn + row) * K + k0 + gseg * 8],
                 (void*)&sB[(size_t)(w * 16 + i * 8) * 64 + (size_t)lane * 8]);
    }
    __syncthreads();

#pragma unroll
    for (int h = 0; h < 2; ++h) {
      short8 af[4], bfr[4];
      int gseg = h * 4 + kq;
#pragma unroll
      for (int mi = 0; mi < 4; ++mi) {
        int row = wy * 64 + mi * 16 + m_l;
        int s = gseg ^ (row & 7);
        af[mi] = *(const short8*)&sA[(size_t)row * 64 + s * 8];
      }
#pragma unroll
      for (int ni = 0; ni < 4; ++ni) {
        int row = wx * 64 + ni * 16 + m_l;
        int s = gseg ^ (row & 7);
        bfr[ni] = *(const short8*)&sB[(size_t)row * 64 + s * 8];
      }
#pragma unroll
      for (int mi = 0; mi < 4; ++mi)
#pragma unroll
        for (int ni = 0; ni < 4; ++ni)
          acc[mi][ni] = __builtin_amdgcn_mfma_f32_16x16x32_bf16(af[mi], bfr[ni], acc[mi][ni], 0, 0, 0);
    }
  }

  const int r0 = kq * 4;   // C/D: col = lane&15, row = (lane>>4)*4 + reg
  float bvv[4];
#pragma unroll
  for (int ni = 0; ni < 4; ++ni) {
    int col = gn + wx * 64 + ni * 16 + m_l;
    bvv[ni] = bias[col];
    float s = 0.f, s2 = 0.f;
#pragma unroll
    for (int mi = 0; mi < 4; ++mi)
#pragma unroll
      for (int r = 0; r < 4; ++r) {
        float v = acc[mi][ni][r] + bvv[ni];
        s += v; s2 += v * v;
      }
    s += __shfl_xor(s, 16, 64);  s2 += __shfl_xor(s2, 16, 64);
    s += __shfl_xor(s, 32, 64);  s2 += __shfl_xor(s2, 32, 64);
    if (kq == 0) {
      atomicAdd(&bn[col], s);
      atomicAdd(&bn[N + col], s2);
    }
  }

  // two-phase LDS-staged coalesced C write
#pragma unroll
  for (int p = 0; p < 2; ++p) {
    __syncthreads();
    if ((wy >> 1) == p) {
      int lr = (wy & 1) * 64;
#pragma unroll
      for (int ni = 0; ni < 4; ++ni) {
        int lcol = wx * 64 + ni * 16 + m_l;
#pragma unroll
        for (int mi = 0; mi < 4; ++mi)
#pragma unroll
          for (int r = 0; r < 4; ++r)
            epi[(size_t)(lr + mi * 16 + r0 + r) * 136 + lcol] = f2bf(acc[mi][ni][r] + bvv[ni]);
      }
    }
    __syncthreads();
#pragma unroll
    for (int i = 0; i < 4; ++i) {
      int cch = tid + i * 512;
      int row = cch >> 4, seg = cch & 15;
      uint4 v = *(const uint4*)&epi[(size_t)row * 136 + seg * 8];
      *(uint4*)&C[(size_t)(gm + p * 128 + row) * N + gn + seg * 8] = v;
    }
  }
}

__global__ void k_count2(const int* __restrict__ src, const int* __restrict__ dst,
                         const int* __restrict__ nid, int* __restrict__ cnt) {
  int e = blockIdx.x * 256 + threadIdx.x;
  int s = nid[src[e]], d = nid[dst[e]];
  if (s >= 0 && d >= 0) atomicAdd(&cnt[d], 1);
}

// single-block exclusive scan of cnt[n] -> ptr[n+1]; n divisible by 1024
__global__ __launch_bounds__(1024) void k_scan(const int* __restrict__ cnt,
                                               int* __restrict__ ptr, int n) {
  __shared__ int sums[1024];
  int t = threadIdx.x;
  int chunk = n / 1024;
  int base = t * chunk;
  int s = 0;
  for (int i = 0; i < chunk; ++i) s += cnt[base + i];
  sums[t] = s; __syncthreads();
  for (int off = 1; off < 1024; off <<= 1) {
    int v = (t >= off) ? sums[t - off] : 0;
    __syncthreads();
    sums[t] += v;
    __syncthreads();
  }
  int run = (t == 0) ? 0 : sums[t - 1];
  for (int i = 0; i < chunk; ++i) { ptr[base + i] = run; run += cnt[base + i]; }
  if (t == 1023) ptr[n] = run;
}

__global__ void k_fill(const int* __restrict__ src, const int* __restrict__ dst,
                       const int* __restrict__ ptr, int* __restrict__ fill,
                       int* __restrict__ csr) {
  int e = blockIdx.x * 256 + threadIdx.x;
  int d = dst[e];
  int pos = ptr[d] + atomicAdd(&fill[d], 1);
  csr[pos] = src[e];
}

__global__ void k_fill2(const int* __restrict__ src, const int* __restrict__ dst,
                        const int* __restrict__ nid, const int* __restrict__ ptr,
                        int* __restrict__ fill, int* __restrict__ csr) {
  int e = blockIdx.x * 256 + threadIdx.x;
  int s = nid[src[e]], d = nid[dst[e]];
  if (s >= 0 && d >= 0) {
    int pos = ptr[d] + atomicAdd(&fill[d], 1);
    csr[pos] = s;
  }
}

// score[v] = tanh(dot(relu(x*a+c), p)/||p||); bn affine computed from raw sums
__global__ __launch_bounds__(256) void k_score(const unsigned short* __restrict__ X,
                                               const float* __restrict__ bnsum,
                                               const float* __restrict__ gam,
                                               const float* __restrict__ bet,
                                               float inv_n,
                                               const float* __restrict__ p,
                                               const float* __restrict__ pnorm,
                                               float* __restrict__ score) {
  __shared__ float wred[4];
  int v = blockIdx.x;
  int t = threadIdx.x;
  int c = t * 4;
  float4 sm = *(const float4*)&bnsum[c];
  float4 sq = *(const float4*)&bnsum[H_ + c];
  float4 gg = *(const float4*)&gam[c];
  float4 bb = *(const float4*)&bet[c];
  float a0, c0, a1, c1, a2, c2, a3, c3;
  bn_affine(sm.x, sq.x, gg.x, bb.x, inv_n, a0, c0);
  bn_affine(sm.y, sq.y, gg.y, bb.y, inv_n, a1, c1);
  bn_affine(sm.z, sq.z, gg.z, bb.z, inv_n, a2, c2);
  bn_affine(sm.w, sq.w, gg.w, bb.w, inv_n, a3, c3);
  ushort4 xu = *(const ushort4*)&X[(size_t)v * H_ + c];
  float hx = fmaxf(bf2f(xu.x) * a0 + c0, 0.f);
  float hy = fmaxf(bf2f(xu.y) * a1 + c1, 0.f);
  float hz = fmaxf(bf2f(xu.z) * a2 + c2, 0.f);
  float hw = fmaxf(bf2f(xu.w) * a3 + c3, 0.f);
  float4 p4 = *(const float4*)&p[c];
  float s = hx * p4.x + hy * p4.y + hz * p4.z + hw * p4.w;
#pragma unroll
  for (int off = 1; off < 64; off <<= 1) s += __shfl_xor(s, off, 64);
  if ((t & 63) == 0) wred[t >> 6] = s;
  __syncthreads();
  if (t == 0) score[v] = tanhf((wred[0] + wred[1] + wred[2] + wred[3]) / pnorm[0]);
}

// per-graph exact descending bitonic sort (tie: smaller index first), 256 threads
__global__ __launch_bounds__(256) void k_topk(const float* __restrict__ score,
                                              int nper, int k,
                                              int* __restrict__ perm,
                                              float* __restrict__ val,
                                              int* __restrict__ newid) {
  __shared__ float sk[1024];
  __shared__ int si[1024];
  int g = blockIdx.x, t = threadIdx.x;
  for (int i = t; i < nper; i += 256) { sk[i] = score[g * nper + i]; si[i] = i; }
  __syncthreads();
  int pairs = nper >> 1;
  for (int k2 = 2; k2 <= nper; k2 <<= 1) {
    for (int j = k2 >> 1; j > 0; j >>= 1) {
      for (int p = t; p < pairs; p += 256) {
        int i = ((p & ~(j - 1)) << 1) | (p & (j - 1));
        int ix = i | j;
        float a = sk[i], b = sk[ix];
        int ia = si[i], ib = si[ix];
        bool aFirst = (a > b) || (a == b && ia < ib);
        bool dirDesc = ((i & k2) == 0);
        if (dirDesc ? (!aFirst) : aFirst) {
          sk[i] = b; sk[ix] = a; si[i] = ib; si[ix] = ia;
        }
      }
      __syncthreads();
    }
  }
  for (int i = t; i < k; i += 256) {
    perm[g * k + i] = g * nper + si[i];
    val[g * k + i] = sk[i];
    if (newid) newid[g * nper + si[i]] = g * k + i;
  }
}

// hpool[i] = relu(conv[perm[i]]*a+c) * val[i]   (bf16 -> bf16, BN fused from raw sums)
__global__ __launch_bounds__(256) void k_pool_bn(const unsigned short* __restrict__ Hm,
                                                 const float* __restrict__ bnsum,
                                                 const float* __restrict__ gam,
                                                 const float* __restrict__ bet,
                                                 float inv_n,
                                                 const int* __restrict__ perm,
                                                 const float* __restrict__ val,
                                                 unsigned short* __restrict__ out) {
  int i = blockIdx.x;
  int c = threadIdx.x * 4;
  int old = perm[i];
  float vv = val[i];
  float4 sm = *(const float4*)&bnsum[c];
  float4 sq = *(const float4*)&bnsum[H_ + c];
  float4 gg = *(const float4*)&gam[c];
  float4 bb = *(const float4*)&bet[c];
  float a0, c0, a1, c1, a2, c2, a3, c3;
  bn_affine(sm.x, sq.x, gg.x, bb.x, inv_n, a0, c0);
  bn_affine(sm.y, sq.y, gg.y, bb.y, inv_n, a1, c1);
  bn_affine(sm.z, sq.z, gg.z, bb.z, inv_n, a2, c2);
  bn_affine(sm.w, sq.w, gg.w, bb.w, inv_n, a3, c3);
  ushort4 xu = *(const ushort4*)&Hm[(size_t)old * H_ + c];
  ushort4 o = {f2bf(fmaxf(bf2f(xu.x) * a0 + c0, 0.f) * vv),
               f2bf(fmaxf(bf2f(xu.y) * a1 + c1, 0.f) * vv),
               f2bf(fmaxf(bf2f(xu.z) * a2 + c2, 0.f) * vv),
               f2bf(fmaxf(bf2f(xu.w) * a3 + c3, 0.f) * vv)};
  *(ushort4*)&out[(size_t)i * H_ + c] = o;
}

// partial column-mean (bf16 in), z-split; out pre-zeroed fp32
__global__ __launch_bounds__(256) void k_mean(const unsigned short* __restrict__ X,
                                              float* __restrict__ out,
                                              int k, int rows_per_blk) {
  int g = blockIdx.x;
  int col = blockIdx.y * 256 + threadIdx.x;
  int j0 = blockIdx.z * rows_per_blk;
  float s = 0.f;
  for (int j = j0; j < j0 + rows_per_blk; ++j)
    s += bf2f(X[(size_t)(g * k + j) * H_ + col]);
  atomicAdd(&out[g * H_ + col], s / (float)k);
}

// partial scaled column-mean with fused BN+ReLU, z-split; out pre-zeroed
__global__ __launch_bounds__(256) void k_mean_scaled_bn(const unsigned short* __restrict__ X,
                                                        const float* __restrict__ bnsum,
                                                        const float* __restrict__ gam,
                                                        const float* __restrict__ bet,
                                                        float inv_n,
                                                        const int* __restrict__ perm,
                                                        const float* __restrict__ val,
                                                        float* __restrict__ out,
                                                        int k, int rows_per_blk) {
  int g = blockIdx.x;
  int col = blockIdx.y * 256 + threadIdx.x;
  int j0 = blockIdx.z * rows_per_blk;
  float a, cc;
  bn_affine(bnsum[col], bnsum[H_ + col], gam[col], bet[col], inv_n, a, cc);
  float s = 0.f;
  for (int j = j0; j < j0 + rows_per_blk; ++j) {
    int r = perm[g * k + j];
    float h = fmaxf(bf2f(X[(size_t)r * H_ + col]) * a + cc, 0.f);
    s += val[g * k + j] * h;
  }
  atomicAdd(&out[g * H_ + col], s / (float)k);
}

// head part 1: zws[g,t] += sum_{k in z-chunk} (x1+x2)[g,k] * Wf[k,t]
__global__ __launch_bounds__(512) void k_head1(const float* __restrict__ x1,
                                               const float* __restrict__ x2,
                                               const float* __restrict__ Wf,
                                               float* __restrict__ zws) {
  __shared__ float tv[128];
  int g = blockIdx.x, z = blockIdx.y, t = threadIdx.x;
  int k0 = z * 128;
  if (t < 128) tv[t] = x1[g * H_ + k0 + t] + x2[g * H_ + k0 + t];
  __syncthreads();
  float acc = 0.f;
#pragma unroll 8
  for (int k = 0; k < 128; ++k) acc += tv[k] * Wf[(size_t)(k0 + k) * 512 + t];
  atomicAdd(&zws[g * 512 + t], acc);
}

// head part 2: z = relu(zws+bf); out = z@Wf1 + bf1
__global__ __launch_bounds__(512) void k_head2(const float* __restrict__ zws,
                                               const float* __restrict__ bf,
                                               const float* __restrict__ Wf1,
                                               const float* __restrict__ bf1,
                                               float* __restrict__ out) {
  __shared__ float red[512];
  int g = blockIdx.x, t = threadIdx.x;
  float zv = fmaxf(zws[g * 512 + t] + bf[t], 0.f);
  for (int o = 0; o < OUT_; ++o) {
    red[t] = zv * Wf1[t * OUT_ + o];
    __syncthreads();
    for (int s = 256; s > 0; s >>= 1) { if (t < s) red[t] += red[t + s]; __syncthreads(); }
    if (t == 0) out[g * OUT_ + o] = red[0] + bf1[o];
    __syncthreads();
  }
}

// ---------------- launch ----------------
extern "C" void kernel_launch(void* const* d_in, const int* in_sizes, int n_in,
                              void* d_out, int out_size, void* d_ws, size_t ws_size,
                              hipStream_t stream) {
  (void)in_sizes; (void)n_in; (void)out_size; (void)ws_size;
  const float* x   = (const float*)d_in[0];
  const int*   ei  = (const int*)d_in[1];
  const float* W1  = (const float*)d_in[3];
  const float* b1  = (const float*)d_in[4];
  const float* g1  = (const float*)d_in[5];
  const float* be1 = (const float*)d_in[6];
  const float* p1  = (const float*)d_in[7];
  const float* W2  = (const float*)d_in[8];
  const float* b2  = (const float*)d_in[9];
  const float* g2  = (const float*)d_in[10];
  const float* be2 = (const float*)d_in[11];
  const float* p2  = (const float*)d_in[12];
  const float* Wf  = (const float*)d_in[13];
  const float* bf  = (const float*)d_in[14];
  const float* Wf1 = (const float*)d_in[15];
  const float* bf1 = (const float*)d_in[16];
  const int* srcv = ei;
  const int* dstv = ei + E_;

  char* ws = (char*)d_ws;
  unsigned short* conv1 = (unsigned short*)(ws + OFF_CONV1);
  unsigned short* xagg  = (unsigned short*)(ws + OFF_XAGG);
  unsigned short* hagg2 = (unsigned short*)(ws + OFF_XAGG);  // aliases xagg (dead by then)
  unsigned short* hpool = (unsigned short*)(ws + OFF_HPOOL);
  unsigned short* conv2 = (unsigned short*)(ws + OFF_CONV2);
  unsigned short* xbf   = (unsigned short*)(ws + OFF_XBF);
  int* cnt1    = (int*)(ws + OFF_CNT1);
  int* fill1   = (int*)(ws + OFF_FILL1);
  int* cnt2    = (int*)(ws + OFF_CNT2);
  int* fill2   = (int*)(ws + OFF_FILL2);
  float* bn1   = (float*)(ws + OFF_BN1);
  float* bn2   = (float*)(ws + OFF_BN2);
  int* ptr1    = (int*)(ws + OFF_PTR1);
  int* ptr2    = (int*)(ws + OFF_PTR2);
  int* csr1    = (int*)(ws + OFF_CSR1);
  int* csr2    = (int*)(ws + OFF_CSR2);
  float* sc1   = (float*)(ws + OFF_SC1);
  float* sc2   = (float*)(ws + OFF_SC2);
  int* perm1   = (int*)(ws + OFF_PERM1);
  float* val1  = (float*)(ws + OFF_VAL1);
  int* perm2   = (int*)(ws + OFF_PERM2);
  float* val2  = (float*)(ws + OFF_VAL2);
  int* newid1  = (int*)(ws + OFF_NEWID);
  float* pnorm = (float*)(ws + OFF_PNORM);
  float* x1    = (float*)(ws + OFF_X1);
  float* x2    = (float*)(ws + OFF_X2);
  float* zws   = (float*)(ws + OFF_ZWS);
  unsigned short* Wt1 = (unsigned short*)(ws + OFF_WT1);
  unsigned short* Wt2 = (unsigned short*)(ws + OFF_WT2);

  hipMemsetAsync(ws + ZERO_BASE, 0, ZERO_BYTES, stream);
  hipMemsetAsync(ws + OFF_NEWID, 0xFF, (size_t)NN1_ * 4, stream);  // new_id = -1

  // fused prep: x->bf16, dst count, W1^T, W2^T, pnorms
  k_prep<<<PREP_BLOCKS, 256, 0, stream>>>(x, dstv, W1, W2, p1, p2,
                                          xbf, cnt1, Wt1, Wt2, pnorm);

  // ---- stage 1 ----
  k_scan<<<1, 1024, 0, stream>>>(cnt1, ptr1, NN1_);
  k_fill<<<E_ / 256, 256, 0, stream>>>(srcv, dstv, ptr1, fill1, csr1);
  k_agg_bf<<<NN1_, FIN_ / 4, 0, stream>>>(xbf, csr1, ptr1, cnt1, xagg, FIN_);
  k_gemm_bf<<<dim3(H_ / 128, NN1_ / 256), 512, 0, stream>>>(xagg, Wt1, b1, conv1, bn1, NN1_, H_, FIN_);
  k_score<<<NN1_, 256, 0, stream>>>(conv1, bn1, g1, be1, 1.0f / (float)NN1_, p1, pnorm + 0, sc1);
  k_topk<<<B_, 256, 0, stream>>>(sc1, N_, K1_, perm1, val1, newid1);
  k_pool_bn<<<NN2_, 256, 0, stream>>>(conv1, bn1, g1, be1, 1.0f / (float)NN1_, perm1, val1, hpool);
  k_mean<<<dim3(B_, H_ / 256, 8), 256, 0, stream>>>(hpool, x1, K1_, K1_ / 8);

  // ---- stage 2 ----
  k_count2<<<E_ / 256, 256, 0, stream>>>(srcv, dstv, newid1, cnt2);
  k_scan<<<1, 1024, 0, stream>>>(cnt2, ptr2, NN2_);
  k_fill2<<<E_ / 256, 256, 0, stream>>>(srcv, dstv, newid1, ptr2, fill2, csr2);
  k_agg_bf<<<NN2_, H_ / 4, 0, stream>>>(hpool, csr2, ptr2, cnt2, hagg2, H_);
  k_gemm_bf<<<dim3(H_ / 128, NN2_ / 256), 512, 0, stream>>>(hagg2, Wt2, b2, conv2, bn2, NN2_, H_, H_);
  k_score<<<NN2_, 256, 0, stream>>>(conv2, bn2, g2, be2, 1.0f / (float)NN2_, p2, pnorm + 1, sc2);
  k_topk<<<B_, 256, 0, stream>>>(sc2, K1_, K2_, perm2, val2, nullptr);
  k_mean_scaled_bn<<<dim3(B_, H_ / 256, 4), 256, 0, stream>>>(conv2, bn2, g2, be2, 1.0f / (float)NN2_,
                                                              perm2, val2, x2, K2_, K2_ / 4);

  // ---- head ----
  k_head1<<<dim3(B_, 8), 512, 0, stream>>>(x1, x2, Wf, zws);
  k_head2<<<B_, 512, 0, stream>>>(zws, bf, Wf1, bf1, (float*)d_out);
}

// Round 11
// 459.197 us; speedup vs baseline: 3.4918x; 1.1160x over previous
//
#include <hip/hip_runtime.h>
#include <hip/hip_bf16.h>
#include <cstdint>
#include <cstddef>

// Problem constants (from reference)
#define B_    32
#define N_    1024
#define DEG_  8
#define FIN_  512
#define H_    1024
#define OUT_  10
#define E_    (B_ * N_ * DEG_)   // 262144
#define NN1_  (B_ * N_)          // 32768
#define K1_   (N_ / 2)           // 512
#define NN2_  (B_ * K1_)         // 16384
#define K2_   (N_ / 4)           // 256
#define EPS_  1e-5f
#define ECAP_ (N_ * DEG_)        // 8192 edges per graph (fixed capacity)

// ---------------- workspace layout (bytes) ----------------
constexpr size_t OFF_CONV1 = 0;                                   // NN1 x H bf16 (64 MiB)
constexpr size_t OFF_XAGG  = OFF_CONV1 + (size_t)NN1_ * H_ * 2;   // NN1 x FIN bf16; stage2: hagg2
constexpr size_t OFF_HPOOL = OFF_XAGG + (size_t)NN1_ * FIN_ * 2;  // NN2 x H bf16
constexpr size_t OFF_CONV2 = OFF_HPOOL + (size_t)NN2_ * H_ * 2;   // NN2 x H bf16
constexpr size_t OFF_CNT1  = OFF_CONV2 + (size_t)NN2_ * H_ * 2;   // NN1 ints (zeroed)
constexpr size_t OFF_FILL1 = OFF_CNT1 + (size_t)NN1_ * 4;
constexpr size_t OFF_CNT2  = OFF_FILL1 + (size_t)NN1_ * 4;
constexpr size_t OFF_FILL2 = OFF_CNT2 + (size_t)NN2_ * 4;
constexpr size_t OFF_BN1   = OFF_FILL2 + (size_t)NN2_ * 4;        // 2H floats raw sums (zeroed)
constexpr size_t OFF_BN2   = OFF_BN1 + (size_t)2 * H_ * 4;
constexpr size_t OFF_X1    = OFF_BN2 + (size_t)2 * H_ * 4;        // B*H floats (zeroed)
constexpr size_t OFF_X2    = OFF_X1 + (size_t)B_ * H_ * 4;
constexpr size_t OFF_ZWS   = OFF_X2 + (size_t)B_ * H_ * 4;        // B*512 floats (zeroed)
constexpr size_t ZERO_BASE = OFF_CNT1;
constexpr size_t ZERO_BYTES = OFF_ZWS + (size_t)B_ * 512 * 4 - ZERO_BASE;
constexpr size_t OFF_PTR1  = OFF_ZWS + (size_t)B_ * 512 * 4;
constexpr size_t OFF_PTR2  = OFF_PTR1 + (size_t)(NN1_ + 64) * 4;
constexpr size_t OFF_CSR1  = OFF_PTR2 + (size_t)(NN2_ + 64) * 4;
constexpr size_t OFF_CSR2  = OFF_CSR1 + (size_t)E_ * 4;
constexpr size_t OFF_SC1   = OFF_CSR2 + (size_t)E_ * 4;
constexpr size_t OFF_SC2   = OFF_SC1 + (size_t)NN1_ * 4;
constexpr size_t OFF_PERM1 = OFF_SC2 + (size_t)NN2_ * 4;
constexpr size_t OFF_VAL1  = OFF_PERM1 + (size_t)NN2_ * 4;
constexpr size_t OFF_PERM2 = OFF_VAL1 + (size_t)NN2_ * 4;
constexpr size_t OFF_VAL2  = OFF_PERM2 + (size_t)(B_ * K2_) * 4;
constexpr size_t OFF_NEWID = OFF_VAL2 + (size_t)(B_ * K2_) * 4;   // NN1 ints (0xFF)
constexpr size_t OFF_PNORM = OFF_NEWID + (size_t)NN1_ * 4;        // padded
constexpr size_t OFF_WT1   = OFF_PNORM + 256;                     // H*FIN bf16
constexpr size_t OFF_WT2   = OFF_WT1 + (size_t)H_ * FIN_ * 2;     // H*H bf16
constexpr size_t OFF_XBF   = OFF_WT2 + (size_t)H_ * H_ * 2;       // NN1 x FIN bf16
// total ≈ 231 MiB

// ---------------- helpers ----------------
typedef short short8 __attribute__((ext_vector_type(8)));
typedef float f32x4 __attribute__((ext_vector_type(4)));

__device__ inline unsigned short f2bf(float f) {
  uint32_t u = __float_as_uint(f);
  u += 0x7fffu + ((u >> 16) & 1u);   // RNE
  return (unsigned short)(u >> 16);
}
__device__ inline float bf2f(unsigned short u) {
  return __uint_as_float(((uint32_t)u) << 16);
}

__device__ inline void load_lds16(const void* g, void* l) {
  __builtin_amdgcn_global_load_lds(
      (const __attribute__((address_space(1))) uint32_t*)g,
      (__attribute__((address_space(3))) uint32_t*)l, 16, 0, 0);
}

// bn affine from raw sums: a = g*rsqrt(var+eps), c = be - mean*a
__device__ inline void bn_affine(float sum, float sumsq, float g, float be,
                                 float inv_n, float& a, float& c) {
  float mean = sum * inv_n;
  float var = sumsq * inv_n - mean * mean;
  a = g * rsqrtf(var + EPS_);
  c = be - mean * a;
}

// ---------------- kernels ----------------

// Fused prep: tobf [0,16384) | count [16384,17408) | wt1 [17408,17920)
//             wt2 [17920,18944) | pnorm [18944,18946)
#define PREP_BLOCKS 18946
__global__ __launch_bounds__(256) void k_prep(const float* __restrict__ x,
                                              const int* __restrict__ dstv,
                                              const float* __restrict__ W1,
                                              const float* __restrict__ W2,
                                              const float* __restrict__ p1,
                                              const float* __restrict__ p2,
                                              unsigned short* __restrict__ xbf,
                                              int* __restrict__ cnt,
                                              unsigned short* __restrict__ Wt1,
                                              unsigned short* __restrict__ Wt2,
                                              float* __restrict__ pn) {
  __shared__ float sh[32][33];
  __shared__ float red[256];
  int bid = blockIdx.x, t = threadIdx.x;
  if (bid < 16384) {                      // fp32 -> bf16 convert of x
    size_t i = ((size_t)bid * 256 + t) * 4;
    float4 v = *(const float4*)&x[i];
    ushort4 o = {f2bf(v.x), f2bf(v.y), f2bf(v.z), f2bf(v.w)};
    *(ushort4*)&xbf[i] = o;
  } else if (bid < 17408) {               // edge dst count
    int e = (bid - 16384) * 256 + t;
    atomicAdd(&cnt[dstv[e]], 1);
  } else if (bid < 18944) {               // weight transpose -> bf16
    const float* W; unsigned short* Wt; int K, N, r;
    if (bid < 17920) { W = W1; Wt = Wt1; K = FIN_; N = H_; r = bid - 17408; }
    else             { W = W2; Wt = Wt2; K = H_;   N = H_; r = bid - 17920; }
    int bx = r & 31, by = r >> 5;
    int k0 = by * 32, n0 = bx * 32;
    int tx = t & 31, ty = t >> 5;
    for (int i = ty; i < 32; i += 8)
      sh[i][tx] = W[(size_t)(k0 + i) * N + n0 + tx];
    __syncthreads();
    for (int i = ty; i < 32; i += 8)
      Wt[(size_t)(n0 + i) * K + k0 + tx] = f2bf(sh[tx][i]);
  } else {                                // pnorm
    const float* p = (bid == 18944) ? p1 : p2;
    float s = 0.f;
    for (int i = t; i < H_; i += 256) s += p[i] * p[i];
    red[t] = s; __syncthreads();
    for (int st = 128; st > 0; st >>= 1) { if (t < st) red[t] += red[t + st]; __syncthreads(); }
    if (t == 0) pn[bid - 18944] = sqrtf(red[0]);
  }
}

// Per-graph exclusive scan: ptr[g*nper + i] = g*ECAP_ + prefix(cnt within graph g).
// One block per graph (32 blocks, 256 threads). Edges are intra-graph, so each
// graph's CSR lives in its own fixed-capacity region; consumers use e0+cnt[v].
__global__ __launch_bounds__(256) void k_scan_g(const int* __restrict__ cnt,
                                                int* __restrict__ ptr, int nper) {
  __shared__ int tot[256];
  int g = blockIdx.x, t = threadIdx.x;
  int chunk = nper / 256;                // 4 (stage 1) or 2 (stage 2)
  int base = g * nper + t * chunk;
  int loc[4];
  int s = 0;
  for (int i = 0; i < chunk; ++i) { loc[i] = s; s += cnt[base + i]; }
  tot[t] = s;
  __syncthreads();
  for (int off = 1; off < 256; off <<= 1) {
    int v = (t >= off) ? tot[t - off] : 0;
    __syncthreads();
    tot[t] += v;
    __syncthreads();
  }
  int pre = (t == 0) ? 0 : tot[t - 1];
  int gbase = g * ECAP_;
  for (int i = 0; i < chunk; ++i) ptr[base + i] = gbase + pre + loc[i];
}

// Aggregation (bf16 in -> bf16 out), XCD-swizzled slabs. e1 = e0 + cnt[v].
__global__ void k_agg_bf(const unsigned short* __restrict__ X,
                         const int* __restrict__ csr,
                         const int* __restrict__ ptr,
                         const int* __restrict__ cnt,
                         unsigned short* __restrict__ out, int F) {
  int bid = blockIdx.x;
  int slab = gridDim.x >> 3;
  int v = (bid & 7) * slab + (bid >> 3);
  int c = threadIdx.x * 4;
  float degv = 1.0f + (float)cnt[v];
  float dinvv = rsqrtf(degv);
  float inv = 1.0f / degv;
  ushort4 xu = *(const ushort4*)&X[(size_t)v * F + c];
  float4 acc = {bf2f(xu.x) * inv, bf2f(xu.y) * inv, bf2f(xu.z) * inv, bf2f(xu.w) * inv};
  int e0 = ptr[v], e1 = e0 + cnt[v];
  for (int e = e0; e < e1; ++e) {
    int s = csr[e];
    float w = dinvv * rsqrtf(1.0f + (float)cnt[s]);
    ushort4 xs = *(const ushort4*)&X[(size_t)s * F + c];
    acc.x += bf2f(xs.x) * w; acc.y += bf2f(xs.y) * w;
    acc.z += bf2f(xs.z) * w; acc.w += bf2f(xs.w) * w;
  }
  ushort4 o = {f2bf(acc.x), f2bf(acc.y), f2bf(acc.z), f2bf(acc.w)};
  *(ushort4*)&out[(size_t)v * F + c] = o;
}

// bf16 MFMA GEMM: 256(m) x 128(n) tile, BK=64 (XOR-swizzled segments),
// 512 threads = 8 waves (4x2). bf16 C via LDS-staged coalesced stores;
// fused per-column sum/sumsq; XCD-banded m-tiles.
__global__ __launch_bounds__(512) void k_gemm_bf(const unsigned short* __restrict__ A,
                                                 const unsigned short* __restrict__ Bt,
                                                 const float* __restrict__ bias,
                                                 unsigned short* __restrict__ C,
                                                 float* __restrict__ bn,
                                                 int M, int N, int K) {
  __shared__ __align__(16) char smem[49152];            // 48 KiB
  unsigned short* sA  = (unsigned short*)smem;          // 256x64 = 32 KiB
  unsigned short* sB  = (unsigned short*)(smem + 256 * 64 * 2);  // 128x64 = 16 KiB
  unsigned short* epi = (unsigned short*)smem;          // 128x136 (epilogue, 34 KiB)

  const int tid = threadIdx.x;
  const int lane = tid & 63;
  const int w = tid >> 6;
  const int wy = w >> 1, wx = w & 1;
  int lin = blockIdx.y * gridDim.x + blockIdx.x;
  int nt = gridDim.x;
  int mchunk = gridDim.y >> 3;
  int xcd = lin & 7;
  int idx = lin >> 3;
  int mtile = xcd * mchunk + idx / nt;
  int ntile = idx % nt;
  const int gm = mtile * 256, gn = ntile * 128;

  const int m_l = lane & 15, kq = lane >> 4;
  const int srow = lane >> 3;           // 0..7: row within 8-row chunk
  const int ssegi = lane & 7;           // 0..7: LDS segment slot

  f32x4 acc[4][4] = {};

  for (int k0 = 0; k0 < K; k0 += 64) {
    __syncthreads();
#pragma unroll
    for (int i = 0; i < 4; ++i) {
      int row = w * 32 + i * 8 + srow;
      int gseg = ssegi ^ (row & 7);
      load_lds16(&A[(size_t)(gm + row) * K + k0 + gseg * 8],
                 (void*)&sA[(size_t)(w * 32 + i * 8) * 64 + (size_t)lane * 8]);
    }
#pragma unroll
    for (int i = 0; i < 2; ++i) {
      int row = w * 16 + i * 8 + srow;
      int gseg = ssegi ^ (row & 7);
      load_lds16(&Bt[(size_t)(gn + row) * K + k0 + gseg * 8],
                 (void*)&sB[(size_t)(w * 16 + i * 8) * 64 + (size_t)lane * 8]);
    }
    __syncthreads();

#pragma unroll
    for (int h = 0; h < 2; ++h) {
      short8 af[4], bfr[4];
      int gseg = h * 4 + kq;
#pragma unroll
      for (int mi = 0; mi < 4; ++mi) {
        int row = wy * 64 + mi * 16 + m_l;
        int s = gseg ^ (row & 7);
        af[mi] = *(const short8*)&sA[(size_t)row * 64 + s * 8];
      }
#pragma unroll
      for (int ni = 0; ni < 4; ++ni) {
        int row = wx * 64 + ni * 16 + m_l;
        int s = gseg ^ (row & 7);
        bfr[ni] = *(const short8*)&sB[(size_t)row * 64 + s * 8];
      }
#pragma unroll
      for (int mi = 0; mi < 4; ++mi)
#pragma unroll
        for (int ni = 0; ni < 4; ++ni)
          acc[mi][ni] = __builtin_amdgcn_mfma_f32_16x16x32_bf16(af[mi], bfr[ni], acc[mi][ni], 0, 0, 0);
    }
  }

  const int r0 = kq * 4;   // C/D: col = lane&15, row = (lane>>4)*4 + reg
  float bvv[4];
#pragma unroll
  for (int ni = 0; ni < 4; ++ni) {
    int col = gn + wx * 64 + ni * 16 + m_l;
    bvv[ni] = bias[col];
    float s = 0.f, s2 = 0.f;
#pragma unroll
    for (int mi = 0; mi < 4; ++mi)
#pragma unroll
      for (int r = 0; r < 4; ++r) {
        float v = acc[mi][ni][r] + bvv[ni];
        s += v; s2 += v * v;
      }
    s += __shfl_xor(s, 16, 64);  s2 += __shfl_xor(s2, 16, 64);
    s += __shfl_xor(s, 32, 64);  s2 += __shfl_xor(s2, 32, 64);
    if (kq == 0) {
      atomicAdd(&bn[col], s);
      atomicAdd(&bn[N + col], s2);
    }
  }

  // two-phase LDS-staged coalesced C write
#pragma unroll
  for (int p = 0; p < 2; ++p) {
    __syncthreads();
    if ((wy >> 1) == p) {
      int lr = (wy & 1) * 64;
#pragma unroll
      for (int ni = 0; ni < 4; ++ni) {
        int lcol = wx * 64 + ni * 16 + m_l;
#pragma unroll
        for (int mi = 0; mi < 4; ++mi)
#pragma unroll
          for (int r = 0; r < 4; ++r)
            epi[(size_t)(lr + mi * 16 + r0 + r) * 136 + lcol] = f2bf(acc[mi][ni][r] + bvv[ni]);
      }
    }
    __syncthreads();
#pragma unroll
    for (int i = 0; i < 4; ++i) {
      int cch = tid + i * 512;
      int row = cch >> 4, seg = cch & 15;
      uint4 v = *(const uint4*)&epi[(size_t)row * 136 + seg * 8];
      *(uint4*)&C[(size_t)(gm + p * 128 + row) * N + gn + seg * 8] = v;
    }
  }
}

__global__ void k_count2(const int* __restrict__ src, const int* __restrict__ dst,
                         const int* __restrict__ nid, int* __restrict__ cnt) {
  int e = blockIdx.x * 256 + threadIdx.x;
  int s = nid[src[e]], d = nid[dst[e]];
  if (s >= 0 && d >= 0) atomicAdd(&cnt[d], 1);
}

__global__ void k_fill(const int* __restrict__ src, const int* __restrict__ dst,
                       const int* __restrict__ ptr, int* __restrict__ fill,
                       int* __restrict__ csr) {
  int e = blockIdx.x * 256 + threadIdx.x;
  int d = dst[e];
  int pos = ptr[d] + atomicAdd(&fill[d], 1);
  csr[pos] = src[e];
}

__global__ void k_fill2(const int* __restrict__ src, const int* __restrict__ dst,
                        const int* __restrict__ nid, const int* __restrict__ ptr,
                        int* __restrict__ fill, int* __restrict__ csr) {
  int e = blockIdx.x * 256 + threadIdx.x;
  int s = nid[src[e]], d = nid[dst[e]];
  if (s >= 0 && d >= 0) {
    int pos = ptr[d] + atomicAdd(&fill[d], 1);
    csr[pos] = s;
  }
}

// score[v] = tanh(dot(relu(x*a+c), p)/||p||); bn affine computed from raw sums
__global__ __launch_bounds__(256) void k_score(const unsigned short* __restrict__ X,
                                               const float* __restrict__ bnsum,
                                               const float* __restrict__ gam,
                                               const float* __restrict__ bet,
                                               float inv_n,
                                               const float* __restrict__ p,
                                               const float* __restrict__ pnorm,
                                               float* __restrict__ score) {
  __shared__ float wred[4];
  int v = blockIdx.x;
  int t = threadIdx.x;
  int c = t * 4;
  float4 sm = *(const float4*)&bnsum[c];
  float4 sq = *(const float4*)&bnsum[H_ + c];
  float4 gg = *(const float4*)&gam[c];
  float4 bb = *(const float4*)&bet[c];
  float a0, c0, a1, c1, a2, c2, a3, c3;
  bn_affine(sm.x, sq.x, gg.x, bb.x, inv_n, a0, c0);
  bn_affine(sm.y, sq.y, gg.y, bb.y, inv_n, a1, c1);
  bn_affine(sm.z, sq.z, gg.z, bb.z, inv_n, a2, c2);
  bn_affine(sm.w, sq.w, gg.w, bb.w, inv_n, a3, c3);
  ushort4 xu = *(const ushort4*)&X[(size_t)v * H_ + c];
  float hx = fmaxf(bf2f(xu.x) * a0 + c0, 0.f);
  float hy = fmaxf(bf2f(xu.y) * a1 + c1, 0.f);
  float hz = fmaxf(bf2f(xu.z) * a2 + c2, 0.f);
  float hw = fmaxf(bf2f(xu.w) * a3 + c3, 0.f);
  float4 p4 = *(const float4*)&p[c];
  float s = hx * p4.x + hy * p4.y + hz * p4.z + hw * p4.w;
#pragma unroll
  for (int off = 1; off < 64; off <<= 1) s += __shfl_xor(s, off, 64);
  if ((t & 63) == 0) wred[t >> 6] = s;
  __syncthreads();
  if (t == 0) score[v] = tanhf((wred[0] + wred[1] + wred[2] + wred[3]) / pnorm[0]);
}

// per-graph exact descending bitonic sort (tie: smaller index first), 256 threads
__global__ __launch_bounds__(256) void k_topk(const float* __restrict__ score,
                                              int nper, int k,
                                              int* __restrict__ perm,
                                              float* __restrict__ val,
                                              int* __restrict__ newid) {
  __shared__ float sk[1024];
  __shared__ int si[1024];
  int g = blockIdx.x, t = threadIdx.x;
  for (int i = t; i < nper; i += 256) { sk[i] = score[g * nper + i]; si[i] = i; }
  __syncthreads();
  int pairs = nper >> 1;
  for (int k2 = 2; k2 <= nper; k2 <<= 1) {
    for (int j = k2 >> 1; j > 0; j >>= 1) {
      for (int p = t; p < pairs; p += 256) {
        int i = ((p & ~(j - 1)) << 1) | (p & (j - 1));
        int ix = i | j;
        float a = sk[i], b = sk[ix];
        int ia = si[i], ib = si[ix];
        bool aFirst = (a > b) || (a == b && ia < ib);
        bool dirDesc = ((i & k2) == 0);
        if (dirDesc ? (!aFirst) : aFirst) {
          sk[i] = b; sk[ix] = a; si[i] = ib; si[ix] = ia;
        }
      }
      __syncthreads();
    }
  }
  for (int i = t; i < k; i += 256) {
    perm[g * k + i] = g * nper + si[i];
    val[g * k + i] = sk[i];
    if (newid) newid[g * nper + si[i]] = g * k + i;
  }
}

// hpool[i] = relu(conv[perm[i]]*a+c) * val[i]   (bf16 -> bf16, BN fused from raw sums)
__global__ __launch_bounds__(256) void k_pool_bn(const unsigned short* __restrict__ Hm,
                                                 const float* __restrict__ bnsum,
                                                 const float* __restrict__ gam,
                                                 const float* __restrict__ bet,
                                                 float inv_n,
                                                 const int* __restrict__ perm,
                                                 const float* __restrict__ val,
                                                 unsigned short* __restrict__ out) {
  int i = blockIdx.x;
  int c = threadIdx.x * 4;
  int old = perm[i];
  float vv = val[i];
  float4 sm = *(const float4*)&bnsum[c];
  float4 sq = *(const float4*)&bnsum[H_ + c];
  float4 gg = *(const float4*)&gam[c];
  float4 bb = *(const float4*)&bet[c];
  float a0, c0, a1, c1, a2, c2, a3, c3;
  bn_affine(sm.x, sq.x, gg.x, bb.x, inv_n, a0, c0);
  bn_affine(sm.y, sq.y, gg.y, bb.y, inv_n, a1, c1);
  bn_affine(sm.z, sq.z, gg.z, bb.z, inv_n, a2, c2);
  bn_affine(sm.w, sq.w, gg.w, bb.w, inv_n, a3, c3);
  ushort4 xu = *(const ushort4*)&Hm[(size_t)old * H_ + c];
  ushort4 o = {f2bf(fmaxf(bf2f(xu.x) * a0 + c0, 0.f) * vv),
               f2bf(fmaxf(bf2f(xu.y) * a1 + c1, 0.f) * vv),
               f2bf(fmaxf(bf2f(xu.z) * a2 + c2, 0.f) * vv),
               f2bf(fmaxf(bf2f(xu.w) * a3 + c3, 0.f) * vv)};
  *(ushort4*)&out[(size_t)i * H_ + c] = o;
}

// partial column-mean (bf16 in), z-split; out pre-zeroed fp32
__global__ __launch_bounds__(256) void k_mean(const unsigned short* __restrict__ X,
                                              float* __restrict__ out,
                                              int k, int rows_per_blk) {
  int g = blockIdx.x;
  int col = blockIdx.y * 256 + threadIdx.x;
  int j0 = blockIdx.z * rows_per_blk;
  float s = 0.f;
  for (int j = j0; j < j0 + rows_per_blk; ++j)
    s += bf2f(X[(size_t)(g * k + j) * H_ + col]);
  atomicAdd(&out[g * H_ + col], s / (float)k);
}

// partial scaled column-mean with fused BN+ReLU, z-split; out pre-zeroed
__global__ __launch_bounds__(256) void k_mean_scaled_bn(const unsigned short* __restrict__ X,
                                                        const float* __restrict__ bnsum,
                                                        const float* __restrict__ gam,
                                                        const float* __restrict__ bet,
                                                        float inv_n,
                                                        const int* __restrict__ perm,
                                                        const float* __restrict__ val,
                                                        float* __restrict__ out,
                                                        int k, int rows_per_blk) {
  int g = blockIdx.x;
  int col = blockIdx.y * 256 + threadIdx.x;
  int j0 = blockIdx.z * rows_per_blk;
  float a, cc;
  bn_affine(bnsum[col], bnsum[H_ + col], gam[col], bet[col], inv_n, a, cc);
  float s = 0.f;
  for (int j = j0; j < j0 + rows_per_blk; ++j) {
    int r = perm[g * k + j];
    float h = fmaxf(bf2f(X[(size_t)r * H_ + col]) * a + cc, 0.f);
    s += val[g * k + j] * h;
  }
  atomicAdd(&out[g * H_ + col], s / (float)k);
}

// head part 1: zws[g,t] += sum_{k in z-chunk} (x1+x2)[g,k] * Wf[k,t]
__global__ __launch_bounds__(512) void k_head1(const float* __restrict__ x1,
                                               const float* __restrict__ x2,
                                               const float* __restrict__ Wf,
                                               float* __restrict__ zws) {
  __shared__ float tv[128];
  int g = blockIdx.x, z = blockIdx.y, t = threadIdx.x;
  int k0 = z * 128;
  if (t < 128) tv[t] = x1[g * H_ + k0 + t] + x2[g * H_ + k0 + t];
  __syncthreads();
  float acc = 0.f;
#pragma unroll 8
  for (int k = 0; k < 128; ++k) acc += tv[k] * Wf[(size_t)(k0 + k) * 512 + t];
  atomicAdd(&zws[g * 512 + t], acc);
}

// head part 2: z = relu(zws+bf); out = z@Wf1 + bf1
__global__ __launch_bounds__(512) void k_head2(const float* __restrict__ zws,
                                               const float* __restrict__ bf,
                                               const float* __restrict__ Wf1,
                                               const float* __restrict__ bf1,
                                               float* __restrict__ out) {
  __shared__ float red[512];
  int g = blockIdx.x, t = threadIdx.x;
  float zv = fmaxf(zws[g * 512 + t] + bf[t], 0.f);
  for (int o = 0; o < OUT_; ++o) {
    red[t] = zv * Wf1[t * OUT_ + o];
    __syncthreads();
    for (int s = 256; s > 0; s >>= 1) { if (t < s) red[t] += red[t + s]; __syncthreads(); }
    if (t == 0) out[g * OUT_ + o] = red[0] + bf1[o];
    __syncthreads();
  }
}

// ---------------- launch ----------------
extern "C" void kernel_launch(void* const* d_in, const int* in_sizes, int n_in,
                              void* d_out, int out_size, void* d_ws, size_t ws_size,
                              hipStream_t stream) {
  (void)in_sizes; (void)n_in; (void)out_size; (void)ws_size;
  const float* x   = (const float*)d_in[0];
  const int*   ei  = (const int*)d_in[1];
  const float* W1  = (const float*)d_in[3];
  const float* b1  = (const float*)d_in[4];
  const float* g1  = (const float*)d_in[5];
  const float* be1 = (const float*)d_in[6];
  const float* p1  = (const float*)d_in[7];
  const float* W2  = (const float*)d_in[8];
  const float* b2  = (const float*)d_in[9];
  const float* g2  = (const float*)d_in[10];
  const float* be2 = (const float*)d_in[11];
  const float* p2  = (const float*)d_in[12];
  const float* Wf  = (const float*)d_in[13];
  const float* bf  = (const float*)d_in[14];
  const float* Wf1 = (const float*)d_in[15];
  const float* bf1 = (const float*)d_in[16];
  const int* srcv = ei;
  const int* dstv = ei + E_;

  char* ws = (char*)d_ws;
  unsigned short* conv1 = (unsigned short*)(ws + OFF_CONV1);
  unsigned short* xagg  = (unsigned short*)(ws + OFF_XAGG);
  unsigned short* hagg2 = (unsigned short*)(ws + OFF_XAGG);  // aliases xagg (dead by then)
  unsigned short* hpool = (unsigned short*)(ws + OFF_HPOOL);
  unsigned short* conv2 = (unsigned short*)(ws + OFF_CONV2);
  unsigned short* xbf   = (unsigned short*)(ws + OFF_XBF);
  int* cnt1    = (int*)(ws + OFF_CNT1);
  int* fill1   = (int*)(ws + OFF_FILL1);
  int* cnt2    = (int*)(ws + OFF_CNT2);
  int* fill2   = (int*)(ws + OFF_FILL2);
  float* bn1   = (float*)(ws + OFF_BN1);
  float* bn2   = (float*)(ws + OFF_BN2);
  int* ptr1    = (int*)(ws + OFF_PTR1);
  int* ptr2    = (int*)(ws + OFF_PTR2);
  int* csr1    = (int*)(ws + OFF_CSR1);
  int* csr2    = (int*)(ws + OFF_CSR2);
  float* sc1   = (float*)(ws + OFF_SC1);
  float* sc2   = (float*)(ws + OFF_SC2);
  int* perm1   = (int*)(ws + OFF_PERM1);
  float* val1  = (float*)(ws + OFF_VAL1);
  int* perm2   = (int*)(ws + OFF_PERM2);
  float* val2  = (float*)(ws + OFF_VAL2);
  int* newid1  = (int*)(ws + OFF_NEWID);
  float* pnorm = (float*)(ws + OFF_PNORM);
  float* x1    = (float*)(ws + OFF_X1);
  float* x2    = (float*)(ws + OFF_X2);
  float* zws   = (float*)(ws + OFF_ZWS);
  unsigned short* Wt1 = (unsigned short*)(ws + OFF_WT1);
  unsigned short* Wt2 = (unsigned short*)(ws + OFF_WT2);

  hipMemsetAsync(ws + ZERO_BASE, 0, ZERO_BYTES, stream);
  hipMemsetAsync(ws + OFF_NEWID, 0xFF, (size_t)NN1_ * 4, stream);  // new_id = -1

  // fused prep: x->bf16, dst count, W1^T, W2^T, pnorms
  k_prep<<<PREP_BLOCKS, 256, 0, stream>>>(x, dstv, W1, W2, p1, p2,
                                          xbf, cnt1, Wt1, Wt2, pnorm);

  // ---- stage 1 ----
  k_scan_g<<<B_, 256, 0, stream>>>(cnt1, ptr1, N_);
  k_fill<<<E_ / 256, 256, 0, stream>>>(srcv, dstv, ptr1, fill1, csr1);
  k_agg_bf<<<NN1_, FIN_ / 4, 0, stream>>>(xbf, csr1, ptr1, cnt1, xagg, FIN_);
  k_gemm_bf<<<dim3(H_ / 128, NN1_ / 256), 512, 0, stream>>>(xagg, Wt1, b1, conv1, bn1, NN1_, H_, FIN_);
  k_score<<<NN1_, 256, 0, stream>>>(conv1, bn1, g1, be1, 1.0f / (float)NN1_, p1, pnorm + 0, sc1);
  k_topk<<<B_, 256, 0, stream>>>(sc1, N_, K1_, perm1, val1, newid1);
  k_pool_bn<<<NN2_, 256, 0, stream>>>(conv1, bn1, g1, be1, 1.0f / (float)NN1_, perm1, val1, hpool);
  k_mean<<<dim3(B_, H_ / 256, 8), 256, 0, stream>>>(hpool, x1, K1_, K1_ / 8);

  // ---- stage 2 ----
  k_count2<<<E_ / 256, 256, 0, stream>>>(srcv, dstv, newid1, cnt2);
  k_scan_g<<<B_, 256, 0, stream>>>(cnt2, ptr2, K1_);
  k_fill2<<<E_ / 256, 256, 0, stream>>>(srcv, dstv, newid1, ptr2, fill2, csr2);
  k_agg_bf<<<NN2_, H_ / 4, 0, stream>>>(hpool, csr2, ptr2, cnt2, hagg2, H_);
  k_gemm_bf<<<dim3(H_ / 128, NN2_ / 256), 512, 0, stream>>>(hagg2, Wt2, b2, conv2, bn2, NN2_, H_, H_);
  k_score<<<NN2_, 256, 0, stream>>>(conv2, bn2, g2, be2, 1.0f / (float)NN2_, p2, pnorm + 1, sc2);
  k_topk<<<B_, 256, 0, stream>>>(sc2, K1_, K2_, perm2, val2, nullptr);
  k_mean_scaled_bn<<<dim3(B_, H_ / 256, 4), 256, 0, stream>>>(conv2, bn2, g2, be2, 1.0f / (float)NN2_,
                                                              perm2, val2, x2, K2_, K2_ / 4);

  // ---- head ----
  k_head1<<<dim3(B_, 8), 512, 0, stream>>>(x1, x2, Wf, zws);
  k_head2<<<B_, 512, 0, stream>>>(zws, bf, Wf1, bf1, (float*)d_out);
}